// Round 3
// baseline (2137.149 us; speedup 1.0000x reference)
//
#include <hip/hip_runtime.h>
#include <math.h>

#define DEV __device__ __forceinline__

DEV float sigm(float x) { return 1.0f / (1.0f + __expf(-x)); }

// ============================ utility kernels ============================

__global__ void fill_i32_kernel(int* p, int v, int n) {
  int i = blockIdx.x * blockDim.x + threadIdx.x;
  if (i < n) p[i] = v;
}

// count incoming edges per dst (including self loops)
__global__ void count_edges_kernel(const int* __restrict__ ei, int* __restrict__ cnt,
                                   int E, int N) {
  int e = blockIdx.x * blockDim.x + threadIdx.x;
  if (e >= E + N) return;
  int d = (e < E) ? ei[E + e] : (e - E);
  atomicAdd(&cnt[d], 1);
}

// in-place exclusive scan within each 256-block; blockSums gets block totals
__global__ void scan1_kernel(int* data, int* blockSums) {
  __shared__ int sh[256];
  int tid = threadIdx.x;
  int gid = blockIdx.x * 256 + tid;
  int v = data[gid];
  sh[tid] = v;
  __syncthreads();
  int val = v;
  for (int off = 1; off < 256; off <<= 1) {
    int add = (tid >= off) ? sh[tid - off] : 0;
    __syncthreads();
    val += add;
    sh[tid] = val;
    __syncthreads();
  }
  data[gid] = val - v;  // exclusive
  if (tid == 255) blockSums[blockIdx.x] = val;
}

// single block: exclusive scan of the 256 block sums, in place
__global__ void scan2_kernel(int* blockSums) {
  __shared__ int sh[256];
  int tid = threadIdx.x;
  int v = blockSums[tid];
  sh[tid] = v;
  __syncthreads();
  int val = v;
  for (int off = 1; off < 256; off <<= 1) {
    int add = (tid >= off) ? sh[tid - off] : 0;
    __syncthreads();
    val += add;
    sh[tid] = val;
    __syncthreads();
  }
  blockSums[tid] = val - v;
}

__global__ void scan3_kernel(int* row_start, int* cursor, const int* blockOff,
                             int N, int Et) {
  int tid = threadIdx.x;
  int gid = blockIdx.x * 256 + tid;
  int v = row_start[gid] + blockOff[blockIdx.x];
  row_start[gid] = v;
  cursor[gid] = v;
  if (gid == 0) row_start[N] = Et;
}

__global__ void scatter_kernel(const int* __restrict__ ei, int* __restrict__ cursor,
                               int* __restrict__ srcs, int E, int N) {
  int e = blockIdx.x * blockDim.x + threadIdx.x;
  if (e >= E + N) return;
  int s, d;
  if (e < E) { s = ei[e]; d = ei[E + e]; } else { s = e - E; d = e - E; }
  int pos = atomicAdd(&cursor[d], 1);
  srcs[pos] = s;
}

// ============================ skinny GEMM ============================
// C[N x M] = act(A[N x K] @ W[K x M] + bias), M <= 256.
// lane = row. W[k][c] is wave-uniform -> s_load into SGPRs; A read as one
// scalar b32 per k per lane (own-row stream, L1-friendly); TN accumulators
// per thread give TN independent FMA chains. No LDS, no barriers.
template <int TN>
__global__ __launch_bounds__(256) void gemm_skinny(
    const float* __restrict__ A, int lda,
    const float* __restrict__ W, int ldw,
    const float* __restrict__ bias,
    float* __restrict__ C, int ldc,
    int K, int act) {
  const long long row = (long long)blockIdx.y * 256 + threadIdx.x;
  const int c0 = blockIdx.x * TN;
  const float* __restrict__ arow = A + row * lda;

  float acc[TN];
#pragma unroll
  for (int c = 0; c < TN; ++c) acc[c] = 0.0f;

#pragma unroll 4
  for (int k = 0; k < K; ++k) {
    float a = arow[k];
    const float* __restrict__ wrow = W + (long long)k * ldw + c0;
#pragma unroll
    for (int c4 = 0; c4 < TN / 4; ++c4) {
      float4 w = *reinterpret_cast<const float4*>(wrow + c4 * 4);
      acc[c4 * 4 + 0] = fmaf(a, w.x, acc[c4 * 4 + 0]);
      acc[c4 * 4 + 1] = fmaf(a, w.y, acc[c4 * 4 + 1]);
      acc[c4 * 4 + 2] = fmaf(a, w.z, acc[c4 * 4 + 2]);
      acc[c4 * 4 + 3] = fmaf(a, w.w, acc[c4 * 4 + 3]);
    }
  }

  float* crow = C + row * ldc + c0;
#pragma unroll
  for (int c4 = 0; c4 < TN / 4; ++c4) {
    float4 v;
    v.x = acc[c4 * 4 + 0] + (bias ? bias[c0 + c4 * 4 + 0] : 0.0f);
    v.y = acc[c4 * 4 + 1] + (bias ? bias[c0 + c4 * 4 + 1] : 0.0f);
    v.z = acc[c4 * 4 + 2] + (bias ? bias[c0 + c4 * 4 + 2] : 0.0f);
    v.w = acc[c4 * 4 + 3] + (bias ? bias[c0 + c4 * 4 + 3] : 0.0f);
    if (act == 1) {
      v.x = fmaxf(v.x, 0.0f); v.y = fmaxf(v.y, 0.0f);
      v.z = fmaxf(v.z, 0.0f); v.w = fmaxf(v.w, 0.0f);
    }
    *reinterpret_cast<float4*>(crow + c4 * 4) = v;
  }
}

// ============================ GAT helpers ============================

// s[i] = dot(G[i,:], a_src), t[i] = dot(G[i,:], a_dst); one wave per node
__global__ __launch_bounds__(256) void st_kernel(
    const float* __restrict__ G, const float* __restrict__ asrc,
    const float* __restrict__ adst, float* __restrict__ s, float* __restrict__ t,
    int N, int fo) {
  int w = (blockIdx.x * blockDim.x + threadIdx.x) >> 6;
  int lane = threadIdx.x & 63;
  if (w >= N) return;
  const float* row = G + (long long)w * fo;
  float ps = 0.0f, pt = 0.0f;
  for (int c = lane; c < fo; c += 64) {
    float v = row[c];
    ps += v * asrc[c];
    pt += v * adst[c];
  }
  for (int off = 32; off; off >>= 1) {
    ps += __shfl_xor(ps, off, 64);
    pt += __shfl_xor(pt, off, 64);
  }
  if (lane == 0) { s[w] = ps; t[w] = pt; }
}

// one wave per dst node: softmax over incoming edges + weighted aggregation
template <int FO>
__global__ __launch_bounds__(256) void gat_aggregate(
    const float* __restrict__ G, const float* __restrict__ s,
    const float* __restrict__ t, const int* __restrict__ row_start,
    const int* __restrict__ srcs, const float* __restrict__ bias,
    float* __restrict__ out, int ldc, int N) {
  int d = (blockIdx.x * blockDim.x + threadIdx.x) >> 6;
  int lane = threadIdx.x & 63;
  if (d >= N) return;
  int start = row_start[d], end = row_start[d + 1];
  float td = t[d];

  // pass 1: max
  float m = -INFINITY;
  for (int j = start + lane; j < end; j += 64) {
    float e = s[srcs[j]] + td;
    e = (e >= 0.0f) ? e : 0.2f * e;
    m = fmaxf(m, e);
  }
  for (int off = 32; off; off >>= 1) m = fmaxf(m, __shfl_xor(m, off, 64));

  // pass 2: denom
  float dsum = 0.0f;
  for (int j = start + lane; j < end; j += 64) {
    float e = s[srcs[j]] + td;
    e = (e >= 0.0f) ? e : 0.2f * e;
    dsum += __expf(e - m);
  }
  for (int off = 32; off; off >>= 1) dsum += __shfl_xor(dsum, off, 64);
  float inv = 1.0f / dsum;

  // pass 3: weighted accumulation (lanes = feature cols, coalesced gathers)
  float acc0 = 0.0f, acc1 = 0.0f;
  for (int j = start; j < end; ++j) {
    int srcj = srcs[j];
    float e = s[srcj] + td;
    e = (e >= 0.0f) ? e : 0.2f * e;
    float alpha = __expf(e - m) * inv;
    acc0 += alpha * G[(long long)srcj * FO + lane];
    if (FO == 128) acc1 += alpha * G[(long long)srcj * FO + 64 + lane];
  }
  float o0 = fmaxf(acc0 + bias[lane], 0.0f);
  out[(long long)d * ldc + lane] = o0;
  if (FO == 128) {
    float o1 = fmaxf(acc1 + bias[64 + lane], 0.0f);
    out[(long long)d * ldc + 64 + lane] = o1;
  }
}

// ============================ LSTM / head ============================

// gates[N x 256] -> h[N x 64]; c = sig(i)*tanh(g); h = sig(o)*tanh(c)
__global__ void lstm_act_kernel(const float* __restrict__ gates,
                                float* __restrict__ h, int N) {
  int idx = blockIdx.x * blockDim.x + threadIdx.x;
  if (idx >= N * 64) return;
  int i = idx >> 6, c = idx & 63;
  const float* g = gates + (long long)i * 256;
  float gi = g[c], gg = g[128 + c], go = g[192 + c];
  float cc = sigm(gi) * tanhf(gg);
  h[idx] = sigm(go) * tanhf(cc);
}

// out[i] = dot(Z[i,:64], w) + b
__global__ void lin3_kernel(const float* __restrict__ Z, const float* __restrict__ w,
                            const float* __restrict__ b, float* __restrict__ out, int N) {
  int i = blockIdx.x * blockDim.x + threadIdx.x;
  if (i >= N) return;
  const float4* z4 = (const float4*)(Z + (long long)i * 64);
  const float4* w4 = (const float4*)w;
  float acc = 0.0f;
#pragma unroll
  for (int k = 0; k < 16; ++k) {
    float4 a = z4[k], ww = w4[k];
    acc += a.x * ww.x + a.y * ww.y + a.z * ww.z + a.w * ww.w;
  }
  out[i] = acc + b[0];
}

// ============================ launcher ============================

static inline void launch_gemm(const float* A, int lda, const float* W, int ldw,
                               const float* bias, float* C, int ldc,
                               int N, int K, int M, int act, hipStream_t stream) {
  // TN=32 for M>=128 (grid >= 4x256 blocks), TN=16 for M=64 -> always
  // >=1024 blocks = >=4 waves/SIMD.
  if (M >= 128) {
    dim3 grid(M / 32, N / 256);
    hipLaunchKernelGGL((gemm_skinny<32>), grid, dim3(256), 0, stream,
                       A, lda, W, ldw, bias, C, ldc, K, act);
  } else {
    dim3 grid(M / 16, N / 256);
    hipLaunchKernelGGL((gemm_skinny<16>), grid, dim3(256), 0, stream,
                       A, lda, W, ldw, bias, C, ldc, K, act);
  }
}

extern "C" void kernel_launch(void* const* d_in, const int* in_sizes, int n_in,
                              void* d_out, int out_size, void* d_ws, size_t ws_size,
                              hipStream_t stream) {
  const int N = 65536, E = 1048576;
  const int Et = E + N;

  const float* x        = (const float*)d_in[0];   // N x 445
  const int*   ei       = (const int*)d_in[1];     // 2 x E
  const float* poi1_W   = (const float*)d_in[2];
  const float* poi1_b   = (const float*)d_in[3];
  const float* poi2_W   = (const float*)d_in[4];
  const float* poi2_b   = (const float*)d_in[5];
  const float* svi1_W   = (const float*)d_in[6];
  const float* svi1_b   = (const float*)d_in[7];
  const float* svi2_W   = (const float*)d_in[8];
  const float* svi2_b   = (const float*)d_in[9];
  const float* all1_W   = (const float*)d_in[10];
  const float* all1_b   = (const float*)d_in[11];
  const float* all2_W   = (const float*)d_in[12];
  const float* all2_b   = (const float*)d_in[13];
  const float* gat1_W   = (const float*)d_in[14];
  const float* gat1_b   = (const float*)d_in[15];
  const float* gat1_as  = (const float*)d_in[16];
  const float* gat1_ad  = (const float*)d_in[17];
  const float* gat2_W   = (const float*)d_in[18];
  const float* gat2_b   = (const float*)d_in[19];
  const float* gat2_as  = (const float*)d_in[20];
  const float* gat2_ad  = (const float*)d_in[21];
  const float* gat3_W   = (const float*)d_in[22];
  const float* gat3_b   = (const float*)d_in[23];
  const float* gat3_as  = (const float*)d_in[24];
  const float* gat3_ad  = (const float*)d_in[25];
  const float* lstm_Wih0= (const float*)d_in[26];  // 24 x 256
  const float* lstm_Wih = (const float*)d_in[27];  // 23 x 64 x 256
  // d_in[28] = lstm_Whh : UNUSED by the reference
  const float* lstm_b   = (const float*)d_in[29];  // 24 x 256
  const float* time1_W  = (const float*)d_in[30];
  const float* time1_b  = (const float*)d_in[31];
  const float* time2_W  = (const float*)d_in[32];
  const float* time2_b  = (const float*)d_in[33];
  const float* lin1_W   = (const float*)d_in[34];
  const float* lin1_b   = (const float*)d_in[35];
  const float* lin2_W   = (const float*)d_in[36];
  const float* lin2_b   = (const float*)d_in[37];
  const float* lin3_W   = (const float*)d_in[38];
  const float* lin3_b   = (const float*)d_in[39];
  float* out = (float*)d_out;

  // ---- workspace layout (floats then ints) ----
  float* wsf   = (float*)d_ws;
  float* R192  = wsf;                         // N x 192  (concat poi|svi)
  float* RA    = R192 + (size_t)N * 192;      // N x 128  (general)
  float* RA2   = RA + (size_t)N * 64;         // second N x 64 half of RA
  float* RB    = RA + (size_t)N * 128;        // N x 256  (gates / general)
  float* Rz    = RB + (size_t)N * 256;        // N x 128  (concat gat3|time)
  float* sArr  = Rz + (size_t)N * 128;        // N
  float* tArr  = sArr + N;                    // N
  int* ints      = (int*)(tArr + N);
  int* row_start = ints;                      // N+1  (also used as cnt)
  int* cursor    = row_start + (N + 1);       // N
  int* srcs      = cursor + N;                // Et
  int* blockSums = srcs + Et;                 // 256

  const int TB = 256;
  const int edgeBlocks = (Et + TB - 1) / TB;

  // ---- build CSR (dst-sorted src list); shared by all 3 GAT layers ----
  hipLaunchKernelGGL(fill_i32_kernel, dim3((N + TB - 1) / TB), dim3(TB), 0, stream,
                     row_start, 0, N);
  hipLaunchKernelGGL(count_edges_kernel, dim3(edgeBlocks), dim3(TB), 0, stream,
                     ei, row_start, E, N);
  hipLaunchKernelGGL(scan1_kernel, dim3(N / 256), dim3(256), 0, stream,
                     row_start, blockSums);
  hipLaunchKernelGGL(scan2_kernel, dim3(1), dim3(256), 0, stream, blockSums);
  hipLaunchKernelGGL(scan3_kernel, dim3(N / 256), dim3(256), 0, stream,
                     row_start, cursor, blockSums, N, Et);
  hipLaunchKernelGGL(scatter_kernel, dim3(edgeBlocks), dim3(TB), 0, stream,
                     ei, cursor, srcs, E, N);

  // ---- MLP towers ----
  // poi: x[:,3:16] -> 64 -> 64 (into R192 cols 0..63)
  launch_gemm(x + 3, 445, poi1_W, 64, poi1_b, RA, 64, N, 13, 64, 1, stream);
  launch_gemm(RA, 64, poi2_W, 64, poi2_b, R192, 192, N, 64, 64, 1, stream);
  // svi: x[:,56:421] -> 128 -> 128 (into R192 cols 64..191)
  launch_gemm(x + 56, 445, svi1_W, 128, svi1_b, RB, 128, N, 365, 128, 1, stream);
  launch_gemm(RB, 128, svi2_W, 128, svi2_b, R192 + 64, 192, N, 128, 128, 1, stream);
  // all: 192 -> 128 -> 128  => H in RB
  launch_gemm(R192, 192, all1_W, 128, all1_b, RA, 128, N, 192, 128, 1, stream);
  launch_gemm(RA, 128, all2_W, 128, all2_b, RB, 128, N, 128, 128, 1, stream);

  const int waveBlocks = N / 4;  // 4 waves (dst nodes) per 256-thread block

  // ---- GAT1: RB(H) -> RA(G) -> aggregate -> RB(H2) ----
  launch_gemm(RB, 128, gat1_W, 128, nullptr, RA, 128, N, 128, 128, 0, stream);
  hipLaunchKernelGGL(st_kernel, dim3(waveBlocks), dim3(256), 0, stream,
                     RA, gat1_as, gat1_ad, sArr, tArr, N, 128);
  hipLaunchKernelGGL((gat_aggregate<128>), dim3(waveBlocks), dim3(256), 0, stream,
                     RA, sArr, tArr, row_start, srcs, gat1_b, RB, 128, N);
  // ---- GAT2 ----
  launch_gemm(RB, 128, gat2_W, 128, nullptr, RA, 128, N, 128, 128, 0, stream);
  hipLaunchKernelGGL(st_kernel, dim3(waveBlocks), dim3(256), 0, stream,
                     RA, gat2_as, gat2_ad, sArr, tArr, N, 128);
  hipLaunchKernelGGL((gat_aggregate<128>), dim3(waveBlocks), dim3(256), 0, stream,
                     RA, sArr, tArr, row_start, srcs, gat2_b, RB, 128, N);
  // ---- GAT3 (fo=64, output into Rz cols 0..63) ----
  launch_gemm(RB, 128, gat3_W, 64, nullptr, RA, 64, N, 128, 64, 0, stream);
  hipLaunchKernelGGL(st_kernel, dim3(waveBlocks), dim3(256), 0, stream,
                     RA, gat3_as, gat3_ad, sArr, tArr, N, 64);
  hipLaunchKernelGGL((gat_aggregate<64>), dim3(waveBlocks), dim3(256), 0, stream,
                     RA, sArr, tArr, row_start, srcs, gat3_b, Rz, 128, N);

  // ---- "LSTM": only layers 0..2 matter (t = hs[2]); Whh/f-gate/cell unused ----
  const int actBlocks = (N * 64 + TB - 1) / TB;
  launch_gemm(x + 421, 445, lstm_Wih0, 256, lstm_b, RB, 256, N, 24, 256, 0, stream);
  hipLaunchKernelGGL(lstm_act_kernel, dim3(actBlocks), dim3(TB), 0, stream, RB, RA, N);
  launch_gemm(RA, 64, lstm_Wih, 256, lstm_b + 256, RB, 256, N, 64, 256, 0, stream);
  hipLaunchKernelGGL(lstm_act_kernel, dim3(actBlocks), dim3(TB), 0, stream, RB, RA2, N);
  launch_gemm(RA2, 64, lstm_Wih + 64 * 256, 256, lstm_b + 512, RB, 256, N, 64, 256, 0, stream);
  hipLaunchKernelGGL(lstm_act_kernel, dim3(actBlocks), dim3(TB), 0, stream, RB, RA, N);

  // ---- time MLP: h2 -> 64 -> 64 (into Rz cols 64..127) ----
  launch_gemm(RA, 64, time1_W, 64, time1_b, RA2, 64, N, 64, 64, 1, stream);
  launch_gemm(RA2, 64, time2_W, 64, time2_b, Rz + 64, 128, N, 64, 64, 1, stream);

  // ---- head: z = [gat3|time] (N x 128) -> 64 -> 64 -> 1 ----
  launch_gemm(Rz, 128, lin1_W, 64, lin1_b, RA, 64, N, 128, 64, 1, stream);
  launch_gemm(RA, 64, lin2_W, 64, lin2_b, RA2, 64, N, 64, 64, 1, stream);
  hipLaunchKernelGGL(lin3_kernel, dim3((N + TB - 1) / TB), dim3(TB), 0, stream,
                     RA2, lin3_W, lin3_b, out, N);
}

// Round 4
// 1455.329 us; speedup vs baseline: 1.4685x; 1.4685x over previous
//
#include <hip/hip_runtime.h>
#include <math.h>

#define DEV __device__ __forceinline__

DEV float sigm(float x) { return 1.0f / (1.0f + __expf(-x)); }

// ============================ utility kernels ============================

__global__ void fill_i32_kernel(int* p, int v, int n) {
  int i = blockIdx.x * blockDim.x + threadIdx.x;
  if (i < n) p[i] = v;
}

// count incoming edges per dst (including self loops)
__global__ void count_edges_kernel(const int* __restrict__ ei, int* __restrict__ cnt,
                                   int E, int N) {
  int e = blockIdx.x * blockDim.x + threadIdx.x;
  if (e >= E + N) return;
  int d = (e < E) ? ei[E + e] : (e - E);
  atomicAdd(&cnt[d], 1);
}

// in-place exclusive scan within each 256-block; blockSums gets block totals
__global__ void scan1_kernel(int* data, int* blockSums) {
  __shared__ int sh[256];
  int tid = threadIdx.x;
  int gid = blockIdx.x * 256 + tid;
  int v = data[gid];
  sh[tid] = v;
  __syncthreads();
  int val = v;
  for (int off = 1; off < 256; off <<= 1) {
    int add = (tid >= off) ? sh[tid - off] : 0;
    __syncthreads();
    val += add;
    sh[tid] = val;
    __syncthreads();
  }
  data[gid] = val - v;  // exclusive
  if (tid == 255) blockSums[blockIdx.x] = val;
}

// single block: exclusive scan of the 256 block sums, in place
__global__ void scan2_kernel(int* blockSums) {
  __shared__ int sh[256];
  int tid = threadIdx.x;
  int v = blockSums[tid];
  sh[tid] = v;
  __syncthreads();
  int val = v;
  for (int off = 1; off < 256; off <<= 1) {
    int add = (tid >= off) ? sh[tid - off] : 0;
    __syncthreads();
    val += add;
    sh[tid] = val;
    __syncthreads();
  }
  blockSums[tid] = val - v;
}

__global__ void scan3_kernel(int* row_start, int* cursor, const int* blockOff,
                             int N, int Et) {
  int tid = threadIdx.x;
  int gid = blockIdx.x * 256 + tid;
  int v = row_start[gid] + blockOff[blockIdx.x];
  row_start[gid] = v;
  cursor[gid] = v;
  if (gid == 0) row_start[N] = Et;
}

__global__ void scatter_kernel(const int* __restrict__ ei, int* __restrict__ cursor,
                               int* __restrict__ srcs, int E, int N) {
  int e = blockIdx.x * blockDim.x + threadIdx.x;
  if (e >= E + N) return;
  int s, d;
  if (e < E) { s = ei[e]; d = ei[E + e]; } else { s = e - E; d = e - E; }
  int pos = atomicAdd(&cursor[d], 1);
  srcs[pos] = s;
}

// ============================ GEMM ============================
// C[N x M] = act(A[N x K] @ W[K x M] + bias). Row-major.
// BM=64 tall-skinny tiles -> grid >= 1024 blocks (4 blocks/CU, 50% occ).
// BK=32 halves barrier count. TN split into float4 groups at g*64+tx*4
// to keep LDS column reads <=2-way bank-aliased.
template <int BM, int BN, int TM, int TN>
__global__ __launch_bounds__(256) void gemm_f32_tile(
    const float* __restrict__ A, int lda,
    const float* __restrict__ W, int ldw,
    const float* __restrict__ bias,
    float* __restrict__ C, int ldc,
    int K, int act) {
  constexpr int BK = 32;
  constexpr int NX = BN / TN;  // 16
  __shared__ float As[BK][BM + 4];
  __shared__ float Ws[BK][BN];
  const int tid = threadIdx.x;
  const int tx = tid % NX;
  const int ty = tid / NX;
  const long long r0 = (long long)blockIdx.y * BM;
  const int c0 = blockIdx.x * BN;

  float acc[TM][TN] = {};

  for (int k0 = 0; k0 < K; k0 += BK) {
    // stage A: BM rows x BK k, transposed into As[kk][row]
    {
      int row = tid & (BM - 1);
      int kb = (tid / BM) * 8;
      const float* ap = A + (r0 + row) * lda + k0 + kb;
#pragma unroll
      for (int j = 0; j < 8; ++j) {
        int kk = kb + j;
        As[kk][row] = (k0 + kk < K) ? ap[j] : 0.0f;
      }
    }
    // stage W: BK x BN (coalesced row-major b128 reads)
    for (int s = tid; s < BK * BN / 8; s += 256) {
      int kk = s / (BN / 8);
      int cb = (s % (BN / 8)) * 8;
      bool ok = (k0 + kk) < K;
      const float* wp = W + (long long)(ok ? (k0 + kk) : 0) * ldw + c0 + cb;
#pragma unroll
      for (int j = 0; j < 8; ++j)
        Ws[kk][cb + j] = ok ? wp[j] : 0.0f;
    }
    __syncthreads();
#pragma unroll
    for (int kk = 0; kk < BK; ++kk) {
      float a_reg[TM], b_reg[TN];
#pragma unroll
      for (int i = 0; i < TM; ++i) a_reg[i] = As[kk][ty * TM + i];
#pragma unroll
      for (int g = 0; g < TN / 4; ++g)
#pragma unroll
        for (int j = 0; j < 4; ++j)
          b_reg[g * 4 + j] = Ws[kk][g * 64 + tx * 4 + j];
#pragma unroll
      for (int i = 0; i < TM; ++i)
#pragma unroll
        for (int j = 0; j < TN; ++j)
          acc[i][j] += a_reg[i] * b_reg[j];
    }
    __syncthreads();
  }

#pragma unroll
  for (int i = 0; i < TM; ++i) {
    long long r = r0 + ty * TM + i;
#pragma unroll
    for (int g = 0; g < TN / 4; ++g) {
      int c = c0 + g * 64 + tx * 4;
      float4 v;
      v.x = acc[i][g * 4 + 0] + (bias ? bias[c + 0] : 0.0f);
      v.y = acc[i][g * 4 + 1] + (bias ? bias[c + 1] : 0.0f);
      v.z = acc[i][g * 4 + 2] + (bias ? bias[c + 2] : 0.0f);
      v.w = acc[i][g * 4 + 3] + (bias ? bias[c + 3] : 0.0f);
      if (act == 1) {
        v.x = fmaxf(v.x, 0.0f); v.y = fmaxf(v.y, 0.0f);
        v.z = fmaxf(v.z, 0.0f); v.w = fmaxf(v.w, 0.0f);
      }
      *reinterpret_cast<float4*>(C + r * ldc + c) = v;
    }
  }
}

// ============================ GAT helpers ============================

// s[i] = dot(G[i,:], a_src), t[i] = dot(G[i,:], a_dst); one wave per node
__global__ __launch_bounds__(256) void st_kernel(
    const float* __restrict__ G, const float* __restrict__ asrc,
    const float* __restrict__ adst, float* __restrict__ s, float* __restrict__ t,
    int N, int fo) {
  int w = (blockIdx.x * blockDim.x + threadIdx.x) >> 6;
  int lane = threadIdx.x & 63;
  if (w >= N) return;
  const float* row = G + (long long)w * fo;
  float ps = 0.0f, pt = 0.0f;
  for (int c = lane; c < fo; c += 64) {
    float v = row[c];
    ps += v * asrc[c];
    pt += v * adst[c];
  }
  for (int off = 32; off; off >>= 1) {
    ps += __shfl_xor(ps, off, 64);
    pt += __shfl_xor(pt, off, 64);
  }
  if (lane == 0) { s[w] = ps; t[w] = pt; }
}

// one wave per dst node: softmax over incoming edges + weighted aggregation
template <int FO>
__global__ __launch_bounds__(256) void gat_aggregate(
    const float* __restrict__ G, const float* __restrict__ s,
    const float* __restrict__ t, const int* __restrict__ row_start,
    const int* __restrict__ srcs, const float* __restrict__ bias,
    float* __restrict__ out, int ldc, int N) {
  int d = (blockIdx.x * blockDim.x + threadIdx.x) >> 6;
  int lane = threadIdx.x & 63;
  if (d >= N) return;
  int start = row_start[d], end = row_start[d + 1];
  float td = t[d];

  // pass 1: max
  float m = -INFINITY;
  for (int j = start + lane; j < end; j += 64) {
    float e = s[srcs[j]] + td;
    e = (e >= 0.0f) ? e : 0.2f * e;
    m = fmaxf(m, e);
  }
  for (int off = 32; off; off >>= 1) m = fmaxf(m, __shfl_xor(m, off, 64));

  // pass 2: denom
  float dsum = 0.0f;
  for (int j = start + lane; j < end; j += 64) {
    float e = s[srcs[j]] + td;
    e = (e >= 0.0f) ? e : 0.2f * e;
    dsum += __expf(e - m);
  }
  for (int off = 32; off; off >>= 1) dsum += __shfl_xor(dsum, off, 64);
  float inv = 1.0f / dsum;

  // pass 3: weighted accumulation (lanes = feature cols, coalesced gathers)
  float acc0 = 0.0f, acc1 = 0.0f;
  for (int j = start; j < end; ++j) {
    int srcj = srcs[j];
    float e = s[srcj] + td;
    e = (e >= 0.0f) ? e : 0.2f * e;
    float alpha = __expf(e - m) * inv;
    acc0 += alpha * G[(long long)srcj * FO + lane];
    if (FO == 128) acc1 += alpha * G[(long long)srcj * FO + 64 + lane];
  }
  float o0 = fmaxf(acc0 + bias[lane], 0.0f);
  out[(long long)d * ldc + lane] = o0;
  if (FO == 128) {
    float o1 = fmaxf(acc1 + bias[64 + lane], 0.0f);
    out[(long long)d * ldc + 64 + lane] = o1;
  }
}

// ============================ LSTM / head ============================

// gates[N x 256] -> h[N x 64]; c = sig(i)*tanh(g); h = sig(o)*tanh(c)
__global__ void lstm_act_kernel(const float* __restrict__ gates,
                                float* __restrict__ h, int N) {
  int idx = blockIdx.x * blockDim.x + threadIdx.x;
  if (idx >= N * 64) return;
  int i = idx >> 6, c = idx & 63;
  const float* g = gates + (long long)i * 256;
  float gi = g[c], gg = g[128 + c], go = g[192 + c];
  float cc = sigm(gi) * tanhf(gg);
  h[idx] = sigm(go) * tanhf(cc);
}

// out[i] = dot(Z[i,:64], w) + b
__global__ void lin3_kernel(const float* __restrict__ Z, const float* __restrict__ w,
                            const float* __restrict__ b, float* __restrict__ out, int N) {
  int i = blockIdx.x * blockDim.x + threadIdx.x;
  if (i >= N) return;
  const float4* z4 = (const float4*)(Z + (long long)i * 64);
  const float4* w4 = (const float4*)w;
  float acc = 0.0f;
#pragma unroll
  for (int k = 0; k < 16; ++k) {
    float4 a = z4[k], ww = w4[k];
    acc += a.x * ww.x + a.y * ww.y + a.z * ww.z + a.w * ww.w;
  }
  out[i] = acc + b[0];
}

// ============================ launcher ============================

static inline void launch_gemm(const float* A, int lda, const float* W, int ldw,
                               const float* bias, float* C, int ldc,
                               int N, int K, int M, int act, hipStream_t stream) {
  if (M % 128 == 0) {
    dim3 grid(M / 128, N / 64);
    hipLaunchKernelGGL((gemm_f32_tile<64, 128, 4, 8>), grid, dim3(256), 0, stream,
                       A, lda, W, ldw, bias, C, ldc, K, act);
  } else {
    dim3 grid(M / 64, N / 64);
    hipLaunchKernelGGL((gemm_f32_tile<64, 64, 4, 4>), grid, dim3(256), 0, stream,
                       A, lda, W, ldw, bias, C, ldc, K, act);
  }
}

extern "C" void kernel_launch(void* const* d_in, const int* in_sizes, int n_in,
                              void* d_out, int out_size, void* d_ws, size_t ws_size,
                              hipStream_t stream) {
  const int N = 65536, E = 1048576;
  const int Et = E + N;

  const float* x        = (const float*)d_in[0];   // N x 445
  const int*   ei       = (const int*)d_in[1];     // 2 x E
  const float* poi1_W   = (const float*)d_in[2];
  const float* poi1_b   = (const float*)d_in[3];
  const float* poi2_W   = (const float*)d_in[4];
  const float* poi2_b   = (const float*)d_in[5];
  const float* svi1_W   = (const float*)d_in[6];
  const float* svi1_b   = (const float*)d_in[7];
  const float* svi2_W   = (const float*)d_in[8];
  const float* svi2_b   = (const float*)d_in[9];
  const float* all1_W   = (const float*)d_in[10];
  const float* all1_b   = (const float*)d_in[11];
  const float* all2_W   = (const float*)d_in[12];
  const float* all2_b   = (const float*)d_in[13];
  const float* gat1_W   = (const float*)d_in[14];
  const float* gat1_b   = (const float*)d_in[15];
  const float* gat1_as  = (const float*)d_in[16];
  const float* gat1_ad  = (const float*)d_in[17];
  const float* gat2_W   = (const float*)d_in[18];
  const float* gat2_b   = (const float*)d_in[19];
  const float* gat2_as  = (const float*)d_in[20];
  const float* gat2_ad  = (const float*)d_in[21];
  const float* gat3_W   = (const float*)d_in[22];
  const float* gat3_b   = (const float*)d_in[23];
  const float* gat3_as  = (const float*)d_in[24];
  const float* gat3_ad  = (const float*)d_in[25];
  const float* lstm_Wih0= (const float*)d_in[26];  // 24 x 256
  const float* lstm_Wih = (const float*)d_in[27];  // 23 x 64 x 256
  // d_in[28] = lstm_Whh : UNUSED by the reference
  const float* lstm_b   = (const float*)d_in[29];  // 24 x 256
  const float* time1_W  = (const float*)d_in[30];
  const float* time1_b  = (const float*)d_in[31];
  const float* time2_W  = (const float*)d_in[32];
  const float* time2_b  = (const float*)d_in[33];
  const float* lin1_W   = (const float*)d_in[34];
  const float* lin1_b   = (const float*)d_in[35];
  const float* lin2_W   = (const float*)d_in[36];
  const float* lin2_b   = (const float*)d_in[37];
  const float* lin3_W   = (const float*)d_in[38];
  const float* lin3_b   = (const float*)d_in[39];
  float* out = (float*)d_out;

  // ---- workspace layout (floats then ints) ----
  float* wsf   = (float*)d_ws;
  float* R192  = wsf;                         // N x 192  (concat poi|svi)
  float* RA    = R192 + (size_t)N * 192;      // N x 128  (general)
  float* RA2   = RA + (size_t)N * 64;         // second N x 64 half of RA
  float* RB    = RA + (size_t)N * 128;        // N x 256  (gates / general)
  float* Rz    = RB + (size_t)N * 256;        // N x 128  (concat gat3|time)
  float* sArr  = Rz + (size_t)N * 128;        // N
  float* tArr  = sArr + N;                    // N
  int* ints      = (int*)(tArr + N);
  int* row_start = ints;                      // N+1  (also used as cnt)
  int* cursor    = row_start + (N + 1);       // N
  int* srcs      = cursor + N;                // Et
  int* blockSums = srcs + Et;                 // 256

  const int TB = 256;
  const int edgeBlocks = (Et + TB - 1) / TB;

  // ---- build CSR (dst-sorted src list); shared by all 3 GAT layers ----
  hipLaunchKernelGGL(fill_i32_kernel, dim3((N + TB - 1) / TB), dim3(TB), 0, stream,
                     row_start, 0, N);
  hipLaunchKernelGGL(count_edges_kernel, dim3(edgeBlocks), dim3(TB), 0, stream,
                     ei, row_start, E, N);
  hipLaunchKernelGGL(scan1_kernel, dim3(N / 256), dim3(256), 0, stream,
                     row_start, blockSums);
  hipLaunchKernelGGL(scan2_kernel, dim3(1), dim3(256), 0, stream, blockSums);
  hipLaunchKernelGGL(scan3_kernel, dim3(N / 256), dim3(256), 0, stream,
                     row_start, cursor, blockSums, N, Et);
  hipLaunchKernelGGL(scatter_kernel, dim3(edgeBlocks), dim3(TB), 0, stream,
                     ei, cursor, srcs, E, N);

  // ---- MLP towers ----
  // poi: x[:,3:16] -> 64 -> 64 (into R192 cols 0..63)
  launch_gemm(x + 3, 445, poi1_W, 64, poi1_b, RA, 64, N, 13, 64, 1, stream);
  launch_gemm(RA, 64, poi2_W, 64, poi2_b, R192, 192, N, 64, 64, 1, stream);
  // svi: x[:,56:421] -> 128 -> 128 (into R192 cols 64..191)
  launch_gemm(x + 56, 445, svi1_W, 128, svi1_b, RB, 128, N, 365, 128, 1, stream);
  launch_gemm(RB, 128, svi2_W, 128, svi2_b, R192 + 64, 192, N, 128, 128, 1, stream);
  // all: 192 -> 128 -> 128  => H in RB
  launch_gemm(R192, 192, all1_W, 128, all1_b, RA, 128, N, 192, 128, 1, stream);
  launch_gemm(RA, 128, all2_W, 128, all2_b, RB, 128, N, 128, 128, 1, stream);

  const int waveBlocks = N / 4;  // 4 waves (dst nodes) per 256-thread block

  // ---- GAT1: RB(H) -> RA(G) -> aggregate -> RB(H2) ----
  launch_gemm(RB, 128, gat1_W, 128, nullptr, RA, 128, N, 128, 128, 0, stream);
  hipLaunchKernelGGL(st_kernel, dim3(waveBlocks), dim3(256), 0, stream,
                     RA, gat1_as, gat1_ad, sArr, tArr, N, 128);
  hipLaunchKernelGGL((gat_aggregate<128>), dim3(waveBlocks), dim3(256), 0, stream,
                     RA, sArr, tArr, row_start, srcs, gat1_b, RB, 128, N);
  // ---- GAT2 ----
  launch_gemm(RB, 128, gat2_W, 128, nullptr, RA, 128, N, 128, 128, 0, stream);
  hipLaunchKernelGGL(st_kernel, dim3(waveBlocks), dim3(256), 0, stream,
                     RA, gat2_as, gat2_ad, sArr, tArr, N, 128);
  hipLaunchKernelGGL((gat_aggregate<128>), dim3(waveBlocks), dim3(256), 0, stream,
                     RA, sArr, tArr, row_start, srcs, gat2_b, RB, 128, N);
  // ---- GAT3 (fo=64, output into Rz cols 0..63) ----
  launch_gemm(RB, 128, gat3_W, 64, nullptr, RA, 64, N, 128, 64, 0, stream);
  hipLaunchKernelGGL(st_kernel, dim3(waveBlocks), dim3(256), 0, stream,
                     RA, gat3_as, gat3_ad, sArr, tArr, N, 64);
  hipLaunchKernelGGL((gat_aggregate<64>), dim3(waveBlocks), dim3(256), 0, stream,
                     RA, sArr, tArr, row_start, srcs, gat3_b, Rz, 128, N);

  // ---- "LSTM": only layers 0..2 matter (t = hs[2]); Whh/f-gate/cell unused ----
  const int actBlocks = (N * 64 + TB - 1) / TB;
  launch_gemm(x + 421, 445, lstm_Wih0, 256, lstm_b, RB, 256, N, 24, 256, 0, stream);
  hipLaunchKernelGGL(lstm_act_kernel, dim3(actBlocks), dim3(TB), 0, stream, RB, RA, N);
  launch_gemm(RA, 64, lstm_Wih, 256, lstm_b + 256, RB, 256, N, 64, 256, 0, stream);
  hipLaunchKernelGGL(lstm_act_kernel, dim3(actBlocks), dim3(TB), 0, stream, RB, RA2, N);
  launch_gemm(RA2, 64, lstm_Wih + 64 * 256, 256, lstm_b + 512, RB, 256, N, 64, 256, 0, stream);
  hipLaunchKernelGGL(lstm_act_kernel, dim3(actBlocks), dim3(TB), 0, stream, RB, RA, N);

  // ---- time MLP: h2 -> 64 -> 64 (into Rz cols 64..127) ----
  launch_gemm(RA, 64, time1_W, 64, time1_b, RA2, 64, N, 64, 64, 1, stream);
  launch_gemm(RA2, 64, time2_W, 64, time2_b, Rz + 64, 128, N, 64, 64, 1, stream);

  // ---- head: z = [gat3|time] (N x 128) -> 64 -> 64 -> 1 ----
  launch_gemm(Rz, 128, lin1_W, 64, lin1_b, RA, 64, N, 128, 64, 1, stream);
  launch_gemm(RA, 64, lin2_W, 64, lin2_b, RA2, 64, N, 64, 64, 1, stream);
  hipLaunchKernelGGL(lin3_kernel, dim3((N + TB - 1) / TB), dim3(TB), 0, stream,
                     RA2, lin3_W, lin3_b, out, N);
}

// Round 5
// 1126.577 us; speedup vs baseline: 1.8970x; 1.2918x over previous
//
#include <hip/hip_runtime.h>
#include <math.h>

#define DEV __device__ __forceinline__

typedef __attribute__((ext_vector_type(8))) short short8;   // 8 bf16 (4 VGPRs)
typedef __attribute__((ext_vector_type(4))) float f32x4;    // MFMA acc
typedef float f32x4u __attribute__((ext_vector_type(4), aligned(4)));  // 4B-aligned vec load

DEV float sigm(float x) { return 1.0f / (1.0f + __expf(-x)); }

// split 8 fp32 -> bf16 hi (truncate) + bf16 lo (truncate of exact residual)
DEV void split_bf16(const float f[8], short8& hi, short8& lo) {
#pragma unroll
  for (int i = 0; i < 8; ++i) {
    unsigned u = __builtin_bit_cast(unsigned, f[i]);
    hi[i] = (short)(u >> 16);
    float h = __builtin_bit_cast(float, u & 0xffff0000u);
    float r = f[i] - h;  // exact (Dekker)
    lo[i] = (short)(__builtin_bit_cast(unsigned, r) >> 16);
  }
}

// ============================ utility kernels ============================

__global__ void fill_i32_kernel(int* p, int v, int n) {
  int i = blockIdx.x * blockDim.x + threadIdx.x;
  if (i < n) p[i] = v;
}

__global__ void count_edges_kernel(const int* __restrict__ ei, int* __restrict__ cnt,
                                   int E, int N) {
  int e = blockIdx.x * blockDim.x + threadIdx.x;
  if (e >= E + N) return;
  int d = (e < E) ? ei[E + e] : (e - E);
  atomicAdd(&cnt[d], 1);
}

__global__ void scan1_kernel(int* data, int* blockSums) {
  __shared__ int sh[256];
  int tid = threadIdx.x;
  int gid = blockIdx.x * 256 + tid;
  int v = data[gid];
  sh[tid] = v;
  __syncthreads();
  int val = v;
  for (int off = 1; off < 256; off <<= 1) {
    int add = (tid >= off) ? sh[tid - off] : 0;
    __syncthreads();
    val += add;
    sh[tid] = val;
    __syncthreads();
  }
  data[gid] = val - v;
  if (tid == 255) blockSums[blockIdx.x] = val;
}

__global__ void scan2_kernel(int* blockSums) {
  __shared__ int sh[256];
  int tid = threadIdx.x;
  int v = blockSums[tid];
  sh[tid] = v;
  __syncthreads();
  int val = v;
  for (int off = 1; off < 256; off <<= 1) {
    int add = (tid >= off) ? sh[tid - off] : 0;
    __syncthreads();
    val += add;
    sh[tid] = val;
    __syncthreads();
  }
  blockSums[tid] = val - v;
}

__global__ void scan3_kernel(int* row_start, int* cursor, const int* blockOff,
                             int N, int Et) {
  int tid = threadIdx.x;
  int gid = blockIdx.x * 256 + tid;
  int v = row_start[gid] + blockOff[blockIdx.x];
  row_start[gid] = v;
  cursor[gid] = v;
  if (gid == 0) row_start[N] = Et;
}

__global__ void scatter_kernel(const int* __restrict__ ei, int* __restrict__ cursor,
                               int* __restrict__ srcs, int E, int N) {
  int e = blockIdx.x * blockDim.x + threadIdx.x;
  if (e >= E + N) return;
  int s, d;
  if (e < E) { s = ei[e]; d = ei[E + e]; } else { s = e - E; d = e - E; }
  int pos = atomicAdd(&cursor[d], 1);
  srcs[pos] = s;
}

// ============================ W pre-split ============================
// Split W[K x M] (row-major, ldw==M) into bf16 hi/lo, packed in MFMA B-frag
// order: frag(kc, ntG) holds B[k= kc*32 + (lane>>4)*8 + j][n= ntG*16 + (lane&15)]
// at linear offset ((kc*(M/16) + ntG)*64 + lane)*8 + j. k >= K zero-padded.
__global__ void wsplit_kernel(const float* __restrict__ W,
                              short* __restrict__ hi, short* __restrict__ lo,
                              int K, int M) {
  int lane = threadIdx.x;                 // 64
  int kc = blockIdx.x, ntG = blockIdx.y;  // gridDim.y == M/16
  int kb = kc * 32 + (lane >> 4) * 8;
  int c = ntG * 16 + (lane & 15);
  float f[8];
#pragma unroll
  for (int j = 0; j < 8; ++j) {
    int k = kb + j;
    f[j] = (k < K) ? W[(long long)k * M + c] : 0.0f;
  }
  short8 h, l;
  split_bf16(f, h, l);
  long long off = (((long long)kc * gridDim.y + ntG) * 64 + lane) * 8;
  *(short8*)(hi + off) = h;
  *(short8*)(lo + off) = l;
}

// ============================ MFMA GEMM ============================
// C[N x M] = act(A @ W + bias), fp32 A split to bf16 hi/lo in-register,
// W pre-split/pre-packed. One wave per block, 64x64 C-tile = 4x4 mfma
// 16x16x32 tiles, 3-term split product. No LDS, no barriers.
__global__ __launch_bounds__(64) void gemm_mfma(
    const float* __restrict__ A, int lda,
    const short* __restrict__ wh, const short* __restrict__ wl,
    const float* __restrict__ bias,
    float* __restrict__ C, int ldc,
    int K, int KC, int M16, int act) {
  const int lane = threadIdx.x;
  const int m = lane & 15, q = lane >> 4;
  const long long r0 = (long long)blockIdx.y * 64;
  const int ntG0 = blockIdx.x * 4;

  f32x4 acc[4][4];
#pragma unroll
  for (int i = 0; i < 4; ++i)
#pragma unroll
    for (int j = 0; j < 4; ++j) acc[i][j] = (f32x4)(0.0f);

  for (int kc = 0; kc < KC; ++kc) {
    // B fragments (coalesced bf16 reads, L1/L2-resident)
    short8 bh[4], bl[4];
#pragma unroll
    for (int nt = 0; nt < 4; ++nt) {
      long long off = (((long long)kc * M16 + (ntG0 + nt)) * 64 + lane) * 8;
      bh[nt] = *(const short8*)(wh + off);
      bl[nt] = *(const short8*)(wl + off);
    }
    // A fragments: direct global fp32 loads + in-register split
    short8 ah[4], al[4];
    const bool full = (kc * 32 + 32 <= K);
#pragma unroll
    for (int mt = 0; mt < 4; ++mt) {
      const float* ap = A + (r0 + mt * 16 + m) * lda + kc * 32 + q * 8;
      float f[8];
      if (full) {
        f32x4u p0 = *(const f32x4u*)ap;
        f32x4u p1 = *(const f32x4u*)(ap + 4);
#pragma unroll
        for (int j = 0; j < 4; ++j) { f[j] = p0[j]; f[4 + j] = p1[j]; }
      } else {
#pragma unroll
        for (int j = 0; j < 8; ++j) {
          int k = kc * 32 + q * 8 + j;
          f[j] = (k < K) ? ap[j] : 0.0f;
        }
      }
      split_bf16(f, ah[mt], al[mt]);
    }
    // 3-term split product
#pragma unroll
    for (int mt = 0; mt < 4; ++mt)
#pragma unroll
      for (int nt = 0; nt < 4; ++nt) {
        acc[mt][nt] = __builtin_amdgcn_mfma_f32_16x16x32_bf16(ah[mt], bh[nt], acc[mt][nt], 0, 0, 0);
        acc[mt][nt] = __builtin_amdgcn_mfma_f32_16x16x32_bf16(ah[mt], bl[nt], acc[mt][nt], 0, 0, 0);
        acc[mt][nt] = __builtin_amdgcn_mfma_f32_16x16x32_bf16(al[mt], bh[nt], acc[mt][nt], 0, 0, 0);
      }
  }

  // epilogue: C/D layout col=lane&15, row=(lane>>4)*4+reg  [m89-verified]
#pragma unroll
  for (int nt = 0; nt < 4; ++nt) {
    int col = (ntG0 + nt) * 16 + m;
    float bsv = bias ? bias[col] : 0.0f;
#pragma unroll
    for (int mt = 0; mt < 4; ++mt) {
      long long rb = r0 + mt * 16 + q * 4;
#pragma unroll
      for (int reg = 0; reg < 4; ++reg) {
        float v = acc[mt][nt][reg] + bsv;
        if (act == 1) v = fmaxf(v, 0.0f);
        C[(rb + reg) * ldc + col] = v;
      }
    }
  }
}

// ============================ GAT helpers ============================

__global__ __launch_bounds__(256) void st_kernel(
    const float* __restrict__ G, const float* __restrict__ asrc,
    const float* __restrict__ adst, float* __restrict__ s, float* __restrict__ t,
    int N, int fo) {
  int w = (blockIdx.x * blockDim.x + threadIdx.x) >> 6;
  int lane = threadIdx.x & 63;
  if (w >= N) return;
  const float* row = G + (long long)w * fo;
  float ps = 0.0f, pt = 0.0f;
  for (int c = lane; c < fo; c += 64) {
    float v = row[c];
    ps += v * asrc[c];
    pt += v * adst[c];
  }
  for (int off = 32; off; off >>= 1) {
    ps += __shfl_xor(ps, off, 64);
    pt += __shfl_xor(pt, off, 64);
  }
  if (lane == 0) { s[w] = ps; t[w] = pt; }
}

template <int FO>
__global__ __launch_bounds__(256) void gat_aggregate(
    const float* __restrict__ G, const float* __restrict__ s,
    const float* __restrict__ t, const int* __restrict__ row_start,
    const int* __restrict__ srcs, const float* __restrict__ bias,
    float* __restrict__ out, int ldc, int N) {
  int d = (blockIdx.x * blockDim.x + threadIdx.x) >> 6;
  int lane = threadIdx.x & 63;
  if (d >= N) return;
  int start = row_start[d], end = row_start[d + 1];
  float td = t[d];

  float mx = -INFINITY;
  for (int j = start + lane; j < end; j += 64) {
    float e = s[srcs[j]] + td;
    e = (e >= 0.0f) ? e : 0.2f * e;
    mx = fmaxf(mx, e);
  }
  for (int off = 32; off; off >>= 1) mx = fmaxf(mx, __shfl_xor(mx, off, 64));

  float dsum = 0.0f;
  for (int j = start + lane; j < end; j += 64) {
    float e = s[srcs[j]] + td;
    e = (e >= 0.0f) ? e : 0.2f * e;
    dsum += __expf(e - mx);
  }
  for (int off = 32; off; off >>= 1) dsum += __shfl_xor(dsum, off, 64);
  float inv = 1.0f / dsum;

  float acc0 = 0.0f, acc1 = 0.0f;
  for (int j = start; j < end; ++j) {
    int srcj = srcs[j];
    float e = s[srcj] + td;
    e = (e >= 0.0f) ? e : 0.2f * e;
    float alpha = __expf(e - mx) * inv;
    acc0 += alpha * G[(long long)srcj * FO + lane];
    if (FO == 128) acc1 += alpha * G[(long long)srcj * FO + 64 + lane];
  }
  float o0 = fmaxf(acc0 + bias[lane], 0.0f);
  out[(long long)d * ldc + lane] = o0;
  if (FO == 128) {
    float o1 = fmaxf(acc1 + bias[64 + lane], 0.0f);
    out[(long long)d * ldc + 64 + lane] = o1;
  }
}

// ============================ LSTM / head ============================

__global__ void lstm_act_kernel(const float* __restrict__ gates,
                                float* __restrict__ h, int N) {
  int idx = blockIdx.x * blockDim.x + threadIdx.x;
  if (idx >= N * 64) return;
  int i = idx >> 6, c = idx & 63;
  const float* g = gates + (long long)i * 256;
  float gi = g[c], gg = g[128 + c], go = g[192 + c];
  float cc = sigm(gi) * tanhf(gg);
  h[idx] = sigm(go) * tanhf(cc);
}

__global__ void lin3_kernel(const float* __restrict__ Z, const float* __restrict__ w,
                            const float* __restrict__ b, float* __restrict__ out, int N) {
  int i = blockIdx.x * blockDim.x + threadIdx.x;
  if (i >= N) return;
  const float4* z4 = (const float4*)(Z + (long long)i * 64);
  const float4* w4 = (const float4*)w;
  float acc = 0.0f;
#pragma unroll
  for (int k = 0; k < 16; ++k) {
    float4 a = z4[k], ww = w4[k];
    acc += a.x * ww.x + a.y * ww.y + a.z * ww.z + a.w * ww.w;
  }
  out[i] = acc + b[0];
}

// ============================ launcher ============================

struct WSplit { const short* hi; const short* lo; };

extern "C" void kernel_launch(void* const* d_in, const int* in_sizes, int n_in,
                              void* d_out, int out_size, void* d_ws, size_t ws_size,
                              hipStream_t stream) {
  const int N = 65536, E = 1048576;
  const int Et = E + N;

  const float* x        = (const float*)d_in[0];
  const int*   ei       = (const int*)d_in[1];
  const float* poi1_W   = (const float*)d_in[2];
  const float* poi1_b   = (const float*)d_in[3];
  const float* poi2_W   = (const float*)d_in[4];
  const float* poi2_b   = (const float*)d_in[5];
  const float* svi1_W   = (const float*)d_in[6];
  const float* svi1_b   = (const float*)d_in[7];
  const float* svi2_W   = (const float*)d_in[8];
  const float* svi2_b   = (const float*)d_in[9];
  const float* all1_W   = (const float*)d_in[10];
  const float* all1_b   = (const float*)d_in[11];
  const float* all2_W   = (const float*)d_in[12];
  const float* all2_b   = (const float*)d_in[13];
  const float* gat1_W   = (const float*)d_in[14];
  const float* gat1_b   = (const float*)d_in[15];
  const float* gat1_as  = (const float*)d_in[16];
  const float* gat1_ad  = (const float*)d_in[17];
  const float* gat2_W   = (const float*)d_in[18];
  const float* gat2_b   = (const float*)d_in[19];
  const float* gat2_as  = (const float*)d_in[20];
  const float* gat2_ad  = (const float*)d_in[21];
  const float* gat3_W   = (const float*)d_in[22];
  const float* gat3_b   = (const float*)d_in[23];
  const float* gat3_as  = (const float*)d_in[24];
  const float* gat3_ad  = (const float*)d_in[25];
  const float* lstm_Wih0= (const float*)d_in[26];
  const float* lstm_Wih = (const float*)d_in[27];
  const float* lstm_b   = (const float*)d_in[29];
  const float* time1_W  = (const float*)d_in[30];
  const float* time1_b  = (const float*)d_in[31];
  const float* time2_W  = (const float*)d_in[32];
  const float* time2_b  = (const float*)d_in[33];
  const float* lin1_W   = (const float*)d_in[34];
  const float* lin1_b   = (const float*)d_in[35];
  const float* lin2_W   = (const float*)d_in[36];
  const float* lin2_b   = (const float*)d_in[37];
  const float* lin3_W   = (const float*)d_in[38];
  const float* lin3_b   = (const float*)d_in[39];
  float* out = (float*)d_out;

  // ---- workspace layout ----
  float* wsf   = (float*)d_ws;
  float* R192  = wsf;
  float* RA    = R192 + (size_t)N * 192;
  float* RA2   = RA + (size_t)N * 64;
  float* RB    = RA + (size_t)N * 128;
  float* Rz    = RB + (size_t)N * 256;
  float* sArr  = Rz + (size_t)N * 128;
  float* tArr  = sArr + N;
  int* ints      = (int*)(tArr + N);
  int* row_start = ints;
  int* cursor    = row_start + (N + 1);
  int* srcs      = cursor + N;
  int* blockSums = srcs + Et;
  // bf16 W-split pool (~1 MB), 16B-aligned
  short* pool = (short*)(((uintptr_t)(blockSums + 256) + 15) & ~(uintptr_t)15);

  auto split = [&](const float* W, int K, int M) -> WSplit {
    int KC = (K + 31) / 32;
    size_t sz = (size_t)KC * M * 32;  // KC * (M/16) * 64 * 8
    short* hi = pool; pool += sz;
    short* lo = pool; pool += sz;
    hipLaunchKernelGGL(wsplit_kernel, dim3(KC, M / 16), dim3(64), 0, stream,
                       W, hi, lo, K, M);
    return {hi, lo};
  };
  auto gemm = [&](const float* A, int lda, WSplit w, const float* bias,
                  float* C, int ldc, int K, int M, int act) {
    hipLaunchKernelGGL(gemm_mfma, dim3(M / 64, N / 64), dim3(64), 0, stream,
                       A, lda, w.hi, w.lo, bias, C, ldc, K, (K + 31) / 32, M / 16, act);
  };

  // ---- pre-split all weights (graph-capture-safe: same work every call) ----
  WSplit wpoi1 = split(poi1_W, 13, 64);
  WSplit wpoi2 = split(poi2_W, 64, 64);
  WSplit wsvi1 = split(svi1_W, 365, 128);
  WSplit wsvi2 = split(svi2_W, 128, 128);
  WSplit wall1 = split(all1_W, 192, 128);
  WSplit wall2 = split(all2_W, 128, 128);
  WSplit wg1   = split(gat1_W, 128, 128);
  WSplit wg2   = split(gat2_W, 128, 128);
  WSplit wg3   = split(gat3_W, 128, 64);
  WSplit wls0  = split(lstm_Wih0, 24, 256);
  WSplit wls1  = split(lstm_Wih, 64, 256);
  WSplit wls2  = split(lstm_Wih + 64 * 256, 64, 256);
  WSplit wt1   = split(time1_W, 64, 64);
  WSplit wt2   = split(time2_W, 64, 64);
  WSplit wl1   = split(lin1_W, 128, 64);
  WSplit wl2   = split(lin2_W, 64, 64);

  const int TB = 256;
  const int edgeBlocks = (Et + TB - 1) / TB;

  // ---- build CSR (shared by all 3 GAT layers) ----
  hipLaunchKernelGGL(fill_i32_kernel, dim3((N + TB - 1) / TB), dim3(TB), 0, stream,
                     row_start, 0, N);
  hipLaunchKernelGGL(count_edges_kernel, dim3(edgeBlocks), dim3(TB), 0, stream,
                     ei, row_start, E, N);
  hipLaunchKernelGGL(scan1_kernel, dim3(N / 256), dim3(256), 0, stream,
                     row_start, blockSums);
  hipLaunchKernelGGL(scan2_kernel, dim3(1), dim3(256), 0, stream, blockSums);
  hipLaunchKernelGGL(scan3_kernel, dim3(N / 256), dim3(256), 0, stream,
                     row_start, cursor, blockSums, N, Et);
  hipLaunchKernelGGL(scatter_kernel, dim3(edgeBlocks), dim3(TB), 0, stream,
                     ei, cursor, srcs, E, N);

  // ---- MLP towers ----
  gemm(x + 3, 445, wpoi1, poi1_b, RA, 64, 13, 64, 1);
  gemm(RA, 64, wpoi2, poi2_b, R192, 192, 64, 64, 1);
  gemm(x + 56, 445, wsvi1, svi1_b, RB, 128, 365, 128, 1);
  gemm(RB, 128, wsvi2, svi2_b, R192 + 64, 192, 128, 128, 1);
  gemm(R192, 192, wall1, all1_b, RA, 128, 192, 128, 1);
  gemm(RA, 128, wall2, all2_b, RB, 128, 128, 128, 1);

  const int waveBlocks = N / 4;

  // ---- GAT1 ----
  gemm(RB, 128, wg1, nullptr, RA, 128, 128, 128, 0);
  hipLaunchKernelGGL(st_kernel, dim3(waveBlocks), dim3(256), 0, stream,
                     RA, gat1_as, gat1_ad, sArr, tArr, N, 128);
  hipLaunchKernelGGL((gat_aggregate<128>), dim3(waveBlocks), dim3(256), 0, stream,
                     RA, sArr, tArr, row_start, srcs, gat1_b, RB, 128, N);
  // ---- GAT2 ----
  gemm(RB, 128, wg2, nullptr, RA, 128, 128, 128, 0);
  hipLaunchKernelGGL(st_kernel, dim3(waveBlocks), dim3(256), 0, stream,
                     RA, gat2_as, gat2_ad, sArr, tArr, N, 128);
  hipLaunchKernelGGL((gat_aggregate<128>), dim3(waveBlocks), dim3(256), 0, stream,
                     RA, sArr, tArr, row_start, srcs, gat2_b, RB, 128, N);
  // ---- GAT3 (fo=64 -> Rz cols 0..63) ----
  gemm(RB, 128, wg3, nullptr, RA, 64, 128, 64, 0);
  hipLaunchKernelGGL(st_kernel, dim3(waveBlocks), dim3(256), 0, stream,
                     RA, gat3_as, gat3_ad, sArr, tArr, N, 64);
  hipLaunchKernelGGL((gat_aggregate<64>), dim3(waveBlocks), dim3(256), 0, stream,
                     RA, sArr, tArr, row_start, srcs, gat3_b, Rz, 128, N);

  // ---- "LSTM": only layers 0..2 matter (t = hs[2]) ----
  const int actBlocks = (N * 64 + TB - 1) / TB;
  gemm(x + 421, 445, wls0, lstm_b, RB, 256, 24, 256, 0);
  hipLaunchKernelGGL(lstm_act_kernel, dim3(actBlocks), dim3(TB), 0, stream, RB, RA, N);
  gemm(RA, 64, wls1, lstm_b + 256, RB, 256, 64, 256, 0);
  hipLaunchKernelGGL(lstm_act_kernel, dim3(actBlocks), dim3(TB), 0, stream, RB, RA2, N);
  gemm(RA2, 64, wls2, lstm_b + 512, RB, 256, 64, 256, 0);
  hipLaunchKernelGGL(lstm_act_kernel, dim3(actBlocks), dim3(TB), 0, stream, RB, RA, N);

  // ---- time MLP -> Rz cols 64..127 ----
  gemm(RA, 64, wt1, time1_b, RA2, 64, 64, 64, 1);
  gemm(RA2, 64, wt2, time2_b, Rz + 64, 128, 64, 64, 1);

  // ---- head ----
  gemm(Rz, 128, wl1, lin1_b, RA, 64, 128, 64, 1);
  gemm(RA, 64, wl2, lin2_b, RA2, 64, 64, 64, 1);
  hipLaunchKernelGGL(lin3_kernel, dim3((N + TB - 1) / TB), dim3(TB), 0, stream,
                     RA2, lin3_W, lin3_b, out, N);
}

// Round 7
// 997.222 us; speedup vs baseline: 2.1431x; 1.1297x over previous
//
#include <hip/hip_runtime.h>
#include <math.h>

#define DEV __device__ __forceinline__

typedef __attribute__((ext_vector_type(8))) short short8;   // 8 bf16 (4 VGPRs)
typedef __attribute__((ext_vector_type(4))) float f32x4;    // MFMA acc
typedef float f32x4u __attribute__((ext_vector_type(4), aligned(4)));

// finite "minus infinity": avoids -INF - -INF = NaN in online-softmax combine
#define NEG_BIG (-3.0e38f)

DEV float sigm(float x) { return 1.0f / (1.0f + __expf(-x)); }

// split 8 fp32 -> bf16 hi (truncate) + bf16 lo (truncate of exact residual)
DEV void split_bf16(const float f[8], short8& hi, short8& lo) {
#pragma unroll
  for (int i = 0; i < 8; ++i) {
    unsigned u = __builtin_bit_cast(unsigned, f[i]);
    hi[i] = (short)(u >> 16);
    float h = __builtin_bit_cast(float, u & 0xffff0000u);
    float r = f[i] - h;  // exact (Dekker)
    lo[i] = (short)(__builtin_bit_cast(unsigned, r) >> 16);
  }
}

// ============================ utility kernels ============================

__global__ void fill_i32_kernel(int* p, int v, int n) {
  int i = blockIdx.x * blockDim.x + threadIdx.x;
  if (i < n) p[i] = v;
}

__global__ void count_edges_kernel(const int* __restrict__ ei, int* __restrict__ cnt,
                                   int E, int N) {
  int e = blockIdx.x * blockDim.x + threadIdx.x;
  if (e >= E + N) return;
  int d = (e < E) ? ei[E + e] : (e - E);
  atomicAdd(&cnt[d], 1);
}

__global__ void scan1_kernel(int* data, int* blockSums) {
  __shared__ int sh[256];
  int tid = threadIdx.x;
  int gid = blockIdx.x * 256 + tid;
  int v = data[gid];
  sh[tid] = v;
  __syncthreads();
  int val = v;
  for (int off = 1; off < 256; off <<= 1) {
    int add = (tid >= off) ? sh[tid - off] : 0;
    __syncthreads();
    val += add;
    sh[tid] = val;
    __syncthreads();
  }
  data[gid] = val - v;
  if (tid == 255) blockSums[blockIdx.x] = val;
}

__global__ void scan2_kernel(int* blockSums) {
  __shared__ int sh[256];
  int tid = threadIdx.x;
  int v = blockSums[tid];
  sh[tid] = v;
  __syncthreads();
  int val = v;
  for (int off = 1; off < 256; off <<= 1) {
    int add = (tid >= off) ? sh[tid - off] : 0;
    __syncthreads();
    val += add;
    sh[tid] = val;
    __syncthreads();
  }
  blockSums[tid] = val - v;
}

__global__ void scan3_kernel(int* row_start, int* cursor, const int* blockOff,
                             int N, int Et) {
  int tid = threadIdx.x;
  int gid = blockIdx.x * 256 + tid;
  int v = row_start[gid] + blockOff[blockIdx.x];
  row_start[gid] = v;
  cursor[gid] = v;
  if (gid == 0) row_start[N] = Et;
}

__global__ void scatter_kernel(const int* __restrict__ ei, int* __restrict__ cursor,
                               int* __restrict__ srcs, int E, int N) {
  int e = blockIdx.x * blockDim.x + threadIdx.x;
  if (e >= E + N) return;
  int s, d;
  if (e < E) { s = ei[e]; d = ei[E + e]; } else { s = e - E; d = e - E; }
  int pos = atomicAdd(&cursor[d], 1);
  srcs[pos] = s;
}

// ============================ W pre-split ============================
__global__ void wsplit_kernel(const float* __restrict__ W,
                              short* __restrict__ hi, short* __restrict__ lo,
                              int K, int M) {
  int lane = threadIdx.x;
  int kc = blockIdx.x, ntG = blockIdx.y;
  int kb = kc * 32 + (lane >> 4) * 8;
  int c = ntG * 16 + (lane & 15);
  float f[8];
#pragma unroll
  for (int j = 0; j < 8; ++j) {
    int k = kb + j;
    f[j] = (k < K) ? W[(long long)k * M + c] : 0.0f;
  }
  short8 h, l;
  split_bf16(f, h, l);
  long long off = (((long long)kc * gridDim.y + ntG) * 64 + lane) * 8;
  *(short8*)(hi + off) = h;
  *(short8*)(lo + off) = l;
}

// ============================ MFMA GEMM ============================
// One wave per block, 64x64 C-tile, 3-term bf16-split product, no LDS.
// 1D grid with XCD swizzle: blocks sharing A rows (same y, different x)
// are 8 apart in blockIdx -> same XCD (round-robin heuristic) -> A re-read
// hits that XCD's L2.
__global__ __launch_bounds__(64) void gemm_mfma(
    const float* __restrict__ A, int lda,
    const short* __restrict__ wh, const short* __restrict__ wl,
    const float* __restrict__ bias,
    float* __restrict__ C, int ldc,
    int K, int KC, int M16, int gx, int act) {
  const int lane = threadIdx.x;
  const int m = lane & 15, q = lane >> 4;
  const int b = blockIdx.x;
  const int x = (b >> 3) % gx;
  const int y = ((b >> 3) / gx) * 8 + (b & 7);
  const long long r0 = (long long)y * 64;
  const int ntG0 = x * 4;

  f32x4 acc[4][4];
#pragma unroll
  for (int i = 0; i < 4; ++i)
#pragma unroll
    for (int j = 0; j < 4; ++j) acc[i][j] = (f32x4)(0.0f);

  for (int kc = 0; kc < KC; ++kc) {
    short8 bh[4], bl[4];
#pragma unroll
    for (int nt = 0; nt < 4; ++nt) {
      long long off = (((long long)kc * M16 + (ntG0 + nt)) * 64 + lane) * 8;
      bh[nt] = *(const short8*)(wh + off);
      bl[nt] = *(const short8*)(wl + off);
    }
    short8 ah[4], al[4];
    const bool full = (kc * 32 + 32 <= K);
#pragma unroll
    for (int mt = 0; mt < 4; ++mt) {
      const float* ap = A + (r0 + mt * 16 + m) * lda + kc * 32 + q * 8;
      float f[8];
      if (full) {
        f32x4u p0 = *(const f32x4u*)ap;
        f32x4u p1 = *(const f32x4u*)(ap + 4);
#pragma unroll
        for (int j = 0; j < 4; ++j) { f[j] = p0[j]; f[4 + j] = p1[j]; }
      } else {
#pragma unroll
        for (int j = 0; j < 8; ++j) {
          int k = kc * 32 + q * 8 + j;
          f[j] = (k < K) ? ap[j] : 0.0f;
        }
      }
      split_bf16(f, ah[mt], al[mt]);
    }
#pragma unroll
    for (int mt = 0; mt < 4; ++mt)
#pragma unroll
      for (int nt = 0; nt < 4; ++nt) {
        acc[mt][nt] = __builtin_amdgcn_mfma_f32_16x16x32_bf16(ah[mt], bh[nt], acc[mt][nt], 0, 0, 0);
        acc[mt][nt] = __builtin_amdgcn_mfma_f32_16x16x32_bf16(ah[mt], bl[nt], acc[mt][nt], 0, 0, 0);
        acc[mt][nt] = __builtin_amdgcn_mfma_f32_16x16x32_bf16(al[mt], bh[nt], acc[mt][nt], 0, 0, 0);
      }
  }

#pragma unroll
  for (int nt = 0; nt < 4; ++nt) {
    int col = (ntG0 + nt) * 16 + m;
    float bsv = bias ? bias[col] : 0.0f;
#pragma unroll
    for (int mt = 0; mt < 4; ++mt) {
      long long rb = r0 + mt * 16 + q * 4;
#pragma unroll
      for (int reg = 0; reg < 4; ++reg) {
        float v = acc[mt][nt][reg] + bsv;
        if (act == 1) v = fmaxf(v, 0.0f);
        C[(rb + reg) * ldc + col] = v;
      }
    }
  }
}

// ============================ GAT helpers ============================

// s,t dot products: float4 loads, FO/4 lanes per node, 64/(FO/4) nodes/wave
template <int FO>
__global__ __launch_bounds__(256) void st_kernel(
    const float* __restrict__ G, const float* __restrict__ asrc,
    const float* __restrict__ adst, float* __restrict__ s, float* __restrict__ t,
    int N) {
  constexpr int LPN = FO / 4;      // lanes per node
  int wv = (blockIdx.x * blockDim.x + threadIdx.x) >> 6;
  int lane = threadIdx.x & 63;
  int sub = lane / LPN, cl = lane % LPN;
  long long node = (long long)wv * (64 / LPN) + sub;
  f32x4u g = *(const f32x4u*)(G + node * FO + cl * 4);
  f32x4u a = *(const f32x4u*)(asrc + cl * 4);
  f32x4u ad = *(const f32x4u*)(adst + cl * 4);
  float ps = g[0] * a[0] + g[1] * a[1] + g[2] * a[2] + g[3] * a[3];
  float pt = g[0] * ad[0] + g[1] * ad[1] + g[2] * ad[2] + g[3] * ad[3];
#pragma unroll
  for (int off = LPN / 2; off; off >>= 1) {
    ps += __shfl_xor(ps, off, 64);
    pt += __shfl_xor(pt, off, 64);
  }
  if (cl == 0) { s[node] = ps; t[node] = pt; }
}

// wave per dst: online-softmax sweep (max+denom in ONE pass) + alpha write.
// m starts at NEG_BIG (finite!) so empty-lane combines give exp(0), not
// exp(-INF - -INF) = NaN  [round-6 bug: NaN -> relu flushed to 0 -> absmax 2e-2]
__global__ __launch_bounds__(256) void agg_softmax(
    const float* __restrict__ s, const float* __restrict__ t,
    const int* __restrict__ row_start, const int* __restrict__ srcs,
    float* __restrict__ alpha, int N) {
  int d = (blockIdx.x * blockDim.x + threadIdx.x) >> 6;
  int lane = threadIdx.x & 63;
  int start = row_start[d], end = row_start[d + 1];
  float td = t[d];

  float m = NEG_BIG, dsum = 0.0f;
  for (int j = start + lane; j < end; j += 64) {
    float e = s[srcs[j]] + td;
    e = (e >= 0.0f) ? e : 0.2f * e;
    float mn = fmaxf(m, e);
    dsum = dsum * __expf(m - mn) + __expf(e - mn);
    m = mn;
  }
#pragma unroll
  for (int off = 32; off; off >>= 1) {
    float mo = __shfl_xor(m, off, 64);
    float dso = __shfl_xor(dsum, off, 64);
    float mn = fmaxf(m, mo);
    dsum = dsum * __expf(m - mn) + dso * __expf(mo - mn);
    m = mn;
  }
  float inv = 1.0f / dsum;

  for (int j = start + lane; j < end; j += 64) {
    float e = s[srcs[j]] + td;
    e = (e >= 0.0f) ? e : 0.2f * e;
    alpha[j] = __expf(e - m) * inv;
  }
}

// wave per dst: out[d] = relu(sum_j alpha[j]*G[src[j]] + bias).
// float4 gathers; 64/(FO/4) edges in flight per wave; shfl combine.
template <int FO>
__global__ __launch_bounds__(256) void agg_gather(
    const float* __restrict__ G, const float* __restrict__ alpha,
    const int* __restrict__ row_start, const int* __restrict__ srcs,
    const float* __restrict__ bias, float* __restrict__ out, int ldc, int N) {
  constexpr int LPE = FO / 4;      // lanes per edge
  constexpr int EPW = 64 / LPE;    // edges in flight
  int d = (blockIdx.x * blockDim.x + threadIdx.x) >> 6;
  int lane = threadIdx.x & 63;
  int grp = lane / LPE, cl = lane % LPE;
  int start = row_start[d], end = row_start[d + 1];

  float a0 = 0.0f, a1 = 0.0f, a2 = 0.0f, a3 = 0.0f;
  for (int j = start + grp; j < end; j += EPW) {
    int src = srcs[j];
    float al = alpha[j];
    f32x4u g = *(const f32x4u*)(G + (long long)src * FO + cl * 4);
    a0 = fmaf(al, g[0], a0);
    a1 = fmaf(al, g[1], a1);
    a2 = fmaf(al, g[2], a2);
    a3 = fmaf(al, g[3], a3);
  }
#pragma unroll
  for (int off = 32; off >= LPE; off >>= 1) {
    a0 += __shfl_xor(a0, off, 64);
    a1 += __shfl_xor(a1, off, 64);
    a2 += __shfl_xor(a2, off, 64);
    a3 += __shfl_xor(a3, off, 64);
  }
  if (grp == 0) {
    f32x4u bs = *(const f32x4u*)(bias + cl * 4);
    f32x4u v;
    v[0] = fmaxf(a0 + bs[0], 0.0f);
    v[1] = fmaxf(a1 + bs[1], 0.0f);
    v[2] = fmaxf(a2 + bs[2], 0.0f);
    v[3] = fmaxf(a3 + bs[3], 0.0f);
    *(f32x4u*)(out + (long long)d * ldc + cl * 4) = v;
  }
}

// ============================ LSTM / head ============================

__global__ void lstm_act_kernel(const float* __restrict__ gates,
                                float* __restrict__ h, int N) {
  int idx = blockIdx.x * blockDim.x + threadIdx.x;
  if (idx >= N * 64) return;
  int i = idx >> 6, c = idx & 63;
  const float* g = gates + (long long)i * 256;
  float gi = g[c], gg = g[128 + c], go = g[192 + c];
  float cc = sigm(gi) * tanhf(gg);
  h[idx] = sigm(go) * tanhf(cc);
}

__global__ void lin3_kernel(const float* __restrict__ Z, const float* __restrict__ w,
                            const float* __restrict__ b, float* __restrict__ out, int N) {
  int i = blockIdx.x * blockDim.x + threadIdx.x;
  if (i >= N) return;
  const float4* z4 = (const float4*)(Z + (long long)i * 64);
  const float4* w4 = (const float4*)w;
  float acc = 0.0f;
#pragma unroll
  for (int k = 0; k < 16; ++k) {
    float4 a = z4[k], ww = w4[k];
    acc += a.x * ww.x + a.y * ww.y + a.z * ww.z + a.w * ww.w;
  }
  out[i] = acc + b[0];
}

// ============================ launcher ============================

struct WSplit { const short* hi; const short* lo; };

extern "C" void kernel_launch(void* const* d_in, const int* in_sizes, int n_in,
                              void* d_out, int out_size, void* d_ws, size_t ws_size,
                              hipStream_t stream) {
  const int N = 65536, E = 1048576;
  const int Et = E + N;

  const float* x        = (const float*)d_in[0];
  const int*   ei       = (const int*)d_in[1];
  const float* poi1_W   = (const float*)d_in[2];
  const float* poi1_b   = (const float*)d_in[3];
  const float* poi2_W   = (const float*)d_in[4];
  const float* poi2_b   = (const float*)d_in[5];
  const float* svi1_W   = (const float*)d_in[6];
  const float* svi1_b   = (const float*)d_in[7];
  const float* svi2_W   = (const float*)d_in[8];
  const float* svi2_b   = (const float*)d_in[9];
  const float* all1_W   = (const float*)d_in[10];
  const float* all1_b   = (const float*)d_in[11];
  const float* all2_W   = (const float*)d_in[12];
  const float* all2_b   = (const float*)d_in[13];
  const float* gat1_W   = (const float*)d_in[14];
  const float* gat1_b   = (const float*)d_in[15];
  const float* gat1_as  = (const float*)d_in[16];
  const float* gat1_ad  = (const float*)d_in[17];
  const float* gat2_W   = (const float*)d_in[18];
  const float* gat2_b   = (const float*)d_in[19];
  const float* gat2_as  = (const float*)d_in[20];
  const float* gat2_ad  = (const float*)d_in[21];
  const float* gat3_W   = (const float*)d_in[22];
  const float* gat3_b   = (const float*)d_in[23];
  const float* gat3_as  = (const float*)d_in[24];
  const float* gat3_ad  = (const float*)d_in[25];
  const float* lstm_Wih0= (const float*)d_in[26];
  const float* lstm_Wih = (const float*)d_in[27];
  const float* lstm_b   = (const float*)d_in[29];
  const float* time1_W  = (const float*)d_in[30];
  const float* time1_b  = (const float*)d_in[31];
  const float* time2_W  = (const float*)d_in[32];
  const float* time2_b  = (const float*)d_in[33];
  const float* lin1_W   = (const float*)d_in[34];
  const float* lin1_b   = (const float*)d_in[35];
  const float* lin2_W   = (const float*)d_in[36];
  const float* lin2_b   = (const float*)d_in[37];
  const float* lin3_W   = (const float*)d_in[38];
  const float* lin3_b   = (const float*)d_in[39];
  float* out = (float*)d_out;

  // ---- workspace layout ----
  float* wsf   = (float*)d_ws;
  float* R192  = wsf;
  float* RA    = R192 + (size_t)N * 192;
  float* RA2   = RA + (size_t)N * 64;
  float* RB    = RA + (size_t)N * 128;
  float* Rz    = RB + (size_t)N * 256;
  float* sArr  = Rz + (size_t)N * 128;
  float* tArr  = sArr + N;
  float* alphaArr = tArr + N;               // Et
  int* ints      = (int*)(alphaArr + Et);
  int* row_start = ints;
  int* cursor    = row_start + (N + 1);
  int* srcs      = cursor + N;
  int* blockSums = srcs + Et;
  short* pool = (short*)(((uintptr_t)(blockSums + 256) + 15) & ~(uintptr_t)15);

  auto split = [&](const float* W, int K, int M) -> WSplit {
    int KC = (K + 31) / 32;
    size_t sz = (size_t)KC * M * 32;
    short* hi = pool; pool += sz;
    short* lo = pool; pool += sz;
    hipLaunchKernelGGL(wsplit_kernel, dim3(KC, M / 16), dim3(64), 0, stream,
                       W, hi, lo, K, M);
    return {hi, lo};
  };
  auto gemm = [&](const float* A, int lda, WSplit w, const float* bias,
                  float* C, int ldc, int K, int M, int act) {
    int gx = M / 64;
    hipLaunchKernelGGL(gemm_mfma, dim3(gx * (N / 64)), dim3(64), 0, stream,
                       A, lda, w.hi, w.lo, bias, C, ldc, K, (K + 31) / 32,
                       M / 16, gx, act);
  };

  // ---- pre-split all weights ----
  WSplit wpoi1 = split(poi1_W, 13, 64);
  WSplit wpoi2 = split(poi2_W, 64, 64);
  WSplit wsvi1 = split(svi1_W, 365, 128);
  WSplit wsvi2 = split(svi2_W, 128, 128);
  WSplit wall1 = split(all1_W, 192, 128);
  WSplit wall2 = split(all2_W, 128, 128);
  WSplit wg1   = split(gat1_W, 128, 128);
  WSplit wg2   = split(gat2_W, 128, 128);
  WSplit wg3   = split(gat3_W, 128, 64);
  WSplit wls0  = split(lstm_Wih0, 24, 256);
  WSplit wls1  = split(lstm_Wih, 64, 256);
  WSplit wls2  = split(lstm_Wih + 64 * 256, 64, 256);
  WSplit wt1   = split(time1_W, 64, 64);
  WSplit wt2   = split(time2_W, 64, 64);
  WSplit wl1   = split(lin1_W, 128, 64);
  WSplit wl2   = split(lin2_W, 64, 64);

  const int TB = 256;
  const int edgeBlocks = (Et + TB - 1) / TB;

  // ---- build CSR ----
  hipLaunchKernelGGL(fill_i32_kernel, dim3((N + TB - 1) / TB), dim3(TB), 0, stream,
                     row_start, 0, N);
  hipLaunchKernelGGL(count_edges_kernel, dim3(edgeBlocks), dim3(TB), 0, stream,
                     ei, row_start, E, N);
  hipLaunchKernelGGL(scan1_kernel, dim3(N / 256), dim3(256), 0, stream,
                     row_start, blockSums);
  hipLaunchKernelGGL(scan2_kernel, dim3(1), dim3(256), 0, stream, blockSums);
  hipLaunchKernelGGL(scan3_kernel, dim3(N / 256), dim3(256), 0, stream,
                     row_start, cursor, blockSums, N, Et);
  hipLaunchKernelGGL(scatter_kernel, dim3(edgeBlocks), dim3(TB), 0, stream,
                     ei, cursor, srcs, E, N);

  // ---- MLP towers ----
  gemm(x + 3, 445, wpoi1, poi1_b, RA, 64, 13, 64, 1);
  gemm(RA, 64, wpoi2, poi2_b, R192, 192, 64, 64, 1);
  gemm(x + 56, 445, wsvi1, svi1_b, RB, 128, 365, 128, 1);
  gemm(RB, 128, wsvi2, svi2_b, R192 + 64, 192, 128, 128, 1);
  gemm(R192, 192, wall1, all1_b, RA, 128, 192, 128, 1);
  gemm(RA, 128, wall2, all2_b, RB, 128, 128, 128, 1);

  const int aggBlocks = N / 4;  // wave per dst, 4 waves/block

  // ---- GAT1 ----
  gemm(RB, 128, wg1, nullptr, RA, 128, 128, 128, 0);
  hipLaunchKernelGGL((st_kernel<128>), dim3(N / 8), dim3(256), 0, stream,
                     RA, gat1_as, gat1_ad, sArr, tArr, N);
  hipLaunchKernelGGL(agg_softmax, dim3(aggBlocks), dim3(256), 0, stream,
                     sArr, tArr, row_start, srcs, alphaArr, N);
  hipLaunchKernelGGL((agg_gather<128>), dim3(aggBlocks), dim3(256), 0, stream,
                     RA, alphaArr, row_start, srcs, gat1_b, RB, 128, N);
  // ---- GAT2 ----
  gemm(RB, 128, wg2, nullptr, RA, 128, 128, 128, 0);
  hipLaunchKernelGGL((st_kernel<128>), dim3(N / 8), dim3(256), 0, stream,
                     RA, gat2_as, gat2_ad, sArr, tArr, N);
  hipLaunchKernelGGL(agg_softmax, dim3(aggBlocks), dim3(256), 0, stream,
                     sArr, tArr, row_start, srcs, alphaArr, N);
  hipLaunchKernelGGL((agg_gather<128>), dim3(aggBlocks), dim3(256), 0, stream,
                     RA, alphaArr, row_start, srcs, gat2_b, RB, 128, N);
  // ---- GAT3 (fo=64 -> Rz cols 0..63) ----
  gemm(RB, 128, wg3, nullptr, RA, 64, 128, 64, 0);
  hipLaunchKernelGGL((st_kernel<64>), dim3(N / 16), dim3(256), 0, stream,
                     RA, gat3_as, gat3_ad, sArr, tArr, N);
  hipLaunchKernelGGL(agg_softmax, dim3(aggBlocks), dim3(256), 0, stream,
                     sArr, tArr, row_start, srcs, alphaArr, N);
  hipLaunchKernelGGL((agg_gather<64>), dim3(aggBlocks), dim3(256), 0, stream,
                     RA, alphaArr, row_start, srcs, gat3_b, Rz, 128, N);

  // ---- "LSTM": only layers 0..2 matter (t = hs[2]) ----
  const int actBlocks = (N * 64 + TB - 1) / TB;
  gemm(x + 421, 445, wls0, lstm_b, RB, 256, 24, 256, 0);
  hipLaunchKernelGGL(lstm_act_kernel, dim3(actBlocks), dim3(TB), 0, stream, RB, RA, N);
  gemm(RA, 64, wls1, lstm_b + 256, RB, 256, 64, 256, 0);
  hipLaunchKernelGGL(lstm_act_kernel, dim3(actBlocks), dim3(TB), 0, stream, RB, RA2, N);
  gemm(RA2, 64, wls2, lstm_b + 512, RB, 256, 64, 256, 0);
  hipLaunchKernelGGL(lstm_act_kernel, dim3(actBlocks), dim3(TB), 0, stream, RB, RA, N);

  // ---- time MLP -> Rz cols 64..127 ----
  gemm(RA, 64, wt1, time1_b, RA2, 64, 64, 64, 1);
  gemm(RA2, 64, wt2, time2_b, Rz + 64, 128, 64, 64, 1);

  // ---- head ----
  gemm(Rz, 128, wl1, lin1_b, RA, 64, 128, 64, 1);
  gemm(RA, 64, wl2, lin2_b, RA2, 64, 64, 64, 1);
  hipLaunchKernelGGL(lin3_kernel, dim3((N + TB - 1) / TB), dim3(TB), 0, stream,
                     RA2, lin3_W, lin3_b, out, N);
}

// Round 8
// 978.359 us; speedup vs baseline: 2.1844x; 1.0193x over previous
//
#include <hip/hip_runtime.h>
#include <math.h>

#define DEV __device__ __forceinline__

typedef __attribute__((ext_vector_type(8))) short short8;   // 8 bf16 (4 VGPRs)
typedef __attribute__((ext_vector_type(4))) float f32x4;    // MFMA acc
typedef float f32x4u __attribute__((ext_vector_type(4), aligned(4)));

// finite "minus infinity": avoids -INF - -INF = NaN in online-softmax combine
#define NEG_BIG (-3.0e38f)

DEV float sigm(float x) { return 1.0f / (1.0f + __expf(-x)); }

// split 8 fp32 -> bf16 hi (truncate) + bf16 lo (truncate of exact residual)
DEV void split_bf16(const float f[8], short8& hi, short8& lo) {
#pragma unroll
  for (int i = 0; i < 8; ++i) {
    unsigned u = __builtin_bit_cast(unsigned, f[i]);
    hi[i] = (short)(u >> 16);
    float h = __builtin_bit_cast(float, u & 0xffff0000u);
    float r = f[i] - h;  // exact (Dekker)
    lo[i] = (short)(__builtin_bit_cast(unsigned, r) >> 16);
  }
}

// ============================ utility kernels ============================

__global__ void fill_i32_kernel(int* p, int v, int n) {
  int i = blockIdx.x * blockDim.x + threadIdx.x;
  if (i < n) p[i] = v;
}

__global__ void count_edges_kernel(const int* __restrict__ ei, int* __restrict__ cnt,
                                   int E, int N) {
  int e = blockIdx.x * blockDim.x + threadIdx.x;
  if (e >= E + N) return;
  int d = (e < E) ? ei[E + e] : (e - E);
  atomicAdd(&cnt[d], 1);
}

__global__ void scan1_kernel(int* data, int* blockSums) {
  __shared__ int sh[256];
  int tid = threadIdx.x;
  int gid = blockIdx.x * 256 + tid;
  int v = data[gid];
  sh[tid] = v;
  __syncthreads();
  int val = v;
  for (int off = 1; off < 256; off <<= 1) {
    int add = (tid >= off) ? sh[tid - off] : 0;
    __syncthreads();
    val += add;
    sh[tid] = val;
    __syncthreads();
  }
  data[gid] = val - v;
  if (tid == 255) blockSums[blockIdx.x] = val;
}

__global__ void scan2_kernel(int* blockSums) {
  __shared__ int sh[256];
  int tid = threadIdx.x;
  int v = blockSums[tid];
  sh[tid] = v;
  __syncthreads();
  int val = v;
  for (int off = 1; off < 256; off <<= 1) {
    int add = (tid >= off) ? sh[tid - off] : 0;
    __syncthreads();
    val += add;
    sh[tid] = val;
    __syncthreads();
  }
  blockSums[tid] = val - v;
}

__global__ void scan3_kernel(int* row_start, int* cursor, const int* blockOff,
                             int N, int Et) {
  int tid = threadIdx.x;
  int gid = blockIdx.x * 256 + tid;
  int v = row_start[gid] + blockOff[blockIdx.x];
  row_start[gid] = v;
  cursor[gid] = v;
  if (gid == 0) row_start[N] = Et;
}

__global__ void scatter_kernel(const int* __restrict__ ei, int* __restrict__ cursor,
                               int* __restrict__ srcs, int E, int N) {
  int e = blockIdx.x * blockDim.x + threadIdx.x;
  if (e >= E + N) return;
  int s, d;
  if (e < E) { s = ei[e]; d = ei[E + e]; } else { s = e - E; d = e - E; }
  int pos = atomicAdd(&cursor[d], 1);
  srcs[pos] = s;
}

// ============================ fused W pre-split ============================
// All 16 weight matrices split/packed in ONE launch (16 separate tiny
// launches cost ~40us of launch overhead). Job table passed by value.
struct WJobs {
  const float* W[16];
  short* hi[16];
  short* lo[16];
  int K[16];
  int M16[16];
  int tile0[16];
};

__global__ __launch_bounds__(64) void wsplit_all(WJobs jb, int njobs) {
  int b = blockIdx.x;
  int ji = 0;
#pragma unroll
  for (int i = 1; i < 16; ++i)
    if (i < njobs && b >= jb.tile0[i]) ji = i;
  int t = b - jb.tile0[ji];
  int M16 = jb.M16[ji];
  int kc = t / M16, ntG = t % M16;
  int K = jb.K[ji], M = M16 * 16;
  const float* __restrict__ W = jb.W[ji];

  int lane = threadIdx.x;
  int kb = kc * 32 + (lane >> 4) * 8;
  int c = ntG * 16 + (lane & 15);
  float f[8];
#pragma unroll
  for (int j = 0; j < 8; ++j) {
    int k = kb + j;
    f[j] = (k < K) ? W[(long long)k * M + c] : 0.0f;
  }
  short8 h, l;
  split_bf16(f, h, l);
  long long off = ((long long)t * 64 + lane) * 8;  // t == kc*M16 + ntG
  *(short8*)(jb.hi[ji] + off) = h;
  *(short8*)(jb.lo[ji] + off) = l;
}

// ============================ MFMA GEMM ============================
// One wave per block, 64x64 C-tile, 3-term bf16-split product, no LDS.
__global__ __launch_bounds__(64) void gemm_mfma(
    const float* __restrict__ A, int lda,
    const short* __restrict__ wh, const short* __restrict__ wl,
    const float* __restrict__ bias,
    float* __restrict__ C, int ldc,
    int K, int KC, int M16, int gx, int act) {
  const int lane = threadIdx.x;
  const int m = lane & 15, q = lane >> 4;
  const int b = blockIdx.x;
  const int x = (b >> 3) % gx;
  const int y = ((b >> 3) / gx) * 8 + (b & 7);
  const long long r0 = (long long)y * 64;
  const int ntG0 = x * 4;

  f32x4 acc[4][4];
#pragma unroll
  for (int i = 0; i < 4; ++i)
#pragma unroll
    for (int j = 0; j < 4; ++j) acc[i][j] = (f32x4)(0.0f);

  for (int kc = 0; kc < KC; ++kc) {
    short8 bh[4], bl[4];
#pragma unroll
    for (int nt = 0; nt < 4; ++nt) {
      long long off = (((long long)kc * M16 + (ntG0 + nt)) * 64 + lane) * 8;
      bh[nt] = *(const short8*)(wh + off);
      bl[nt] = *(const short8*)(wl + off);
    }
    short8 ah[4], al[4];
    const bool full = (kc * 32 + 32 <= K);
#pragma unroll
    for (int mt = 0; mt < 4; ++mt) {
      const float* ap = A + (r0 + mt * 16 + m) * lda + kc * 32 + q * 8;
      float f[8];
      if (full) {
        f32x4u p0 = *(const f32x4u*)ap;
        f32x4u p1 = *(const f32x4u*)(ap + 4);
#pragma unroll
        for (int j = 0; j < 4; ++j) { f[j] = p0[j]; f[4 + j] = p1[j]; }
      } else {
#pragma unroll
        for (int j = 0; j < 8; ++j) {
          int k = kc * 32 + q * 8 + j;
          f[j] = (k < K) ? ap[j] : 0.0f;
        }
      }
      split_bf16(f, ah[mt], al[mt]);
    }
#pragma unroll
    for (int mt = 0; mt < 4; ++mt)
#pragma unroll
      for (int nt = 0; nt < 4; ++nt) {
        acc[mt][nt] = __builtin_amdgcn_mfma_f32_16x16x32_bf16(ah[mt], bh[nt], acc[mt][nt], 0, 0, 0);
        acc[mt][nt] = __builtin_amdgcn_mfma_f32_16x16x32_bf16(ah[mt], bl[nt], acc[mt][nt], 0, 0, 0);
        acc[mt][nt] = __builtin_amdgcn_mfma_f32_16x16x32_bf16(al[mt], bh[nt], acc[mt][nt], 0, 0, 0);
      }
  }

#pragma unroll
  for (int nt = 0; nt < 4; ++nt) {
    int col = (ntG0 + nt) * 16 + m;
    float bsv = bias ? bias[col] : 0.0f;
#pragma unroll
    for (int mt = 0; mt < 4; ++mt) {
      long long rb = r0 + mt * 16 + q * 4;
#pragma unroll
      for (int reg = 0; reg < 4; ++reg) {
        float v = acc[mt][nt][reg] + bsv;
        if (act == 1) v = fmaxf(v, 0.0f);
        C[(rb + reg) * ldc + col] = v;
      }
    }
  }
}

// ============================ GAT helpers ============================

// s,t dot products: float4 loads, FO/4 lanes per node, 64/(FO/4) nodes/wave
template <int FO>
__global__ __launch_bounds__(256) void st_kernel(
    const float* __restrict__ G, const float* __restrict__ asrc,
    const float* __restrict__ adst, float* __restrict__ s, float* __restrict__ t,
    int N) {
  constexpr int LPN = FO / 4;
  int wv = (blockIdx.x * blockDim.x + threadIdx.x) >> 6;
  int lane = threadIdx.x & 63;
  int sub = lane / LPN, cl = lane % LPN;
  long long node = (long long)wv * (64 / LPN) + sub;
  f32x4u g = *(const f32x4u*)(G + node * FO + cl * 4);
  f32x4u a = *(const f32x4u*)(asrc + cl * 4);
  f32x4u ad = *(const f32x4u*)(adst + cl * 4);
  float ps = g[0] * a[0] + g[1] * a[1] + g[2] * a[2] + g[3] * a[3];
  float pt = g[0] * ad[0] + g[1] * ad[1] + g[2] * ad[2] + g[3] * ad[3];
#pragma unroll
  for (int off = LPN / 2; off; off >>= 1) {
    ps += __shfl_xor(ps, off, 64);
    pt += __shfl_xor(pt, off, 64);
  }
  if (cl == 0) { s[node] = ps; t[node] = pt; }
}

// wave per dst: online-softmax sweep + alpha write (m starts finite: NEG_BIG)
__global__ __launch_bounds__(256) void agg_softmax(
    const float* __restrict__ s, const float* __restrict__ t,
    const int* __restrict__ row_start, const int* __restrict__ srcs,
    float* __restrict__ alpha, int N) {
  int d = (blockIdx.x * blockDim.x + threadIdx.x) >> 6;
  int lane = threadIdx.x & 63;
  int start = row_start[d], end = row_start[d + 1];
  float td = t[d];

  float m = NEG_BIG, dsum = 0.0f;
  for (int j = start + lane; j < end; j += 64) {
    float e = s[srcs[j]] + td;
    e = (e >= 0.0f) ? e : 0.2f * e;
    float mn = fmaxf(m, e);
    dsum = dsum * __expf(m - mn) + __expf(e - mn);
    m = mn;
  }
#pragma unroll
  for (int off = 32; off; off >>= 1) {
    float mo = __shfl_xor(m, off, 64);
    float dso = __shfl_xor(dsum, off, 64);
    float mn = fmaxf(m, mo);
    dsum = dsum * __expf(m - mn) + dso * __expf(mo - mn);
    m = mn;
  }
  float inv = 1.0f / dsum;

  for (int j = start + lane; j < end; j += 64) {
    float e = s[srcs[j]] + td;
    e = (e >= 0.0f) ? e : 0.2f * e;
    alpha[j] = __expf(e - m) * inv;
  }
}

// XCD feature-partitioned gather: each block handles COLS=32 columns;
// split = blockIdx % NSPLIT, so under round-robin blockIdx%8 -> XCD mapping
// each XCD touches only a 32-col slice of G (8 MB vs 32 MB working set).
// 8 lanes/edge -> 8 independent edge-gathers in flight per wave, 2x unrolled.
template <int FO, int NSPLIT>
__global__ __launch_bounds__(256) void agg_gather(
    const float* __restrict__ G, const float* __restrict__ alpha,
    const int* __restrict__ row_start, const int* __restrict__ srcs,
    const float* __restrict__ bias, float* __restrict__ out, int ldc, int N) {
  constexpr int COLS = 32;           // FO / NSPLIT
  constexpr int LPE = COLS / 4;      // 8 lanes per edge
  constexpr int EPW = 64 / LPE;      // 8 edges in flight
  const int b = blockIdx.x;
  const int split = b & (NSPLIT - 1);
  const int d = (b / NSPLIT) * 4 + (threadIdx.x >> 6);
  const int colOff = split * COLS;
  const int lane = threadIdx.x & 63;
  const int grp = lane / LPE, cl = lane % LPE;
  const int start = row_start[d], end = row_start[d + 1];
  const float* __restrict__ Gc = G + colOff + cl * 4;

  float a0 = 0.0f, a1 = 0.0f, a2 = 0.0f, a3 = 0.0f;
  int j = start + grp;
  for (; j + EPW < end; j += 2 * EPW) {
    int s0 = srcs[j], s1 = srcs[j + EPW];
    float al0 = alpha[j], al1 = alpha[j + EPW];
    f32x4u g0 = *(const f32x4u*)(Gc + (long long)s0 * FO);
    f32x4u g1 = *(const f32x4u*)(Gc + (long long)s1 * FO);
    a0 = fmaf(al0, g0[0], a0); a1 = fmaf(al0, g0[1], a1);
    a2 = fmaf(al0, g0[2], a2); a3 = fmaf(al0, g0[3], a3);
    a0 = fmaf(al1, g1[0], a0); a1 = fmaf(al1, g1[1], a1);
    a2 = fmaf(al1, g1[2], a2); a3 = fmaf(al1, g1[3], a3);
  }
  if (j < end) {
    int s0 = srcs[j];
    float al0 = alpha[j];
    f32x4u g0 = *(const f32x4u*)(Gc + (long long)s0 * FO);
    a0 = fmaf(al0, g0[0], a0); a1 = fmaf(al0, g0[1], a1);
    a2 = fmaf(al0, g0[2], a2); a3 = fmaf(al0, g0[3], a3);
  }
#pragma unroll
  for (int off = 32; off >= LPE; off >>= 1) {
    a0 += __shfl_xor(a0, off, 64);
    a1 += __shfl_xor(a1, off, 64);
    a2 += __shfl_xor(a2, off, 64);
    a3 += __shfl_xor(a3, off, 64);
  }
  if (grp == 0) {
    f32x4u bs = *(const f32x4u*)(bias + colOff + cl * 4);
    f32x4u v;
    v[0] = fmaxf(a0 + bs[0], 0.0f);
    v[1] = fmaxf(a1 + bs[1], 0.0f);
    v[2] = fmaxf(a2 + bs[2], 0.0f);
    v[3] = fmaxf(a3 + bs[3], 0.0f);
    *(f32x4u*)(out + (long long)d * ldc + colOff + cl * 4) = v;
  }
}

// ============================ LSTM / head ============================

// gates[N x 256] -> h[N x 64], float4-vectorized
__global__ void lstm_act_kernel(const float* __restrict__ gates,
                                float* __restrict__ h, int N) {
  int idx = blockIdx.x * blockDim.x + threadIdx.x;
  if (idx >= N * 16) return;
  int i = idx >> 4, c4 = (idx & 15) * 4;
  const float* g = gates + (long long)i * 256;
  f32x4u gi = *(const f32x4u*)(g + c4);
  f32x4u gg = *(const f32x4u*)(g + 128 + c4);
  f32x4u go = *(const f32x4u*)(g + 192 + c4);
  f32x4u hv;
#pragma unroll
  for (int k = 0; k < 4; ++k) {
    float cc = sigm(gi[k]) * tanhf(gg[k]);
    hv[k] = sigm(go[k]) * tanhf(cc);
  }
  *(f32x4u*)(h + (long long)i * 64 + c4) = hv;
}

__global__ void lin3_kernel(const float* __restrict__ Z, const float* __restrict__ w,
                            const float* __restrict__ b, float* __restrict__ out, int N) {
  int i = blockIdx.x * blockDim.x + threadIdx.x;
  if (i >= N) return;
  const float4* z4 = (const float4*)(Z + (long long)i * 64);
  const float4* w4 = (const float4*)w;
  float acc = 0.0f;
#pragma unroll
  for (int k = 0; k < 16; ++k) {
    float4 a = z4[k], ww = w4[k];
    acc += a.x * ww.x + a.y * ww.y + a.z * ww.z + a.w * ww.w;
  }
  out[i] = acc + b[0];
}

// ============================ launcher ============================

struct WSplit { const short* hi; const short* lo; };

extern "C" void kernel_launch(void* const* d_in, const int* in_sizes, int n_in,
                              void* d_out, int out_size, void* d_ws, size_t ws_size,
                              hipStream_t stream) {
  const int N = 65536, E = 1048576;
  const int Et = E + N;

  const float* x        = (const float*)d_in[0];
  const int*   ei       = (const int*)d_in[1];
  const float* poi1_W   = (const float*)d_in[2];
  const float* poi1_b   = (const float*)d_in[3];
  const float* poi2_W   = (const float*)d_in[4];
  const float* poi2_b   = (const float*)d_in[5];
  const float* svi1_W   = (const float*)d_in[6];
  const float* svi1_b   = (const float*)d_in[7];
  const float* svi2_W   = (const float*)d_in[8];
  const float* svi2_b   = (const float*)d_in[9];
  const float* all1_W   = (const float*)d_in[10];
  const float* all1_b   = (const float*)d_in[11];
  const float* all2_W   = (const float*)d_in[12];
  const float* all2_b   = (const float*)d_in[13];
  const float* gat1_W   = (const float*)d_in[14];
  const float* gat1_b   = (const float*)d_in[15];
  const float* gat1_as  = (const float*)d_in[16];
  const float* gat1_ad  = (const float*)d_in[17];
  const float* gat2_W   = (const float*)d_in[18];
  const float* gat2_b   = (const float*)d_in[19];
  const float* gat2_as  = (const float*)d_in[20];
  const float* gat2_ad  = (const float*)d_in[21];
  const float* gat3_W   = (const float*)d_in[22];
  const float* gat3_b   = (const float*)d_in[23];
  const float* gat3_as  = (const float*)d_in[24];
  const float* gat3_ad  = (const float*)d_in[25];
  const float* lstm_Wih0= (const float*)d_in[26];
  const float* lstm_Wih = (const float*)d_in[27];
  const float* lstm_b   = (const float*)d_in[29];
  const float* time1_W  = (const float*)d_in[30];
  const float* time1_b  = (const float*)d_in[31];
  const float* time2_W  = (const float*)d_in[32];
  const float* time2_b  = (const float*)d_in[33];
  const float* lin1_W   = (const float*)d_in[34];
  const float* lin1_b   = (const float*)d_in[35];
  const float* lin2_W   = (const float*)d_in[36];
  const float* lin2_b   = (const float*)d_in[37];
  const float* lin3_W   = (const float*)d_in[38];
  const float* lin3_b   = (const float*)d_in[39];
  float* out = (float*)d_out;

  // ---- workspace layout ----
  float* wsf   = (float*)d_ws;
  float* R192  = wsf;
  float* RA    = R192 + (size_t)N * 192;
  float* RA2   = RA + (size_t)N * 64;
  float* RB    = RA + (size_t)N * 128;
  float* Rz    = RB + (size_t)N * 256;
  float* sArr  = Rz + (size_t)N * 128;
  float* tArr  = sArr + N;
  float* alphaArr = tArr + N;               // Et
  int* ints      = (int*)(alphaArr + Et);
  int* row_start = ints;
  int* cursor    = row_start + (N + 1);
  int* srcs      = cursor + N;
  int* blockSums = srcs + Et;
  short* pool = (short*)(((uintptr_t)(blockSums + 256) + 15) & ~(uintptr_t)15);

  WJobs jb{};
  int nj = 0, tiles = 0;
  auto split = [&](const float* W, int K, int M) -> WSplit {
    int KC = (K + 31) / 32;
    size_t sz = (size_t)KC * M * 32;
    short* hi = pool; pool += sz;
    short* lo = pool; pool += sz;
    jb.W[nj] = W; jb.hi[nj] = hi; jb.lo[nj] = lo;
    jb.K[nj] = K; jb.M16[nj] = M / 16; jb.tile0[nj] = tiles;
    tiles += KC * (M / 16);
    ++nj;
    return {hi, lo};
  };
  auto gemm = [&](const float* A, int lda, WSplit w, const float* bias,
                  float* C, int ldc, int K, int M, int act) {
    int gx = M / 64;
    hipLaunchKernelGGL(gemm_mfma, dim3(gx * (N / 64)), dim3(64), 0, stream,
                       A, lda, w.hi, w.lo, bias, C, ldc, K, (K + 31) / 32,
                       M / 16, gx, act);
  };

  // ---- register all weight splits, then ONE fused split launch ----
  WSplit wpoi1 = split(poi1_W, 13, 64);
  WSplit wpoi2 = split(poi2_W, 64, 64);
  WSplit wsvi1 = split(svi1_W, 365, 128);
  WSplit wsvi2 = split(svi2_W, 128, 128);
  WSplit wall1 = split(all1_W, 192, 128);
  WSplit wall2 = split(all2_W, 128, 128);
  WSplit wg1   = split(gat1_W, 128, 128);
  WSplit wg2   = split(gat2_W, 128, 128);
  WSplit wg3   = split(gat3_W, 128, 64);
  WSplit wls0  = split(lstm_Wih0, 24, 256);
  WSplit wls1  = split(lstm_Wih, 64, 256);
  WSplit wls2  = split(lstm_Wih + 64 * 256, 64, 256);
  WSplit wt1   = split(time1_W, 64, 64);
  WSplit wt2   = split(time2_W, 64, 64);
  WSplit wl1   = split(lin1_W, 128, 64);
  WSplit wl2   = split(lin2_W, 64, 64);
  hipLaunchKernelGGL(wsplit_all, dim3(tiles), dim3(64), 0, stream, jb, nj);

  const int TB = 256;
  const int edgeBlocks = (Et + TB - 1) / TB;

  // ---- build CSR ----
  hipLaunchKernelGGL(fill_i32_kernel, dim3((N + TB - 1) / TB), dim3(TB), 0, stream,
                     row_start, 0, N);
  hipLaunchKernelGGL(count_edges_kernel, dim3(edgeBlocks), dim3(TB), 0, stream,
                     ei, row_start, E, N);
  hipLaunchKernelGGL(scan1_kernel, dim3(N / 256), dim3(256), 0, stream,
                     row_start, blockSums);
  hipLaunchKernelGGL(scan2_kernel, dim3(1), dim3(256), 0, stream, blockSums);
  hipLaunchKernelGGL(scan3_kernel, dim3(N / 256), dim3(256), 0, stream,
                     row_start, cursor, blockSums, N, Et);
  hipLaunchKernelGGL(scatter_kernel, dim3(edgeBlocks), dim3(TB), 0, stream,
                     ei, cursor, srcs, E, N);

  // ---- MLP towers ----
  gemm(x + 3, 445, wpoi1, poi1_b, RA, 64, 13, 64, 1);
  gemm(RA, 64, wpoi2, poi2_b, R192, 192, 64, 64, 1);
  gemm(x + 56, 445, wsvi1, svi1_b, RB, 128, 365, 128, 1);
  gemm(RB, 128, wsvi2, svi2_b, R192 + 64, 192, 128, 128, 1);
  gemm(R192, 192, wall1, all1_b, RA, 128, 192, 128, 1);
  gemm(RA, 128, wall2, all2_b, RB, 128, 128, 128, 1);

  const int aggBlocks = N / 4;  // wave per dst, 4 waves/block

  // ---- GAT1 ----
  gemm(RB, 128, wg1, nullptr, RA, 128, 128, 128, 0);
  hipLaunchKernelGGL((st_kernel<128>), dim3(N / 8), dim3(256), 0, stream,
                     RA, gat1_as, gat1_ad, sArr, tArr, N);
  hipLaunchKernelGGL(agg_softmax, dim3(aggBlocks), dim3(256), 0, stream,
                     sArr, tArr, row_start, srcs, alphaArr, N);
  hipLaunchKernelGGL((agg_gather<128, 4>), dim3(N), dim3(256), 0, stream,
                     RA, alphaArr, row_start, srcs, gat1_b, RB, 128, N);
  // ---- GAT2 ----
  gemm(RB, 128, wg2, nullptr, RA, 128, 128, 128, 0);
  hipLaunchKernelGGL((st_kernel<128>), dim3(N / 8), dim3(256), 0, stream,
                     RA, gat2_as, gat2_ad, sArr, tArr, N);
  hipLaunchKernelGGL(agg_softmax, dim3(aggBlocks), dim3(256), 0, stream,
                     sArr, tArr, row_start, srcs, alphaArr, N);
  hipLaunchKernelGGL((agg_gather<128, 4>), dim3(N), dim3(256), 0, stream,
                     RA, alphaArr, row_start, srcs, gat2_b, RB, 128, N);
  // ---- GAT3 (fo=64 -> Rz cols 0..63) ----
  gemm(RB, 128, wg3, nullptr, RA, 64, 128, 64, 0);
  hipLaunchKernelGGL((st_kernel<64>), dim3(N / 16), dim3(256), 0, stream,
                     RA, gat3_as, gat3_ad, sArr, tArr, N);
  hipLaunchKernelGGL(agg_softmax, dim3(aggBlocks), dim3(256), 0, stream,
                     sArr, tArr, row_start, srcs, alphaArr, N);
  hipLaunchKernelGGL((agg_gather<64, 2>), dim3(N / 2), dim3(256), 0, stream,
                     RA, alphaArr, row_start, srcs, gat3_b, Rz, 128, N);

  // ---- "LSTM": only layers 0..2 matter (t = hs[2]) ----
  const int actBlocks = (N * 16 + TB - 1) / TB;
  gemm(x + 421, 445, wls0, lstm_b, RB, 256, 24, 256, 0);
  hipLaunchKernelGGL(lstm_act_kernel, dim3(actBlocks), dim3(TB), 0, stream, RB, RA, N);
  gemm(RA, 64, wls1, lstm_b + 256, RB, 256, 64, 256, 0);
  hipLaunchKernelGGL(lstm_act_kernel, dim3(actBlocks), dim3(TB), 0, stream, RB, RA2, N);
  gemm(RA2, 64, wls2, lstm_b + 512, RB, 256, 64, 256, 0);
  hipLaunchKernelGGL(lstm_act_kernel, dim3(actBlocks), dim3(TB), 0, stream, RB, RA, N);

  // ---- time MLP -> Rz cols 64..127 ----
  gemm(RA, 64, wt1, time1_b, RA2, 64, 64, 64, 1);
  gemm(RA2, 64, wt2, time2_b, Rz + 64, 128, 64, 64, 1);

  // ---- head ----
  gemm(Rz, 128, wl1, lin1_b, RA, 64, 128, 64, 1);
  gemm(RA, 64, wl2, lin2_b, RA2, 64, 64, 64, 1);
  hipLaunchKernelGGL(lin3_kernel, dim3((N + TB - 1) / TB), dim3(TB), 0, stream,
                     RA2, lin3_W, lin3_b, out, N);
}

// Round 9
// 907.773 us; speedup vs baseline: 2.3543x; 1.0778x over previous
//
#include <hip/hip_runtime.h>
#include <math.h>

#define DEV __device__ __forceinline__

typedef __attribute__((ext_vector_type(8))) short short8;   // 8 bf16 (4 VGPRs)
typedef __attribute__((ext_vector_type(4))) float f32x4;    // MFMA acc
typedef float f32x4u __attribute__((ext_vector_type(4), aligned(4)));

// finite "minus infinity": avoids -INF - -INF = NaN in online-softmax combine
#define NEG_BIG (-3.0e38f)

DEV float sigm(float x) { return 1.0f / (1.0f + __expf(-x)); }
DEV float leaky(float e) { return (e >= 0.0f) ? e : 0.2f * e; }

// split 8 fp32 -> bf16 hi (truncate) + bf16 lo (truncate of exact residual)
DEV void split_bf16(const float f[8], short8& hi, short8& lo) {
#pragma unroll
  for (int i = 0; i < 8; ++i) {
    unsigned u = __builtin_bit_cast(unsigned, f[i]);
    hi[i] = (short)(u >> 16);
    float h = __builtin_bit_cast(float, u & 0xffff0000u);
    float r = f[i] - h;  // exact (Dekker)
    lo[i] = (short)(__builtin_bit_cast(unsigned, r) >> 16);
  }
}

// ============================ utility kernels ============================

__global__ void fill_i32_kernel(int* p, int v, int n) {
  int i = blockIdx.x * blockDim.x + threadIdx.x;
  if (i < n) p[i] = v;
}

__global__ void count_edges_kernel(const int* __restrict__ ei, int* __restrict__ cnt,
                                   int E, int N) {
  int e = blockIdx.x * blockDim.x + threadIdx.x;
  if (e >= E + N) return;
  int d = (e < E) ? ei[E + e] : (e - E);
  atomicAdd(&cnt[d], 1);
}

__global__ void scan1_kernel(int* data, int* blockSums) {
  __shared__ int sh[256];
  int tid = threadIdx.x;
  int gid = blockIdx.x * 256 + tid;
  int v = data[gid];
  sh[tid] = v;
  __syncthreads();
  int val = v;
  for (int off = 1; off < 256; off <<= 1) {
    int add = (tid >= off) ? sh[tid - off] : 0;
    __syncthreads();
    val += add;
    sh[tid] = val;
    __syncthreads();
  }
  data[gid] = val - v;
  if (tid == 255) blockSums[blockIdx.x] = val;
}

__global__ void scan2_kernel(int* blockSums) {
  __shared__ int sh[256];
  int tid = threadIdx.x;
  int v = blockSums[tid];
  sh[tid] = v;
  __syncthreads();
  int val = v;
  for (int off = 1; off < 256; off <<= 1) {
    int add = (tid >= off) ? sh[tid - off] : 0;
    __syncthreads();
    val += add;
    sh[tid] = val;
    __syncthreads();
  }
  blockSums[tid] = val - v;
}

__global__ void scan3_kernel(int* row_start, int* cursor, const int* blockOff,
                             int N, int Et) {
  int tid = threadIdx.x;
  int gid = blockIdx.x * 256 + tid;
  int v = row_start[gid] + blockOff[blockIdx.x];
  row_start[gid] = v;
  cursor[gid] = v;
  if (gid == 0) row_start[N] = Et;
}

__global__ void scatter_kernel(const int* __restrict__ ei, int* __restrict__ cursor,
                               int* __restrict__ srcs, int E, int N) {
  int e = blockIdx.x * blockDim.x + threadIdx.x;
  if (e >= E + N) return;
  int s, d;
  if (e < E) { s = ei[e]; d = ei[E + e]; } else { s = e - E; d = e - E; }
  int pos = atomicAdd(&cursor[d], 1);
  srcs[pos] = s;
}

// ============================ fused W pre-split ============================
struct WJobs {
  const float* W[16];
  short* hi[16];
  short* lo[16];
  int K[16];
  int M16[16];
  int tile0[16];
};

__global__ __launch_bounds__(64) void wsplit_all(WJobs jb, int njobs) {
  int b = blockIdx.x;
  int ji = 0;
#pragma unroll
  for (int i = 1; i < 16; ++i)
    if (i < njobs && b >= jb.tile0[i]) ji = i;
  int t = b - jb.tile0[ji];
  int M16 = jb.M16[ji];
  int kc = t / M16, ntG = t % M16;
  int K = jb.K[ji], M = M16 * 16;
  const float* __restrict__ W = jb.W[ji];

  int lane = threadIdx.x;
  int kb = kc * 32 + (lane >> 4) * 8;
  int c = ntG * 16 + (lane & 15);
  float f[8];
#pragma unroll
  for (int j = 0; j < 8; ++j) {
    int k = kb + j;
    f[j] = (k < K) ? W[(long long)k * M + c] : 0.0f;
  }
  short8 h, l;
  split_bf16(f, h, l);
  long long off = ((long long)t * 64 + lane) * 8;
  *(short8*)(jb.hi[ji] + off) = h;
  *(short8*)(jb.lo[ji] + off) = l;
}

// ============================ MFMA GEMM ============================
// One wave per block, 64x64 C-tile, 3-term bf16-split product, no LDS.
__global__ __launch_bounds__(64) void gemm_mfma(
    const float* __restrict__ A, int lda,
    const short* __restrict__ wh, const short* __restrict__ wl,
    const float* __restrict__ bias,
    float* __restrict__ C, int ldc,
    int K, int KC, int M16, int gx, int act) {
  const int lane = threadIdx.x;
  const int m = lane & 15, q = lane >> 4;
  const int b = blockIdx.x;
  const int x = (b >> 3) % gx;
  const int y = ((b >> 3) / gx) * 8 + (b & 7);
  const long long r0 = (long long)y * 64;
  const int ntG0 = x * 4;

  f32x4 acc[4][4];
#pragma unroll
  for (int i = 0; i < 4; ++i)
#pragma unroll
    for (int j = 0; j < 4; ++j) acc[i][j] = (f32x4)(0.0f);

  for (int kc = 0; kc < KC; ++kc) {
    short8 bh[4], bl[4];
#pragma unroll
    for (int nt = 0; nt < 4; ++nt) {
      long long off = (((long long)kc * M16 + (ntG0 + nt)) * 64 + lane) * 8;
      bh[nt] = *(const short8*)(wh + off);
      bl[nt] = *(const short8*)(wl + off);
    }
    short8 ah[4], al[4];
    const bool full = (kc * 32 + 32 <= K);
#pragma unroll
    for (int mt = 0; mt < 4; ++mt) {
      const float* ap = A + (r0 + mt * 16 + m) * lda + kc * 32 + q * 8;
      float f[8];
      if (full) {
        f32x4u p0 = *(const f32x4u*)ap;
        f32x4u p1 = *(const f32x4u*)(ap + 4);
#pragma unroll
        for (int j = 0; j < 4; ++j) { f[j] = p0[j]; f[4 + j] = p1[j]; }
      } else {
#pragma unroll
        for (int j = 0; j < 8; ++j) {
          int k = kc * 32 + q * 8 + j;
          f[j] = (k < K) ? ap[j] : 0.0f;
        }
      }
      split_bf16(f, ah[mt], al[mt]);
    }
#pragma unroll
    for (int mt = 0; mt < 4; ++mt)
#pragma unroll
      for (int nt = 0; nt < 4; ++nt) {
        acc[mt][nt] = __builtin_amdgcn_mfma_f32_16x16x32_bf16(ah[mt], bh[nt], acc[mt][nt], 0, 0, 0);
        acc[mt][nt] = __builtin_amdgcn_mfma_f32_16x16x32_bf16(ah[mt], bl[nt], acc[mt][nt], 0, 0, 0);
        acc[mt][nt] = __builtin_amdgcn_mfma_f32_16x16x32_bf16(al[mt], bh[nt], acc[mt][nt], 0, 0, 0);
      }
  }

#pragma unroll
  for (int nt = 0; nt < 4; ++nt) {
    int col = (ntG0 + nt) * 16 + m;
    float bsv = bias ? bias[col] : 0.0f;
#pragma unroll
    for (int mt = 0; mt < 4; ++mt) {
      long long rb = r0 + mt * 16 + q * 4;
#pragma unroll
      for (int reg = 0; reg < 4; ++reg) {
        float v = acc[mt][nt][reg] + bsv;
        if (act == 1) v = fmaxf(v, 0.0f);
        C[(rb + reg) * ldc + col] = v;
      }
    }
  }
}

// ============================ GAT helpers ============================

// s,t dot products: float4 loads, FO/4 lanes per node, 64/(FO/4) nodes/wave
template <int FO>
__global__ __launch_bounds__(256) void st_kernel(
    const float* __restrict__ G, const float* __restrict__ asrc,
    const float* __restrict__ adst, float* __restrict__ s, float* __restrict__ t,
    int N) {
  constexpr int LPN = FO / 4;
  int wv = (blockIdx.x * blockDim.x + threadIdx.x) >> 6;
  int lane = threadIdx.x & 63;
  int sub = lane / LPN, cl = lane % LPN;
  long long node = (long long)wv * (64 / LPN) + sub;
  f32x4u g = *(const f32x4u*)(G + node * FO + cl * 4);
  f32x4u a = *(const f32x4u*)(asrc + cl * 4);
  f32x4u ad = *(const f32x4u*)(adst + cl * 4);
  float ps = g[0] * a[0] + g[1] * a[1] + g[2] * a[2] + g[3] * a[3];
  float pt = g[0] * ad[0] + g[1] * ad[1] + g[2] * ad[2] + g[3] * ad[3];
#pragma unroll
  for (int off = LPN / 2; off; off >>= 1) {
    ps += __shfl_xor(ps, off, 64);
    pt += __shfl_xor(pt, off, 64);
  }
  if (cl == 0) { s[node] = ps; t[node] = pt; }
}

// Fused per-dst softmax + gather. One wave per dst (4 dst per block).
// Phase 1: online softmax (1 lane/edge), e cached in LDS (deg<=CAP; rare
// overflow recomputed). Phase 2: in-LDS e->alpha, then alpha-weighted
// full-row G gathers (FO/4 lanes per edge, 2-edge unroll for ILP).
template <int FO>
__global__ __launch_bounds__(256) void gat_agg(
    const float* __restrict__ G, const float* __restrict__ s,
    const float* __restrict__ t, const int* __restrict__ row_start,
    const int* __restrict__ srcs, const float* __restrict__ bias,
    float* __restrict__ out, int ldc) {
  constexpr int CAP = 128;
  constexpr int LPE = FO / 4;      // lanes per edge
  constexpr int EPW = 64 / LPE;    // edge groups per wave
  __shared__ float ecache[4][CAP];
  const int wv = threadIdx.x >> 6;
  const int lane = threadIdx.x & 63;
  const int d = blockIdx.x * 4 + wv;
  const int start = row_start[d], end = row_start[d + 1];
  const float td = t[d];

  // ---- phase 1: online softmax, cache e ----
  float m = NEG_BIG, dsum = 0.0f;
  for (int j = start + lane; j < end; j += 64) {
    float e = leaky(s[srcs[j]] + td);
    int idx = j - start;
    if (idx < CAP) ecache[wv][idx] = e;
    float mn = fmaxf(m, e);
    dsum = dsum * __expf(m - mn) + __expf(e - mn);
    m = mn;
  }
#pragma unroll
  for (int off = 32; off; off >>= 1) {
    float mo = __shfl_xor(m, off, 64);
    float dso = __shfl_xor(dsum, off, 64);
    float mn = fmaxf(m, mo);
    dsum = dsum * __expf(m - mn) + dso * __expf(mo - mn);
    m = mn;
  }
  const float inv = 1.0f / dsum;

  // ---- e -> alpha in LDS (each lane converts its own writes) ----
  const int deg = end - start;
  const int capdeg = deg < CAP ? deg : CAP;
  for (int idx = lane; idx < capdeg; idx += 64)
    ecache[wv][idx] = __expf(ecache[wv][idx] - m) * inv;
  __syncthreads();  // safety: LDS visibility before cross-lane phase-2 reads

  // ---- phase 2: alpha-weighted gather, 2-edge unroll ----
  const int grp = lane / LPE, cl = lane % LPE;
  const float* __restrict__ Gc = G + cl * 4;
  float a0 = 0.0f, a1 = 0.0f, a2 = 0.0f, a3 = 0.0f;
  int j = start + grp;
  for (; j + EPW < end; j += 2 * EPW) {
    int s0 = srcs[j], s1 = srcs[j + EPW];
    int i0 = j - start, i1 = i0 + EPW;
    float al0 = (i0 < CAP) ? ecache[wv][i0]
                           : __expf(leaky(s[s0] + td) - m) * inv;
    float al1 = (i1 < CAP) ? ecache[wv][i1]
                           : __expf(leaky(s[s1] + td) - m) * inv;
    f32x4u g0 = *(const f32x4u*)(Gc + (long long)s0 * FO);
    f32x4u g1 = *(const f32x4u*)(Gc + (long long)s1 * FO);
    a0 = fmaf(al0, g0[0], a0); a1 = fmaf(al0, g0[1], a1);
    a2 = fmaf(al0, g0[2], a2); a3 = fmaf(al0, g0[3], a3);
    a0 = fmaf(al1, g1[0], a0); a1 = fmaf(al1, g1[1], a1);
    a2 = fmaf(al1, g1[2], a2); a3 = fmaf(al1, g1[3], a3);
  }
  if (j < end) {
    int s0 = srcs[j];
    int i0 = j - start;
    float al0 = (i0 < CAP) ? ecache[wv][i0]
                           : __expf(leaky(s[s0] + td) - m) * inv;
    f32x4u g0 = *(const f32x4u*)(Gc + (long long)s0 * FO);
    a0 = fmaf(al0, g0[0], a0); a1 = fmaf(al0, g0[1], a1);
    a2 = fmaf(al0, g0[2], a2); a3 = fmaf(al0, g0[3], a3);
  }
#pragma unroll
  for (int off = 32; off >= LPE; off >>= 1) {
    a0 += __shfl_xor(a0, off, 64);
    a1 += __shfl_xor(a1, off, 64);
    a2 += __shfl_xor(a2, off, 64);
    a3 += __shfl_xor(a3, off, 64);
  }
  if (grp == 0) {
    f32x4u bs = *(const f32x4u*)(bias + cl * 4);
    f32x4u v;
    v[0] = fmaxf(a0 + bs[0], 0.0f);
    v[1] = fmaxf(a1 + bs[1], 0.0f);
    v[2] = fmaxf(a2 + bs[2], 0.0f);
    v[3] = fmaxf(a3 + bs[3], 0.0f);
    *(f32x4u*)(out + (long long)d * ldc + cl * 4) = v;
  }
}

// ============================ LSTM / head ============================

__global__ void lstm_act_kernel(const float* __restrict__ gates,
                                float* __restrict__ h, int N) {
  int idx = blockIdx.x * blockDim.x + threadIdx.x;
  if (idx >= N * 16) return;
  int i = idx >> 4, c4 = (idx & 15) * 4;
  const float* g = gates + (long long)i * 256;
  f32x4u gi = *(const f32x4u*)(g + c4);
  f32x4u gg = *(const f32x4u*)(g + 128 + c4);
  f32x4u go = *(const f32x4u*)(g + 192 + c4);
  f32x4u hv;
#pragma unroll
  for (int k = 0; k < 4; ++k) {
    float cc = sigm(gi[k]) * tanhf(gg[k]);
    hv[k] = sigm(go[k]) * tanhf(cc);
  }
  *(f32x4u*)(h + (long long)i * 64 + c4) = hv;
}

__global__ void lin3_kernel(const float* __restrict__ Z, const float* __restrict__ w,
                            const float* __restrict__ b, float* __restrict__ out, int N) {
  int i = blockIdx.x * blockDim.x + threadIdx.x;
  if (i >= N) return;
  const float4* z4 = (const float4*)(Z + (long long)i * 64);
  const float4* w4 = (const float4*)w;
  float acc = 0.0f;
#pragma unroll
  for (int k = 0; k < 16; ++k) {
    float4 a = z4[k], ww = w4[k];
    acc += a.x * ww.x + a.y * ww.y + a.z * ww.z + a.w * ww.w;
  }
  out[i] = acc + b[0];
}

// ============================ launcher ============================

struct WSplit { const short* hi; const short* lo; };

extern "C" void kernel_launch(void* const* d_in, const int* in_sizes, int n_in,
                              void* d_out, int out_size, void* d_ws, size_t ws_size,
                              hipStream_t stream) {
  const int N = 65536, E = 1048576;
  const int Et = E + N;

  const float* x        = (const float*)d_in[0];
  const int*   ei       = (const int*)d_in[1];
  const float* poi1_W   = (const float*)d_in[2];
  const float* poi1_b   = (const float*)d_in[3];
  const float* poi2_W   = (const float*)d_in[4];
  const float* poi2_b   = (const float*)d_in[5];
  const float* svi1_W   = (const float*)d_in[6];
  const float* svi1_b   = (const float*)d_in[7];
  const float* svi2_W   = (const float*)d_in[8];
  const float* svi2_b   = (const float*)d_in[9];
  const float* all1_W   = (const float*)d_in[10];
  const float* all1_b   = (const float*)d_in[11];
  const float* all2_W   = (const float*)d_in[12];
  const float* all2_b   = (const float*)d_in[13];
  const float* gat1_W   = (const float*)d_in[14];
  const float* gat1_b   = (const float*)d_in[15];
  const float* gat1_as  = (const float*)d_in[16];
  const float* gat1_ad  = (const float*)d_in[17];
  const float* gat2_W   = (const float*)d_in[18];
  const float* gat2_b   = (const float*)d_in[19];
  const float* gat2_as  = (const float*)d_in[20];
  const float* gat2_ad  = (const float*)d_in[21];
  const float* gat3_W   = (const float*)d_in[22];
  const float* gat3_b   = (const float*)d_in[23];
  const float* gat3_as  = (const float*)d_in[24];
  const float* gat3_ad  = (const float*)d_in[25];
  const float* lstm_Wih0= (const float*)d_in[26];
  const float* lstm_Wih = (const float*)d_in[27];
  const float* lstm_b   = (const float*)d_in[29];
  const float* time1_W  = (const float*)d_in[30];
  const float* time1_b  = (const float*)d_in[31];
  const float* time2_W  = (const float*)d_in[32];
  const float* time2_b  = (const float*)d_in[33];
  const float* lin1_W   = (const float*)d_in[34];
  const float* lin1_b   = (const float*)d_in[35];
  const float* lin2_W   = (const float*)d_in[36];
  const float* lin2_b   = (const float*)d_in[37];
  const float* lin3_W   = (const float*)d_in[38];
  const float* lin3_b   = (const float*)d_in[39];
  float* out = (float*)d_out;

  // ---- workspace layout ----
  float* wsf   = (float*)d_ws;
  float* R192  = wsf;
  float* RA    = R192 + (size_t)N * 192;
  float* RA2   = RA + (size_t)N * 64;
  float* RB    = RA + (size_t)N * 128;
  float* Rz    = RB + (size_t)N * 256;
  float* sArr  = Rz + (size_t)N * 128;
  float* tArr  = sArr + N;
  int* ints      = (int*)(tArr + N);
  int* row_start = ints;
  int* cursor    = row_start + (N + 1);
  int* srcs      = cursor + N;
  int* blockSums = srcs + Et;
  short* pool = (short*)(((uintptr_t)(blockSums + 256) + 15) & ~(uintptr_t)15);

  WJobs jb{};
  int nj = 0, tiles = 0;
  auto split = [&](const float* W, int K, int M) -> WSplit {
    int KC = (K + 31) / 32;
    size_t sz = (size_t)KC * M * 32;
    short* hi = pool; pool += sz;
    short* lo = pool; pool += sz;
    jb.W[nj] = W; jb.hi[nj] = hi; jb.lo[nj] = lo;
    jb.K[nj] = K; jb.M16[nj] = M / 16; jb.tile0[nj] = tiles;
    tiles += KC * (M / 16);
    ++nj;
    return {hi, lo};
  };
  auto gemm = [&](const float* A, int lda, WSplit w, const float* bias,
                  float* C, int ldc, int K, int M, int act) {
    int gx = M / 64;
    hipLaunchKernelGGL(gemm_mfma, dim3(gx * (N / 64)), dim3(64), 0, stream,
                       A, lda, w.hi, w.lo, bias, C, ldc, K, (K + 31) / 32,
                       M / 16, gx, act);
  };

  // ---- register all weight splits, then ONE fused split launch ----
  WSplit wpoi1 = split(poi1_W, 13, 64);
  WSplit wpoi2 = split(poi2_W, 64, 64);
  WSplit wsvi1 = split(svi1_W, 365, 128);
  WSplit wsvi2 = split(svi2_W, 128, 128);
  WSplit wall1 = split(all1_W, 192, 128);
  WSplit wall2 = split(all2_W, 128, 128);
  WSplit wg1   = split(gat1_W, 128, 128);
  WSplit wg2   = split(gat2_W, 128, 128);
  WSplit wg3   = split(gat3_W, 128, 64);
  WSplit wls0  = split(lstm_Wih0, 24, 256);
  WSplit wls1  = split(lstm_Wih, 64, 256);
  WSplit wls2  = split(lstm_Wih + 64 * 256, 64, 256);
  WSplit wt1   = split(time1_W, 64, 64);
  WSplit wt2   = split(time2_W, 64, 64);
  WSplit wl1   = split(lin1_W, 128, 64);
  WSplit wl2   = split(lin2_W, 64, 64);
  hipLaunchKernelGGL(wsplit_all, dim3(tiles), dim3(64), 0, stream, jb, nj);

  const int TB = 256;
  const int edgeBlocks = (Et + TB - 1) / TB;

  // ---- build CSR ----
  hipLaunchKernelGGL(fill_i32_kernel, dim3((N + TB - 1) / TB), dim3(TB), 0, stream,
                     row_start, 0, N);
  hipLaunchKernelGGL(count_edges_kernel, dim3(edgeBlocks), dim3(TB), 0, stream,
                     ei, row_start, E, N);
  hipLaunchKernelGGL(scan1_kernel, dim3(N / 256), dim3(256), 0, stream,
                     row_start, blockSums);
  hipLaunchKernelGGL(scan2_kernel, dim3(1), dim3(256), 0, stream, blockSums);
  hipLaunchKernelGGL(scan3_kernel, dim3(N / 256), dim3(256), 0, stream,
                     row_start, cursor, blockSums, N, Et);
  hipLaunchKernelGGL(scatter_kernel, dim3(edgeBlocks), dim3(TB), 0, stream,
                     ei, cursor, srcs, E, N);

  // ---- MLP towers ----
  gemm(x + 3, 445, wpoi1, poi1_b, RA, 64, 13, 64, 1);
  gemm(RA, 64, wpoi2, poi2_b, R192, 192, 64, 64, 1);
  gemm(x + 56, 445, wsvi1, svi1_b, RB, 128, 365, 128, 1);
  gemm(RB, 128, wsvi2, svi2_b, R192 + 64, 192, 128, 128, 1);
  gemm(R192, 192, wall1, all1_b, RA, 128, 192, 128, 1);
  gemm(RA, 128, wall2, all2_b, RB, 128, 128, 128, 1);

  const int aggBlocks = N / 4;  // wave per dst, 4 dst per block

  // ---- GAT1 ----
  gemm(RB, 128, wg1, nullptr, RA, 128, 128, 128, 0);
  hipLaunchKernelGGL((st_kernel<128>), dim3(N / 8), dim3(256), 0, stream,
                     RA, gat1_as, gat1_ad, sArr, tArr, N);
  hipLaunchKernelGGL((gat_agg<128>), dim3(aggBlocks), dim3(256), 0, stream,
                     RA, sArr, tArr, row_start, srcs, gat1_b, RB, 128);
  // ---- GAT2 ----
  gemm(RB, 128, wg2, nullptr, RA, 128, 128, 128, 0);
  hipLaunchKernelGGL((st_kernel<128>), dim3(N / 8), dim3(256), 0, stream,
                     RA, gat2_as, gat2_ad, sArr, tArr, N);
  hipLaunchKernelGGL((gat_agg<128>), dim3(aggBlocks), dim3(256), 0, stream,
                     RA, sArr, tArr, row_start, srcs, gat2_b, RB, 128);
  // ---- GAT3 (fo=64 -> Rz cols 0..63) ----
  gemm(RB, 128, wg3, nullptr, RA, 64, 128, 64, 0);
  hipLaunchKernelGGL((st_kernel<64>), dim3(N / 16), dim3(256), 0, stream,
                     RA, gat3_as, gat3_ad, sArr, tArr, N);
  hipLaunchKernelGGL((gat_agg<64>), dim3(aggBlocks), dim3(256), 0, stream,
                     RA, sArr, tArr, row_start, srcs, gat3_b, Rz, 128);

  // ---- "LSTM": only layers 0..2 matter (t = hs[2]) ----
  const int actBlocks = (N * 16 + TB - 1) / TB;
  gemm(x + 421, 445, wls0, lstm_b, RB, 256, 24, 256, 0);
  hipLaunchKernelGGL(lstm_act_kernel, dim3(actBlocks), dim3(TB), 0, stream, RB, RA, N);
  gemm(RA, 64, wls1, lstm_b + 256, RB, 256, 64, 256, 0);
  hipLaunchKernelGGL(lstm_act_kernel, dim3(actBlocks), dim3(TB), 0, stream, RB, RA2, N);
  gemm(RA2, 64, wls2, lstm_b + 512, RB, 256, 64, 256, 0);
  hipLaunchKernelGGL(lstm_act_kernel, dim3(actBlocks), dim3(TB), 0, stream, RB, RA, N);

  // ---- time MLP -> Rz cols 64..127 ----
  gemm(RA, 64, wt1, time1_b, RA2, 64, 64, 64, 1);
  gemm(RA2, 64, wt2, time2_b, Rz + 64, 128, 64, 64, 1);

  // ---- head ----
  gemm(Rz, 128, wl1, lin1_b, RA, 64, 128, 64, 1);
  gemm(RA, 64, wl2, lin2_b, RA2, 64, 64, 64, 1);
  hipLaunchKernelGGL(lin3_kernel, dim3((N + TB - 1) / TB), dim3(TB), 0, stream,
                     RA2, lin3_W, lin3_b, out, N);
}

// Round 10
// 894.913 us; speedup vs baseline: 2.3881x; 1.0144x over previous
//
#include <hip/hip_runtime.h>
#include <math.h>

#define DEV __device__ __forceinline__

typedef __attribute__((ext_vector_type(8))) short short8;   // 8 bf16 (4 VGPRs)
typedef __attribute__((ext_vector_type(4))) float f32x4;    // MFMA acc
typedef float f32x4u __attribute__((ext_vector_type(4), aligned(4)));

// finite "minus infinity": avoids -INF - -INF = NaN in online-softmax combine
#define NEG_BIG (-3.0e38f)

DEV float sigm(float x) { return 1.0f / (1.0f + __expf(-x)); }
DEV float leaky(float e) { return (e >= 0.0f) ? e : 0.2f * e; }

// split 8 fp32 -> bf16 hi (truncate) + bf16 lo (truncate of exact residual)
DEV void split_bf16(const float f[8], short8& hi, short8& lo) {
#pragma unroll
  for (int i = 0; i < 8; ++i) {
    unsigned u = __builtin_bit_cast(unsigned, f[i]);
    hi[i] = (short)(u >> 16);
    float h = __builtin_bit_cast(float, u & 0xffff0000u);
    float r = f[i] - h;  // exact (Dekker)
    lo[i] = (short)(__builtin_bit_cast(unsigned, r) >> 16);
  }
}

// ============================ utility kernels ============================

__global__ void fill_i32_kernel(int* p, int v, int n) {
  int i = blockIdx.x * blockDim.x + threadIdx.x;
  if (i < n) p[i] = v;
}

__global__ void count_edges_kernel(const int* __restrict__ ei, int* __restrict__ cnt,
                                   int E, int N) {
  int e = blockIdx.x * blockDim.x + threadIdx.x;
  if (e >= E + N) return;
  int d = (e < E) ? ei[E + e] : (e - E);
  atomicAdd(&cnt[d], 1);
}

__global__ void scan1_kernel(int* data, int* blockSums) {
  __shared__ int sh[256];
  int tid = threadIdx.x;
  int gid = blockIdx.x * 256 + tid;
  int v = data[gid];
  sh[tid] = v;
  __syncthreads();
  int val = v;
  for (int off = 1; off < 256; off <<= 1) {
    int add = (tid >= off) ? sh[tid - off] : 0;
    __syncthreads();
    val += add;
    sh[tid] = val;
    __syncthreads();
  }
  data[gid] = val - v;
  if (tid == 255) blockSums[blockIdx.x] = val;
}

__global__ void scan2_kernel(int* blockSums) {
  __shared__ int sh[256];
  int tid = threadIdx.x;
  int v = blockSums[tid];
  sh[tid] = v;
  __syncthreads();
  int val = v;
  for (int off = 1; off < 256; off <<= 1) {
    int add = (tid >= off) ? sh[tid - off] : 0;
    __syncthreads();
    val += add;
    sh[tid] = val;
    __syncthreads();
  }
  blockSums[tid] = val - v;
}

__global__ void scan3_kernel(int* row_start, int* cursor, const int* blockOff,
                             int N, int Et) {
  int tid = threadIdx.x;
  int gid = blockIdx.x * 256 + tid;
  int v = row_start[gid] + blockOff[blockIdx.x];
  row_start[gid] = v;
  cursor[gid] = v;
  if (gid == 0) row_start[N] = Et;
}

__global__ void scatter_kernel(const int* __restrict__ ei, int* __restrict__ cursor,
                               int* __restrict__ srcs, int E, int N) {
  int e = blockIdx.x * blockDim.x + threadIdx.x;
  if (e >= E + N) return;
  int s, d;
  if (e < E) { s = ei[e]; d = ei[E + e]; } else { s = e - E; d = e - E; }
  int pos = atomicAdd(&cursor[d], 1);
  srcs[pos] = s;
}

// ============================ fused W pre-split ============================
// skip=1: source cols {0..63,128..255} of a 256-wide W (drops dead f-gate).
struct WJobs {
  const float* W[16];
  short* hi[16];
  short* lo[16];
  int K[16];
  int M16[16];
  int ldw[16];
  int skip[16];
  int tile0[16];
};

__global__ __launch_bounds__(64) void wsplit_all(WJobs jb, int njobs) {
  int b = blockIdx.x;
  int ji = 0;
#pragma unroll
  for (int i = 1; i < 16; ++i)
    if (i < njobs && b >= jb.tile0[i]) ji = i;
  int t = b - jb.tile0[ji];
  int M16 = jb.M16[ji];
  int kc = t / M16, ntG = t % M16;
  int K = jb.K[ji], ldw = jb.ldw[ji];
  const float* __restrict__ W = jb.W[ji];

  int lane = threadIdx.x;
  int kb = kc * 32 + (lane >> 4) * 8;
  int c = ntG * 16 + (lane & 15);
  if (jb.skip[ji] && c >= 64) c += 64;  // skip dead f-gate columns
  float f[8];
#pragma unroll
  for (int j = 0; j < 8; ++j) {
    int k = kb + j;
    f[j] = (k < K) ? W[(long long)k * ldw + c] : 0.0f;
  }
  short8 h, l;
  split_bf16(f, h, l);
  long long off = ((long long)t * 64 + lane) * 8;
  *(short8*)(jb.hi[ji] + off) = h;
  *(short8*)(jb.lo[ji] + off) = l;
}

// ============================ MFMA GEMM ============================
// One wave per block, MT*16 x 64 C-tile, 3-term bf16-split product, no LDS.
// MT=2 (32-row tiles) doubles grid vs 64-row: 2-6 waves/SIMD so cross-wave
// MFMA/VALU co-scheduling hides the split cost (1 wave/SIMD was the round-8
// small-M bottleneck).
template <int MT>
__global__ __launch_bounds__(64) void gemm_mfma(
    const float* __restrict__ A, int lda,
    const short* __restrict__ wh, const short* __restrict__ wl,
    const float* __restrict__ bias,
    float* __restrict__ C, int ldc,
    int K, int KC, int M16, int gx, int act) {
  const int lane = threadIdx.x;
  const int m = lane & 15, q = lane >> 4;
  const int b = blockIdx.x;
  const int x = (b >> 3) % gx;
  const int y = ((b >> 3) / gx) * 8 + (b & 7);
  const long long r0 = (long long)y * (MT * 16);
  const int ntG0 = x * 4;

  f32x4 acc[MT][4];
#pragma unroll
  for (int i = 0; i < MT; ++i)
#pragma unroll
    for (int j = 0; j < 4; ++j) acc[i][j] = (f32x4)(0.0f);

  for (int kc = 0; kc < KC; ++kc) {
    short8 bh[4], bl[4];
#pragma unroll
    for (int nt = 0; nt < 4; ++nt) {
      long long off = (((long long)kc * M16 + (ntG0 + nt)) * 64 + lane) * 8;
      bh[nt] = *(const short8*)(wh + off);
      bl[nt] = *(const short8*)(wl + off);
    }
    short8 ah[MT], al[MT];
    const bool full = (kc * 32 + 32 <= K);
#pragma unroll
    for (int mt = 0; mt < MT; ++mt) {
      const float* ap = A + (r0 + mt * 16 + m) * lda + kc * 32 + q * 8;
      float f[8];
      if (full) {
        f32x4u p0 = *(const f32x4u*)ap;
        f32x4u p1 = *(const f32x4u*)(ap + 4);
#pragma unroll
        for (int j = 0; j < 4; ++j) { f[j] = p0[j]; f[4 + j] = p1[j]; }
      } else {
#pragma unroll
        for (int j = 0; j < 8; ++j) {
          int k = kc * 32 + q * 8 + j;
          f[j] = (k < K) ? ap[j] : 0.0f;
        }
      }
      split_bf16(f, ah[mt], al[mt]);
    }
#pragma unroll
    for (int mt = 0; mt < MT; ++mt)
#pragma unroll
      for (int nt = 0; nt < 4; ++nt) {
        acc[mt][nt] = __builtin_amdgcn_mfma_f32_16x16x32_bf16(ah[mt], bh[nt], acc[mt][nt], 0, 0, 0);
        acc[mt][nt] = __builtin_amdgcn_mfma_f32_16x16x32_bf16(ah[mt], bl[nt], acc[mt][nt], 0, 0, 0);
        acc[mt][nt] = __builtin_amdgcn_mfma_f32_16x16x32_bf16(al[mt], bh[nt], acc[mt][nt], 0, 0, 0);
      }
  }

#pragma unroll
  for (int nt = 0; nt < 4; ++nt) {
    int col = (ntG0 + nt) * 16 + m;
    float bsv = bias ? bias[col] : 0.0f;
#pragma unroll
    for (int mt = 0; mt < MT; ++mt) {
      long long rb = r0 + mt * 16 + q * 4;
#pragma unroll
      for (int reg = 0; reg < 4; ++reg) {
        float v = acc[mt][nt][reg] + bsv;
        if (act == 1) v = fmaxf(v, 0.0f);
        C[(rb + reg) * ldc + col] = v;
      }
    }
  }
}

// ============================ GAT helpers ============================

// s,t dot products: float4 loads, FO/4 lanes per node, 64/(FO/4) nodes/wave
template <int FO>
__global__ __launch_bounds__(256) void st_kernel(
    const float* __restrict__ G, const float* __restrict__ asrc,
    const float* __restrict__ adst, float* __restrict__ s, float* __restrict__ t,
    int N) {
  constexpr int LPN = FO / 4;
  int wv = (blockIdx.x * blockDim.x + threadIdx.x) >> 6;
  int lane = threadIdx.x & 63;
  int sub = lane / LPN, cl = lane % LPN;
  long long node = (long long)wv * (64 / LPN) + sub;
  f32x4u g = *(const f32x4u*)(G + node * FO + cl * 4);
  f32x4u a = *(const f32x4u*)(asrc + cl * 4);
  f32x4u ad = *(const f32x4u*)(adst + cl * 4);
  float ps = g[0] * a[0] + g[1] * a[1] + g[2] * a[2] + g[3] * a[3];
  float pt = g[0] * ad[0] + g[1] * ad[1] + g[2] * ad[2] + g[3] * ad[3];
#pragma unroll
  for (int off = LPN / 2; off; off >>= 1) {
    ps += __shfl_xor(ps, off, 64);
    pt += __shfl_xor(pt, off, 64);
  }
  if (cl == 0) { s[node] = ps; t[node] = pt; }
}

// Fused per-dst softmax + gather. One wave per dst (4 dst per block).
// Phase 1: online softmax (1 lane/edge), e cached in LDS (deg<=CAP; rare
// overflow recomputed). Phase 2: in-LDS e->alpha, then alpha-weighted
// full-row G gathers (FO/4 lanes per edge, 4-edge unroll for ILP).
template <int FO>
__global__ __launch_bounds__(256) void gat_agg(
    const float* __restrict__ G, const float* __restrict__ s,
    const float* __restrict__ t, const int* __restrict__ row_start,
    const int* __restrict__ srcs, const float* __restrict__ bias,
    float* __restrict__ out, int ldc) {
  constexpr int CAP = 128;
  constexpr int LPE = FO / 4;      // lanes per edge
  constexpr int EPW = 64 / LPE;    // edge groups per wave
  __shared__ float ecache[4][CAP];
  const int wv = threadIdx.x >> 6;
  const int lane = threadIdx.x & 63;
  const int d = blockIdx.x * 4 + wv;
  const int start = row_start[d], end = row_start[d + 1];
  const float td = t[d];

  // ---- phase 1: online softmax, cache e ----
  float m = NEG_BIG, dsum = 0.0f;
  for (int j = start + lane; j < end; j += 64) {
    float e = leaky(s[srcs[j]] + td);
    int idx = j - start;
    if (idx < CAP) ecache[wv][idx] = e;
    float mn = fmaxf(m, e);
    dsum = dsum * __expf(m - mn) + __expf(e - mn);
    m = mn;
  }
#pragma unroll
  for (int off = 32; off; off >>= 1) {
    float mo = __shfl_xor(m, off, 64);
    float dso = __shfl_xor(dsum, off, 64);
    float mn = fmaxf(m, mo);
    dsum = dsum * __expf(m - mn) + dso * __expf(mo - mn);
    m = mn;
  }
  const float inv = 1.0f / dsum;

  // ---- e -> alpha in LDS ----
  const int deg = end - start;
  const int capdeg = deg < CAP ? deg : CAP;
  for (int idx = lane; idx < capdeg; idx += 64)
    ecache[wv][idx] = __expf(ecache[wv][idx] - m) * inv;
  __syncthreads();

  // ---- phase 2: alpha-weighted gather, 4-edge unroll ----
  const int grp = lane / LPE, cl = lane % LPE;
  const float* __restrict__ Gc = G + cl * 4;
  float a0 = 0.0f, a1 = 0.0f, a2 = 0.0f, a3 = 0.0f;
  int j = start + grp;
  for (; j + 3 * EPW < end; j += 4 * EPW) {
    int i0 = j - start;
    int s0 = srcs[j], s1 = srcs[j + EPW];
    int s2 = srcs[j + 2 * EPW], s3 = srcs[j + 3 * EPW];
    float al0 = (i0 < CAP) ? ecache[wv][i0]
                           : __expf(leaky(s[s0] + td) - m) * inv;
    float al1 = (i0 + EPW < CAP) ? ecache[wv][i0 + EPW]
                                 : __expf(leaky(s[s1] + td) - m) * inv;
    float al2 = (i0 + 2 * EPW < CAP) ? ecache[wv][i0 + 2 * EPW]
                                     : __expf(leaky(s[s2] + td) - m) * inv;
    float al3 = (i0 + 3 * EPW < CAP) ? ecache[wv][i0 + 3 * EPW]
                                     : __expf(leaky(s[s3] + td) - m) * inv;
    f32x4u g0 = *(const f32x4u*)(Gc + (long long)s0 * FO);
    f32x4u g1 = *(const f32x4u*)(Gc + (long long)s1 * FO);
    f32x4u g2 = *(const f32x4u*)(Gc + (long long)s2 * FO);
    f32x4u g3 = *(const f32x4u*)(Gc + (long long)s3 * FO);
    a0 = fmaf(al0, g0[0], a0); a1 = fmaf(al0, g0[1], a1);
    a2 = fmaf(al0, g0[2], a2); a3 = fmaf(al0, g0[3], a3);
    a0 = fmaf(al1, g1[0], a0); a1 = fmaf(al1, g1[1], a1);
    a2 = fmaf(al1, g1[2], a2); a3 = fmaf(al1, g1[3], a3);
    a0 = fmaf(al2, g2[0], a0); a1 = fmaf(al2, g2[1], a1);
    a2 = fmaf(al2, g2[2], a2); a3 = fmaf(al2, g2[3], a3);
    a0 = fmaf(al3, g3[0], a0); a1 = fmaf(al3, g3[1], a1);
    a2 = fmaf(al3, g3[2], a2); a3 = fmaf(al3, g3[3], a3);
  }
  for (; j < end; j += EPW) {
    int s0 = srcs[j];
    int i0 = j - start;
    float al0 = (i0 < CAP) ? ecache[wv][i0]
                           : __expf(leaky(s[s0] + td) - m) * inv;
    f32x4u g0 = *(const f32x4u*)(Gc + (long long)s0 * FO);
    a0 = fmaf(al0, g0[0], a0); a1 = fmaf(al0, g0[1], a1);
    a2 = fmaf(al0, g0[2], a2); a3 = fmaf(al0, g0[3], a3);
  }
#pragma unroll
  for (int off = 32; off >= LPE; off >>= 1) {
    a0 += __shfl_xor(a0, off, 64);
    a1 += __shfl_xor(a1, off, 64);
    a2 += __shfl_xor(a2, off, 64);
    a3 += __shfl_xor(a3, off, 64);
  }
  if (grp == 0) {
    f32x4u bs = *(const f32x4u*)(bias + cl * 4);
    f32x4u v;
    v[0] = fmaxf(a0 + bs[0], 0.0f);
    v[1] = fmaxf(a1 + bs[1], 0.0f);
    v[2] = fmaxf(a2 + bs[2], 0.0f);
    v[3] = fmaxf(a3 + bs[3], 0.0f);
    *(f32x4u*)(out + (long long)d * ldc + cl * 4) = v;
  }
}

// ============================ LSTM / head ============================

// gates[N x 192] = {i,g,o} (f-gate never computed: dead in reference).
// bias = original 256-wide lstm_b row; h = sig(o+bo)*tanh(sig(i+bi)*tanh(g+bg))
__global__ void lstm_act_kernel(const float* __restrict__ gates,
                                const float* __restrict__ bias,
                                float* __restrict__ h, int N) {
  int idx = blockIdx.x * blockDim.x + threadIdx.x;
  if (idx >= N * 16) return;
  int i = idx >> 4, c4 = (idx & 15) * 4;
  const float* g = gates + (long long)i * 192;
  f32x4u gi = *(const f32x4u*)(g + c4);
  f32x4u gg = *(const f32x4u*)(g + 64 + c4);
  f32x4u go = *(const f32x4u*)(g + 128 + c4);
  f32x4u bi = *(const f32x4u*)(bias + c4);
  f32x4u bg = *(const f32x4u*)(bias + 128 + c4);
  f32x4u bo = *(const f32x4u*)(bias + 192 + c4);
  f32x4u hv;
#pragma unroll
  for (int k = 0; k < 4; ++k) {
    float cc = sigm(gi[k] + bi[k]) * tanhf(gg[k] + bg[k]);
    hv[k] = sigm(go[k] + bo[k]) * tanhf(cc);
  }
  *(f32x4u*)(h + (long long)i * 64 + c4) = hv;
}

__global__ void lin3_kernel(const float* __restrict__ Z, const float* __restrict__ w,
                            const float* __restrict__ b, float* __restrict__ out, int N) {
  int i = blockIdx.x * blockDim.x + threadIdx.x;
  if (i >= N) return;
  const float4* z4 = (const float4*)(Z + (long long)i * 64);
  const float4* w4 = (const float4*)w;
  float acc = 0.0f;
#pragma unroll
  for (int k = 0; k < 16; ++k) {
    float4 a = z4[k], ww = w4[k];
    acc += a.x * ww.x + a.y * ww.y + a.z * ww.z + a.w * ww.w;
  }
  out[i] = acc + b[0];
}

// ============================ launcher ============================

struct WSplit { const short* hi; const short* lo; };

extern "C" void kernel_launch(void* const* d_in, const int* in_sizes, int n_in,
                              void* d_out, int out_size, void* d_ws, size_t ws_size,
                              hipStream_t stream) {
  const int N = 65536, E = 1048576;
  const int Et = E + N;

  const float* x        = (const float*)d_in[0];
  const int*   ei       = (const int*)d_in[1];
  const float* poi1_W   = (const float*)d_in[2];
  const float* poi1_b   = (const float*)d_in[3];
  const float* poi2_W   = (const float*)d_in[4];
  const float* poi2_b   = (const float*)d_in[5];
  const float* svi1_W   = (const float*)d_in[6];
  const float* svi1_b   = (const float*)d_in[7];
  const float* svi2_W   = (const float*)d_in[8];
  const float* svi2_b   = (const float*)d_in[9];
  const float* all1_W   = (const float*)d_in[10];
  const float* all1_b   = (const float*)d_in[11];
  const float* all2_W   = (const float*)d_in[12];
  const float* all2_b   = (const float*)d_in[13];
  const float* gat1_W   = (const float*)d_in[14];
  const float* gat1_b   = (const float*)d_in[15];
  const float* gat1_as  = (const float*)d_in[16];
  const float* gat1_ad  = (const float*)d_in[17];
  const float* gat2_W   = (const float*)d_in[18];
  const float* gat2_b   = (const float*)d_in[19];
  const float* gat2_as  = (const float*)d_in[20];
  const float* gat2_ad  = (const float*)d_in[21];
  const float* gat3_W   = (const float*)d_in[22];
  const float* gat3_b   = (const float*)d_in[23];
  const float* gat3_as  = (const float*)d_in[24];
  const float* gat3_ad  = (const float*)d_in[25];
  const float* lstm_Wih0= (const float*)d_in[26];
  const float* lstm_Wih = (const float*)d_in[27];
  const float* lstm_b   = (const float*)d_in[29];
  const float* time1_W  = (const float*)d_in[30];
  const float* time1_b  = (const float*)d_in[31];
  const float* time2_W  = (const float*)d_in[32];
  const float* time2_b  = (const float*)d_in[33];
  const float* lin1_W   = (const float*)d_in[34];
  const float* lin1_b   = (const float*)d_in[35];
  const float* lin2_W   = (const float*)d_in[36];
  const float* lin2_b   = (const float*)d_in[37];
  const float* lin3_W   = (const float*)d_in[38];
  const float* lin3_b   = (const float*)d_in[39];
  float* out = (float*)d_out;

  // ---- workspace layout ----
  float* wsf   = (float*)d_ws;
  float* R192  = wsf;
  float* RA    = R192 + (size_t)N * 192;
  float* RA2   = RA + (size_t)N * 64;
  float* RB    = RA + (size_t)N * 128;
  float* Rz    = RB + (size_t)N * 256;
  float* sArr  = Rz + (size_t)N * 128;
  float* tArr  = sArr + N;
  int* ints      = (int*)(tArr + N);
  int* row_start = ints;
  int* cursor    = row_start + (N + 1);
  int* srcs      = cursor + N;
  int* blockSums = srcs + Et;
  short* pool = (short*)(((uintptr_t)(blockSums + 256) + 15) & ~(uintptr_t)15);

  WJobs jb{};
  int nj = 0, tiles = 0;
  auto split = [&](const float* W, int K, int M, int ldw, int skip) -> WSplit {
    int KC = (K + 31) / 32;
    size_t sz = (size_t)KC * M * 32;
    short* hi = pool; pool += sz;
    short* lo = pool; pool += sz;
    jb.W[nj] = W; jb.hi[nj] = hi; jb.lo[nj] = lo;
    jb.K[nj] = K; jb.M16[nj] = M / 16; jb.ldw[nj] = ldw; jb.skip[nj] = skip;
    jb.tile0[nj] = tiles;
    tiles += KC * (M / 16);
    ++nj;
    return {hi, lo};
  };
  auto gemm = [&](const float* A, int lda, WSplit w, const float* bias,
                  float* C, int ldc, int K, int M, int act) {
    int gx = M / 64;
    hipLaunchKernelGGL((gemm_mfma<2>), dim3(gx * (N / 32)), dim3(64), 0, stream,
                       A, lda, w.hi, w.lo, bias, C, ldc, K, (K + 31) / 32,
                       M / 16, gx, act);
  };

  // ---- register all weight splits, then ONE fused split launch ----
  WSplit wpoi1 = split(poi1_W, 13, 64, 64, 0);
  WSplit wpoi2 = split(poi2_W, 64, 64, 64, 0);
  WSplit wsvi1 = split(svi1_W, 365, 128, 128, 0);
  WSplit wsvi2 = split(svi2_W, 128, 128, 128, 0);
  WSplit wall1 = split(all1_W, 192, 128, 128, 0);
  WSplit wall2 = split(all2_W, 128, 128, 128, 0);
  WSplit wg1   = split(gat1_W, 128, 128, 128, 0);
  WSplit wg2   = split(gat2_W, 128, 128, 128, 0);
  WSplit wg3   = split(gat3_W, 128, 64, 64, 0);
  // LSTM: pack cols {0..63,128..255} (i,g,o) — f-gate is dead code
  WSplit wls0  = split(lstm_Wih0, 24, 192, 256, 1);
  WSplit wls1  = split(lstm_Wih, 64, 192, 256, 1);
  WSplit wls2  = split(lstm_Wih + 64 * 256, 64, 192, 256, 1);
  WSplit wt1   = split(time1_W, 64, 64, 64, 0);
  WSplit wt2   = split(time2_W, 64, 64, 64, 0);
  WSplit wl1   = split(lin1_W, 128, 64, 64, 0);
  WSplit wl2   = split(lin2_W, 64, 64, 64, 0);
  hipLaunchKernelGGL(wsplit_all, dim3(tiles), dim3(64), 0, stream, jb, nj);

  const int TB = 256;
  const int edgeBlocks = (Et + TB - 1) / TB;

  // ---- build CSR ----
  hipLaunchKernelGGL(fill_i32_kernel, dim3((N + TB - 1) / TB), dim3(TB), 0, stream,
                     row_start, 0, N);
  hipLaunchKernelGGL(count_edges_kernel, dim3(edgeBlocks), dim3(TB), 0, stream,
                     ei, row_start, E, N);
  hipLaunchKernelGGL(scan1_kernel, dim3(N / 256), dim3(256), 0, stream,
                     row_start, blockSums);
  hipLaunchKernelGGL(scan2_kernel, dim3(1), dim3(256), 0, stream, blockSums);
  hipLaunchKernelGGL(scan3_kernel, dim3(N / 256), dim3(256), 0, stream,
                     row_start, cursor, blockSums, N, Et);
  hipLaunchKernelGGL(scatter_kernel, dim3(edgeBlocks), dim3(TB), 0, stream,
                     ei, cursor, srcs, E, N);

  // ---- MLP towers ----
  gemm(x + 3, 445, wpoi1, poi1_b, RA, 64, 13, 64, 1);
  gemm(RA, 64, wpoi2, poi2_b, R192, 192, 64, 64, 1);
  gemm(x + 56, 445, wsvi1, svi1_b, RB, 128, 365, 128, 1);
  gemm(RB, 128, wsvi2, svi2_b, R192 + 64, 192, 128, 128, 1);
  gemm(R192, 192, wall1, all1_b, RA, 128, 192, 128, 1);
  gemm(RA, 128, wall2, all2_b, RB, 128, 128, 128, 1);

  const int aggBlocks = N / 4;  // wave per dst, 4 dst per block

  // ---- GAT1 ----
  gemm(RB, 128, wg1, nullptr, RA, 128, 128, 128, 0);
  hipLaunchKernelGGL((st_kernel<128>), dim3(N / 8), dim3(256), 0, stream,
                     RA, gat1_as, gat1_ad, sArr, tArr, N);
  hipLaunchKernelGGL((gat_agg<128>), dim3(aggBlocks), dim3(256), 0, stream,
                     RA, sArr, tArr, row_start, srcs, gat1_b, RB, 128);
  // ---- GAT2 ----
  gemm(RB, 128, wg2, nullptr, RA, 128, 128, 128, 0);
  hipLaunchKernelGGL((st_kernel<128>), dim3(N / 8), dim3(256), 0, stream,
                     RA, gat2_as, gat2_ad, sArr, tArr, N);
  hipLaunchKernelGGL((gat_agg<128>), dim3(aggBlocks), dim3(256), 0, stream,
                     RA, sArr, tArr, row_start, srcs, gat2_b, RB, 128);
  // ---- GAT3 (fo=64 -> Rz cols 0..63) ----
  gemm(RB, 128, wg3, nullptr, RA, 64, 128, 64, 0);
  hipLaunchKernelGGL((st_kernel<64>), dim3(N / 16), dim3(256), 0, stream,
                     RA, gat3_as, gat3_ad, sArr, tArr, N);
  hipLaunchKernelGGL((gat_agg<64>), dim3(aggBlocks), dim3(256), 0, stream,
                     RA, sArr, tArr, row_start, srcs, gat3_b, Rz, 128);

  // ---- "LSTM": only layers 0..2 matter (t = hs[2]); f-gate skipped ----
  const int actBlocks = (N * 16 + TB - 1) / TB;
  gemm(x + 421, 445, wls0, nullptr, RB, 192, 24, 192, 0);
  hipLaunchKernelGGL(lstm_act_kernel, dim3(actBlocks), dim3(TB), 0, stream,
                     RB, lstm_b, RA, N);
  gemm(RA, 64, wls1, nullptr, RB, 192, 64, 192, 0);
  hipLaunchKernelGGL(lstm_act_kernel, dim3(actBlocks), dim3(TB), 0, stream,
                     RB, lstm_b + 256, RA2, N);
  gemm(RA2, 64, wls2, nullptr, RB, 192, 64, 192, 0);
  hipLaunchKernelGGL(lstm_act_kernel, dim3(actBlocks), dim3(TB), 0, stream,
                     RB, lstm_b + 512, RA, N);

  // ---- time MLP -> Rz cols 64..127 ----
  gemm(RA, 64, wt1, time1_b, RA2, 64, 64, 64, 1);
  gemm(RA2, 64, wt2, time2_b, Rz + 64, 128, 64, 64, 1);

  // ---- head ----
  gemm(Rz, 128, wl1, lin1_b, RA, 64, 128, 64, 1);
  gemm(RA, 64, wl2, lin2_b, RA2, 64, 64, 64, 1);
  hipLaunchKernelGGL(lin3_kernel, dim3((N + TB - 1) / TB), dim3(TB), 0, stream,
                     RA2, lin3_W, lin3_b, out, N);
}

// Round 11
// 893.978 us; speedup vs baseline: 2.3906x; 1.0010x over previous
//
#include <hip/hip_runtime.h>
#include <math.h>

#define DEV __device__ __forceinline__

typedef __attribute__((ext_vector_type(8))) short short8;   // 8 bf16 (4 VGPRs)
typedef __attribute__((ext_vector_type(4))) float f32x4;    // MFMA acc
typedef float f32x4u __attribute__((ext_vector_type(4), aligned(4)));
typedef __attribute__((ext_vector_type(4))) unsigned int u32x4;

// finite "minus infinity": avoids -INF - -INF = NaN in online-softmax combine
#define NEG_BIG (-3.0e38f)

DEV float sigm(float x) { return 1.0f / (1.0f + __expf(-x)); }
DEV float leaky(float e) { return (e >= 0.0f) ? e : 0.2f * e; }

// split 8 fp32 -> bf16 hi (truncate) + bf16 lo (truncate of exact residual)
DEV void split_bf16(const float f[8], short8& hi, short8& lo) {
#pragma unroll
  for (int i = 0; i < 8; ++i) {
    unsigned u = __builtin_bit_cast(unsigned, f[i]);
    hi[i] = (short)(u >> 16);
    float h = __builtin_bit_cast(float, u & 0xffff0000u);
    float r = f[i] - h;  // exact (Dekker)
    lo[i] = (short)(__builtin_bit_cast(unsigned, r) >> 16);
  }
}

// fp32 -> packed u32 (bf16hi<<16 | bf16lo), truncation split: identical
// numerics to split_bf16, relocated to the producer epilogue.
DEV unsigned packsplit(float v) {
  unsigned u = __builtin_bit_cast(unsigned, v);
  unsigned hf = u & 0xffff0000u;
  float r = v - __builtin_bit_cast(float, hf);
  return hf | (__builtin_bit_cast(unsigned, r) >> 16);
}

// unpack 8 packed u32 -> hi/lo short8 via v_perm (8 VALU vs ~40 for split)
DEV void unpack_pk(const u32x4 p0, const u32x4 p1, short8& hi, short8& lo) {
  u32x4 h, l;
  h[0] = __builtin_amdgcn_perm(p0[1], p0[0], 0x07060302u);
  h[1] = __builtin_amdgcn_perm(p0[3], p0[2], 0x07060302u);
  h[2] = __builtin_amdgcn_perm(p1[1], p1[0], 0x07060302u);
  h[3] = __builtin_amdgcn_perm(p1[3], p1[2], 0x07060302u);
  l[0] = __builtin_amdgcn_perm(p0[1], p0[0], 0x05040100u);
  l[1] = __builtin_amdgcn_perm(p0[3], p0[2], 0x05040100u);
  l[2] = __builtin_amdgcn_perm(p1[1], p1[0], 0x05040100u);
  l[3] = __builtin_amdgcn_perm(p1[3], p1[2], 0x05040100u);
  hi = __builtin_bit_cast(short8, h);
  lo = __builtin_bit_cast(short8, l);
}

// ============================ utility kernels ============================

__global__ void fill_i32_kernel(int* p, int v, int n) {
  int i = blockIdx.x * blockDim.x + threadIdx.x;
  if (i < n) p[i] = v;
}

__global__ void count_edges_kernel(const int* __restrict__ ei, int* __restrict__ cnt,
                                   int E, int N) {
  int e = blockIdx.x * blockDim.x + threadIdx.x;
  if (e >= E + N) return;
  int d = (e < E) ? ei[E + e] : (e - E);
  atomicAdd(&cnt[d], 1);
}

__global__ void scan1_kernel(int* data, int* blockSums) {
  __shared__ int sh[256];
  int tid = threadIdx.x;
  int gid = blockIdx.x * 256 + tid;
  int v = data[gid];
  sh[tid] = v;
  __syncthreads();
  int val = v;
  for (int off = 1; off < 256; off <<= 1) {
    int add = (tid >= off) ? sh[tid - off] : 0;
    __syncthreads();
    val += add;
    sh[tid] = val;
    __syncthreads();
  }
  data[gid] = val - v;
  if (tid == 255) blockSums[blockIdx.x] = val;
}

__global__ void scan2_kernel(int* blockSums) {
  __shared__ int sh[256];
  int tid = threadIdx.x;
  int v = blockSums[tid];
  sh[tid] = v;
  __syncthreads();
  int val = v;
  for (int off = 1; off < 256; off <<= 1) {
    int add = (tid >= off) ? sh[tid - off] : 0;
    __syncthreads();
    val += add;
    sh[tid] = val;
    __syncthreads();
  }
  blockSums[tid] = val - v;
}

__global__ void scan3_kernel(int* row_start, int* cursor, const int* blockOff,
                             int N, int Et) {
  int tid = threadIdx.x;
  int gid = blockIdx.x * 256 + tid;
  int v = row_start[gid] + blockOff[blockIdx.x];
  row_start[gid] = v;
  cursor[gid] = v;
  if (gid == 0) row_start[N] = Et;
}

__global__ void scatter_kernel(const int* __restrict__ ei, int* __restrict__ cursor,
                               int* __restrict__ srcs, int E, int N) {
  int e = blockIdx.x * blockDim.x + threadIdx.x;
  if (e >= E + N) return;
  int s, d;
  if (e < E) { s = ei[e]; d = ei[E + e]; } else { s = e - E; d = e - E; }
  int pos = atomicAdd(&cursor[d], 1);
  srcs[pos] = s;
}

// ============================ fused W pre-split ============================
// skip=1: source cols {0..63,128..255} of a 256-wide W (drops dead f-gate).
struct WJobs {
  const float* W[16];
  short* hi[16];
  short* lo[16];
  int K[16];
  int M16[16];
  int ldw[16];
  int skip[16];
  int tile0[16];
};

__global__ __launch_bounds__(64) void wsplit_all(WJobs jb, int njobs) {
  int b = blockIdx.x;
  int ji = 0;
#pragma unroll
  for (int i = 1; i < 16; ++i)
    if (i < njobs && b >= jb.tile0[i]) ji = i;
  int t = b - jb.tile0[ji];
  int M16 = jb.M16[ji];
  int kc = t / M16, ntG = t % M16;
  int K = jb.K[ji], ldw = jb.ldw[ji];
  const float* __restrict__ W = jb.W[ji];

  int lane = threadIdx.x;
  int kb = kc * 32 + (lane >> 4) * 8;
  int c = ntG * 16 + (lane & 15);
  if (jb.skip[ji] && c >= 64) c += 64;  // skip dead f-gate columns
  float f[8];
#pragma unroll
  for (int j = 0; j < 8; ++j) {
    int k = kb + j;
    f[j] = (k < K) ? W[(long long)k * ldw + c] : 0.0f;
  }
  short8 h, l;
  split_bf16(f, h, l);
  long long off = ((long long)t * 64 + lane) * 8;
  *(short8*)(jb.hi[ji] + off) = h;
  *(short8*)(jb.lo[ji] + off) = l;
}

// ============================ MFMA GEMM ============================
// One wave per block, MT*16 x 64 C-tile, 3-term bf16-split product, no LDS.
// APK=0: A fp32, split in-loop (x-sourced single-use inputs).
// APK=1: A packed u32 (hi|lo), v_perm unpack (internal tensors) - MFMA-bound.
// OPK=0: C fp32.  OPK=1: C packed u32 for downstream GEMM consumption.
template <int MT, int APK, int OPK>
__global__ __launch_bounds__(64) void gemm_mfma(
    const void* __restrict__ Av, int lda,
    const short* __restrict__ wh, const short* __restrict__ wl,
    const float* __restrict__ bias,
    void* __restrict__ Cv, int ldc,
    int K, int KC, int M16, int gx, int act) {
  const int lane = threadIdx.x;
  const int m = lane & 15, q = lane >> 4;
  const int b = blockIdx.x;
  const int x = (b >> 3) % gx;
  const int y = ((b >> 3) / gx) * 8 + (b & 7);
  const long long r0 = (long long)y * (MT * 16);
  const int ntG0 = x * 4;

  f32x4 acc[MT][4];
#pragma unroll
  for (int i = 0; i < MT; ++i)
#pragma unroll
    for (int j = 0; j < 4; ++j) acc[i][j] = (f32x4)(0.0f);

  for (int kc = 0; kc < KC; ++kc) {
    short8 bh[4], bl[4];
#pragma unroll
    for (int nt = 0; nt < 4; ++nt) {
      long long off = (((long long)kc * M16 + (ntG0 + nt)) * 64 + lane) * 8;
      bh[nt] = *(const short8*)(wh + off);
      bl[nt] = *(const short8*)(wl + off);
    }
    short8 ah[MT], al[MT];
#pragma unroll
    for (int mt = 0; mt < MT; ++mt) {
      if (APK == 1) {
        const unsigned* ap = (const unsigned*)Av + (r0 + mt * 16 + m) * lda + kc * 32 + q * 8;
        u32x4 p0 = *(const u32x4*)ap;
        u32x4 p1 = *(const u32x4*)(ap + 4);
        unpack_pk(p0, p1, ah[mt], al[mt]);
      } else {
        const float* ap = (const float*)Av + (r0 + mt * 16 + m) * lda + kc * 32 + q * 8;
        float f[8];
        const bool full = (kc * 32 + 32 <= K);
        if (full) {
          f32x4u p0 = *(const f32x4u*)ap;
          f32x4u p1 = *(const f32x4u*)(ap + 4);
#pragma unroll
          for (int j = 0; j < 4; ++j) { f[j] = p0[j]; f[4 + j] = p1[j]; }
        } else {
#pragma unroll
          for (int j = 0; j < 8; ++j) {
            int k = kc * 32 + q * 8 + j;
            f[j] = (k < K) ? ap[j] : 0.0f;
          }
        }
        split_bf16(f, ah[mt], al[mt]);
      }
    }
#pragma unroll
    for (int mt = 0; mt < MT; ++mt)
#pragma unroll
      for (int nt = 0; nt < 4; ++nt) {
        acc[mt][nt] = __builtin_amdgcn_mfma_f32_16x16x32_bf16(ah[mt], bh[nt], acc[mt][nt], 0, 0, 0);
        acc[mt][nt] = __builtin_amdgcn_mfma_f32_16x16x32_bf16(ah[mt], bl[nt], acc[mt][nt], 0, 0, 0);
        acc[mt][nt] = __builtin_amdgcn_mfma_f32_16x16x32_bf16(al[mt], bh[nt], acc[mt][nt], 0, 0, 0);
      }
  }

#pragma unroll
  for (int nt = 0; nt < 4; ++nt) {
    int col = (ntG0 + nt) * 16 + m;
    float bsv = bias ? bias[col] : 0.0f;
#pragma unroll
    for (int mt = 0; mt < MT; ++mt) {
      long long rb = r0 + mt * 16 + q * 4;
#pragma unroll
      for (int reg = 0; reg < 4; ++reg) {
        float v = acc[mt][nt][reg] + bsv;
        if (act == 1) v = fmaxf(v, 0.0f);
        if (OPK == 1)
          ((unsigned*)Cv)[(rb + reg) * ldc + col] = packsplit(v);
        else
          ((float*)Cv)[(rb + reg) * ldc + col] = v;
      }
    }
  }
}

// ============================ GAT helpers ============================

// s,t dot products: float4 loads, FO/4 lanes per node, 64/(FO/4) nodes/wave
template <int FO>
__global__ __launch_bounds__(256) void st_kernel(
    const float* __restrict__ G, const float* __restrict__ asrc,
    const float* __restrict__ adst, float* __restrict__ s, float* __restrict__ t,
    int N) {
  constexpr int LPN = FO / 4;
  int wv = (blockIdx.x * blockDim.x + threadIdx.x) >> 6;
  int lane = threadIdx.x & 63;
  int sub = lane / LPN, cl = lane % LPN;
  long long node = (long long)wv * (64 / LPN) + sub;
  f32x4u g = *(const f32x4u*)(G + node * FO + cl * 4);
  f32x4u a = *(const f32x4u*)(asrc + cl * 4);
  f32x4u ad = *(const f32x4u*)(adst + cl * 4);
  float ps = g[0] * a[0] + g[1] * a[1] + g[2] * a[2] + g[3] * a[3];
  float pt = g[0] * ad[0] + g[1] * ad[1] + g[2] * ad[2] + g[3] * ad[3];
#pragma unroll
  for (int off = LPN / 2; off; off >>= 1) {
    ps += __shfl_xor(ps, off, 64);
    pt += __shfl_xor(pt, off, 64);
  }
  if (cl == 0) { s[node] = ps; t[node] = pt; }
}

// Fused per-dst softmax + gather. One wave per dst (4 dst per block).
// OPK=1: output packed u32 (hi|lo) for downstream GEMM-A consumption.
template <int FO, int OPK>
__global__ __launch_bounds__(256) void gat_agg(
    const float* __restrict__ G, const float* __restrict__ s,
    const float* __restrict__ t, const int* __restrict__ row_start,
    const int* __restrict__ srcs, const float* __restrict__ bias,
    void* __restrict__ outv, int ldc) {
  constexpr int CAP = 128;
  constexpr int LPE = FO / 4;      // lanes per edge
  constexpr int EPW = 64 / LPE;    // edge groups per wave
  __shared__ float ecache[4][CAP];
  const int wv = threadIdx.x >> 6;
  const int lane = threadIdx.x & 63;
  const int d = blockIdx.x * 4 + wv;
  const int start = row_start[d], end = row_start[d + 1];
  const float td = t[d];

  // ---- phase 1: online softmax, cache e ----
  float m = NEG_BIG, dsum = 0.0f;
  for (int j = start + lane; j < end; j += 64) {
    float e = leaky(s[srcs[j]] + td);
    int idx = j - start;
    if (idx < CAP) ecache[wv][idx] = e;
    float mn = fmaxf(m, e);
    dsum = dsum * __expf(m - mn) + __expf(e - mn);
    m = mn;
  }
#pragma unroll
  for (int off = 32; off; off >>= 1) {
    float mo = __shfl_xor(m, off, 64);
    float dso = __shfl_xor(dsum, off, 64);
    float mn = fmaxf(m, mo);
    dsum = dsum * __expf(m - mn) + dso * __expf(mo - mn);
    m = mn;
  }
  const float inv = 1.0f / dsum;

  // ---- e -> alpha in LDS ----
  const int deg = end - start;
  const int capdeg = deg < CAP ? deg : CAP;
  for (int idx = lane; idx < capdeg; idx += 64)
    ecache[wv][idx] = __expf(ecache[wv][idx] - m) * inv;
  __syncthreads();

  // ---- phase 2: alpha-weighted gather, 2-edge unroll ----
  const int grp = lane / LPE, cl = lane % LPE;
  const float* __restrict__ Gc = G + cl * 4;
  float a0 = 0.0f, a1 = 0.0f, a2 = 0.0f, a3 = 0.0f;
  int j = start + grp;
  for (; j + EPW < end; j += 2 * EPW) {
    int s0 = srcs[j], s1 = srcs[j + EPW];
    int i0 = j - start, i1 = i0 + EPW;
    float al0 = (i0 < CAP) ? ecache[wv][i0]
                           : __expf(leaky(s[s0] + td) - m) * inv;
    float al1 = (i1 < CAP) ? ecache[wv][i1]
                           : __expf(leaky(s[s1] + td) - m) * inv;
    f32x4u g0 = *(const f32x4u*)(Gc + (long long)s0 * FO);
    f32x4u g1 = *(const f32x4u*)(Gc + (long long)s1 * FO);
    a0 = fmaf(al0, g0[0], a0); a1 = fmaf(al0, g0[1], a1);
    a2 = fmaf(al0, g0[2], a2); a3 = fmaf(al0, g0[3], a3);
    a0 = fmaf(al1, g1[0], a0); a1 = fmaf(al1, g1[1], a1);
    a2 = fmaf(al1, g1[2], a2); a3 = fmaf(al1, g1[3], a3);
  }
  if (j < end) {
    int s0 = srcs[j];
    int i0 = j - start;
    float al0 = (i0 < CAP) ? ecache[wv][i0]
                           : __expf(leaky(s[s0] + td) - m) * inv;
    f32x4u g0 = *(const f32x4u*)(Gc + (long long)s0 * FO);
    a0 = fmaf(al0, g0[0], a0); a1 = fmaf(al0, g0[1], a1);
    a2 = fmaf(al0, g0[2], a2); a3 = fmaf(al0, g0[3], a3);
  }
#pragma unroll
  for (int off = 32; off >= LPE; off >>= 1) {
    a0 += __shfl_xor(a0, off, 64);
    a1 += __shfl_xor(a1, off, 64);
    a2 += __shfl_xor(a2, off, 64);
    a3 += __shfl_xor(a3, off, 64);
  }
  if (grp == 0) {
    f32x4u bs = *(const f32x4u*)(bias + cl * 4);
    float v0 = fmaxf(a0 + bs[0], 0.0f);
    float v1 = fmaxf(a1 + bs[1], 0.0f);
    float v2 = fmaxf(a2 + bs[2], 0.0f);
    float v3 = fmaxf(a3 + bs[3], 0.0f);
    if (OPK == 1) {
      u32x4 pv;
      pv[0] = packsplit(v0); pv[1] = packsplit(v1);
      pv[2] = packsplit(v2); pv[3] = packsplit(v3);
      *(u32x4*)((unsigned*)outv + (long long)d * ldc + cl * 4) = pv;
    } else {
      f32x4u v; v[0] = v0; v[1] = v1; v[2] = v2; v[3] = v3;
      *(f32x4u*)((float*)outv + (long long)d * ldc + cl * 4) = v;
    }
  }
}

// ============================ LSTM / head ============================

// gates[N x 192] = {i,g,o} (f-gate dead). h written packed u32 for GEMM-A.
__global__ void lstm_act_kernel(const float* __restrict__ gates,
                                const float* __restrict__ bias,
                                unsigned* __restrict__ h, int N) {
  int idx = blockIdx.x * blockDim.x + threadIdx.x;
  if (idx >= N * 16) return;
  int i = idx >> 4, c4 = (idx & 15) * 4;
  const float* g = gates + (long long)i * 192;
  f32x4u gi = *(const f32x4u*)(g + c4);
  f32x4u gg = *(const f32x4u*)(g + 64 + c4);
  f32x4u go = *(const f32x4u*)(g + 128 + c4);
  f32x4u bi = *(const f32x4u*)(bias + c4);
  f32x4u bg = *(const f32x4u*)(bias + 128 + c4);
  f32x4u bo = *(const f32x4u*)(bias + 192 + c4);
  u32x4 hv;
#pragma unroll
  for (int k = 0; k < 4; ++k) {
    float cc = sigm(gi[k] + bi[k]) * tanhf(gg[k] + bg[k]);
    hv[k] = packsplit(sigm(go[k] + bo[k]) * tanhf(cc));
  }
  *(u32x4*)(h + (long long)i * 64 + c4) = hv;
}

__global__ void lin3_kernel(const float* __restrict__ Z, const float* __restrict__ w,
                            const float* __restrict__ b, float* __restrict__ out, int N) {
  int i = blockIdx.x * blockDim.x + threadIdx.x;
  if (i >= N) return;
  const float4* z4 = (const float4*)(Z + (long long)i * 64);
  const float4* w4 = (const float4*)w;
  float acc = 0.0f;
#pragma unroll
  for (int k = 0; k < 16; ++k) {
    float4 a = z4[k], ww = w4[k];
    acc += a.x * ww.x + a.y * ww.y + a.z * ww.z + a.w * ww.w;
  }
  out[i] = acc + b[0];
}

// ============================ launcher ============================

struct WSplit { const short* hi; const short* lo; };

extern "C" void kernel_launch(void* const* d_in, const int* in_sizes, int n_in,
                              void* d_out, int out_size, void* d_ws, size_t ws_size,
                              hipStream_t stream) {
  const int N = 65536, E = 1048576;
  const int Et = E + N;

  const float* x        = (const float*)d_in[0];
  const int*   ei       = (const int*)d_in[1];
  const float* poi1_W   = (const float*)d_in[2];
  const float* poi1_b   = (const float*)d_in[3];
  const float* poi2_W   = (const float*)d_in[4];
  const float* poi2_b   = (const float*)d_in[5];
  const float* svi1_W   = (const float*)d_in[6];
  const float* svi1_b   = (const float*)d_in[7];
  const float* svi2_W   = (const float*)d_in[8];
  const float* svi2_b   = (const float*)d_in[9];
  const float* all1_W   = (const float*)d_in[10];
  const float* all1_b   = (const float*)d_in[11];
  const float* all2_W   = (const float*)d_in[12];
  const float* all2_b   = (const float*)d_in[13];
  const float* gat1_W   = (const float*)d_in[14];
  const float* gat1_b   = (const float*)d_in[15];
  const float* gat1_as  = (const float*)d_in[16];
  const float* gat1_ad  = (const float*)d_in[17];
  const float* gat2_W   = (const float*)d_in[18];
  const float* gat2_b   = (const float*)d_in[19];
  const float* gat2_as  = (const float*)d_in[20];
  const float* gat2_ad  = (const float*)d_in[21];
  const float* gat3_W   = (const float*)d_in[22];
  const float* gat3_b   = (const float*)d_in[23];
  const float* gat3_as  = (const float*)d_in[24];
  const float* gat3_ad  = (const float*)d_in[25];
  const float* lstm_Wih0= (const float*)d_in[26];
  const float* lstm_Wih = (const float*)d_in[27];
  const float* lstm_b   = (const float*)d_in[29];
  const float* time1_W  = (const float*)d_in[30];
  const float* time1_b  = (const float*)d_in[31];
  const float* time2_W  = (const float*)d_in[32];
  const float* time2_b  = (const float*)d_in[33];
  const float* lin1_W   = (const float*)d_in[34];
  const float* lin1_b   = (const float*)d_in[35];
  const float* lin2_W   = (const float*)d_in[36];
  const float* lin2_b   = (const float*)d_in[37];
  const float* lin3_W   = (const float*)d_in[38];
  const float* lin3_b   = (const float*)d_in[39];
  float* out = (float*)d_out;

  // ---- workspace layout (packed u32 buffers are same 4B/elem as fp32) ----
  float* wsf   = (float*)d_ws;
  float* R192  = wsf;                       // N x 192 packed
  float* RA    = R192 + (size_t)N * 192;    // N x 128 (G fp32 / packed)
  float* RA2   = RA + (size_t)N * 64;       // N x 64
  float* RB    = RA + (size_t)N * 128;      // N x 256 (H packed / gates fp32)
  float* Rz    = RB + (size_t)N * 256;      // N x 128 packed (gat3|time)
  float* sArr  = Rz + (size_t)N * 128;
  float* tArr  = sArr + N;
  int* ints      = (int*)(tArr + N);
  int* row_start = ints;
  int* cursor    = row_start + (N + 1);
  int* srcs      = cursor + N;
  int* blockSums = srcs + Et;
  short* pool = (short*)(((uintptr_t)(blockSums + 256) + 15) & ~(uintptr_t)15);

  WJobs jb{};
  int nj = 0, tiles = 0;
  auto split = [&](const float* W, int K, int M, int ldw, int skip) -> WSplit {
    int KC = (K + 31) / 32;
    size_t sz = (size_t)KC * M * 32;
    short* hi = pool; pool += sz;
    short* lo = pool; pool += sz;
    jb.W[nj] = W; jb.hi[nj] = hi; jb.lo[nj] = lo;
    jb.K[nj] = K; jb.M16[nj] = M / 16; jb.ldw[nj] = ldw; jb.skip[nj] = skip;
    jb.tile0[nj] = tiles;
    tiles += KC * (M / 16);
    ++nj;
    return {hi, lo};
  };
  auto gemm = [&](const void* A, int lda, WSplit w, const float* bias,
                  void* C, int ldc, int K, int M, int act, int apk, int opk) {
    int gx = M / 64;
    dim3 grid(gx * (N / 32)), blk(64);
    int KC = (K + 31) / 32, M16 = M / 16;
    if (apk == 0 && opk == 0)
      hipLaunchKernelGGL((gemm_mfma<2, 0, 0>), grid, blk, 0, stream,
                         A, lda, w.hi, w.lo, bias, C, ldc, K, KC, M16, gx, act);
    else if (apk == 0 && opk == 1)
      hipLaunchKernelGGL((gemm_mfma<2, 0, 1>), grid, blk, 0, stream,
                         A, lda, w.hi, w.lo, bias, C, ldc, K, KC, M16, gx, act);
    else if (apk == 1 && opk == 0)
      hipLaunchKernelGGL((gemm_mfma<2, 1, 0>), grid, blk, 0, stream,
                         A, lda, w.hi, w.lo, bias, C, ldc, K, KC, M16, gx, act);
    else
      hipLaunchKernelGGL((gemm_mfma<2, 1, 1>), grid, blk, 0, stream,
                         A, lda, w.hi, w.lo, bias, C, ldc, K, KC, M16, gx, act);
  };

  // ---- register all weight splits, then ONE fused split launch ----
  WSplit wpoi1 = split(poi1_W, 13, 64, 64, 0);
  WSplit wpoi2 = split(poi2_W, 64, 64, 64, 0);
  WSplit wsvi1 = split(svi1_W, 365, 128, 128, 0);
  WSplit wsvi2 = split(svi2_W, 128, 128, 128, 0);
  WSplit wall1 = split(all1_W, 192, 128, 128, 0);
  WSplit wall2 = split(all2_W, 128, 128, 128, 0);
  WSplit wg1   = split(gat1_W, 128, 128, 128, 0);
  WSplit wg2   = split(gat2_W, 128, 128, 128, 0);
  WSplit wg3   = split(gat3_W, 128, 64, 64, 0);
  WSplit wls0  = split(lstm_Wih0, 24, 192, 256, 1);
  WSplit wls1  = split(lstm_Wih, 64, 192, 256, 1);
  WSplit wls2  = split(lstm_Wih + 64 * 256, 64, 192, 256, 1);
  WSplit wt1   = split(time1_W, 64, 64, 64, 0);
  WSplit wt2   = split(time2_W, 64, 64, 64, 0);
  WSplit wl1   = split(lin1_W, 128, 64, 64, 0);
  WSplit wl2   = split(lin2_W, 64, 64, 64, 0);
  hipLaunchKernelGGL(wsplit_all, dim3(tiles), dim3(64), 0, stream, jb, nj);

  const int TB = 256;
  const int edgeBlocks = (Et + TB - 1) / TB;

  // ---- build CSR ----
  hipLaunchKernelGGL(fill_i32_kernel, dim3((N + TB - 1) / TB), dim3(TB), 0, stream,
                     row_start, 0, N);
  hipLaunchKernelGGL(count_edges_kernel, dim3(edgeBlocks), dim3(TB), 0, stream,
                     ei, row_start, E, N);
  hipLaunchKernelGGL(scan1_kernel, dim3(N / 256), dim3(256), 0, stream,
                     row_start, blockSums);
  hipLaunchKernelGGL(scan2_kernel, dim3(1), dim3(256), 0, stream, blockSums);
  hipLaunchKernelGGL(scan3_kernel, dim3(N / 256), dim3(256), 0, stream,
                     row_start, cursor, blockSums, N, Et);
  hipLaunchKernelGGL(scatter_kernel, dim3(edgeBlocks), dim3(TB), 0, stream,
                     ei, cursor, srcs, E, N);

  // ---- MLP towers (internal tensors packed) ----
  gemm(x + 3, 445, wpoi1, poi1_b, RA, 64, 13, 64, 1, 0, 1);
  gemm(RA, 64, wpoi2, poi2_b, R192, 192, 64, 64, 1, 1, 1);
  gemm(x + 56, 445, wsvi1, svi1_b, RB, 128, 365, 128, 1, 0, 1);
  gemm(RB, 128, wsvi2, svi2_b, R192 + 64, 192, 128, 128, 1, 1, 1);
  gemm(R192, 192, wall1, all1_b, RA, 128, 192, 128, 1, 1, 1);
  gemm(RA, 128, wall2, all2_b, RB, 128, 128, 128, 1, 1, 1);  // H packed -> RB

  const int aggBlocks = N / 4;

  // ---- GAT1: H(pk) -> G(fp32) -> agg -> H2(pk) ----
  gemm(RB, 128, wg1, nullptr, RA, 128, 128, 128, 0, 1, 0);
  hipLaunchKernelGGL((st_kernel<128>), dim3(N / 8), dim3(256), 0, stream,
                     RA, gat1_as, gat1_ad, sArr, tArr, N);
  hipLaunchKernelGGL((gat_agg<128, 1>), dim3(aggBlocks), dim3(256), 0, stream,
                     RA, sArr, tArr, row_start, srcs, gat1_b, RB, 128);
  // ---- GAT2 ----
  gemm(RB, 128, wg2, nullptr, RA, 128, 128, 128, 0, 1, 0);
  hipLaunchKernelGGL((st_kernel<128>), dim3(N / 8), dim3(256), 0, stream,
                     RA, gat2_as, gat2_ad, sArr, tArr, N);
  hipLaunchKernelGGL((gat_agg<128, 1>), dim3(aggBlocks), dim3(256), 0, stream,
                     RA, sArr, tArr, row_start, srcs, gat2_b, RB, 128);
  // ---- GAT3 (fo=64 -> Rz cols 0..63 packed) ----
  gemm(RB, 128, wg3, nullptr, RA, 64, 128, 64, 0, 1, 0);
  hipLaunchKernelGGL((st_kernel<64>), dim3(N / 16), dim3(256), 0, stream,
                     RA, gat3_as, gat3_ad, sArr, tArr, N);
  hipLaunchKernelGGL((gat_agg<64, 1>), dim3(aggBlocks), dim3(256), 0, stream,
                     RA, sArr, tArr, row_start, srcs, gat3_b, Rz, 128);

  // ---- "LSTM": layers 0..2, f-gate skipped; h tensors packed ----
  const int actBlocks = (N * 16 + TB - 1) / TB;
  gemm(x + 421, 445, wls0, nullptr, RB, 192, 24, 192, 0, 0, 0);
  hipLaunchKernelGGL(lstm_act_kernel, dim3(actBlocks), dim3(TB), 0, stream,
                     RB, lstm_b, (unsigned*)RA, N);
  gemm(RA, 64, wls1, nullptr, RB, 192, 64, 192, 0, 1, 0);
  hipLaunchKernelGGL(lstm_act_kernel, dim3(actBlocks), dim3(TB), 0, stream,
                     RB, lstm_b + 256, (unsigned*)RA2, N);
  gemm(RA2, 64, wls2, nullptr, RB, 192, 64, 192, 0, 1, 0);
  hipLaunchKernelGGL(lstm_act_kernel, dim3(actBlocks), dim3(TB), 0, stream,
                     RB, lstm_b + 512, (unsigned*)RA, N);

  // ---- time MLP -> Rz cols 64..127 packed ----
  gemm(RA, 64, wt1, time1_b, RA2, 64, 64, 64, 1, 1, 1);
  gemm(RA2, 64, wt2, time2_b, Rz + 64, 128, 64, 64, 1, 1, 1);

  // ---- head ----
  gemm(Rz, 128, wl1, lin1_b, RA, 64, 128, 64, 1, 1, 1);
  gemm(RA, 64, wl2, lin2_b, RA2, 64, 64, 64, 1, 1, 0);  // fp32 for lin3
  hipLaunchKernelGGL(lin3_kernel, dim3((N + TB - 1) / TB), dim3(TB), 0, stream,
                     RA2, lin3_W, lin3_b, out, N);
}

// Round 12
// 804.850 us; speedup vs baseline: 2.6553x; 1.1107x over previous
//
#include <hip/hip_runtime.h>
#include <math.h>

#define DEV __device__ __forceinline__

typedef __attribute__((ext_vector_type(8))) short short8;   // 8 bf16 (4 VGPRs)
typedef __attribute__((ext_vector_type(4))) float f32x4;    // MFMA acc
typedef float f32x4u __attribute__((ext_vector_type(4), aligned(4)));
typedef __attribute__((ext_vector_type(4))) unsigned int u32x4;

#define NEG_BIG (-3.0e38f)
#define CAPB 4096   // bucket capacity (mean 2176, +40 sigma)
#define CHUNK 4096  // edges staged per bucket_bin block

DEV float sigm(float x) { return 1.0f / (1.0f + __expf(-x)); }
DEV float leaky(float e) { return (e >= 0.0f) ? e : 0.2f * e; }

// split 8 fp32 -> bf16 hi (truncate) + bf16 lo (truncate of exact residual)
DEV void split_bf16(const float f[8], short8& hi, short8& lo) {
#pragma unroll
  for (int i = 0; i < 8; ++i) {
    unsigned u = __builtin_bit_cast(unsigned, f[i]);
    hi[i] = (short)(u >> 16);
    float h = __builtin_bit_cast(float, u & 0xffff0000u);
    float r = f[i] - h;  // exact (Dekker)
    lo[i] = (short)(__builtin_bit_cast(unsigned, r) >> 16);
  }
}

// fp32 -> packed u32 (bf16hi<<16 | bf16lo); numerics identical to split_bf16
DEV unsigned packsplit(float v) {
  unsigned u = __builtin_bit_cast(unsigned, v);
  unsigned hf = u & 0xffff0000u;
  float r = v - __builtin_bit_cast(float, hf);
  return hf | (__builtin_bit_cast(unsigned, r) >> 16);
}

// unpack 8 packed u32 -> hi/lo short8 via v_perm
DEV void unpack_pk(const u32x4 p0, const u32x4 p1, short8& hi, short8& lo) {
  u32x4 h, l;
  h[0] = __builtin_amdgcn_perm(p0[1], p0[0], 0x07060302u);
  h[1] = __builtin_amdgcn_perm(p0[3], p0[2], 0x07060302u);
  h[2] = __builtin_amdgcn_perm(p1[1], p1[0], 0x07060302u);
  h[3] = __builtin_amdgcn_perm(p1[3], p1[2], 0x07060302u);
  l[0] = __builtin_amdgcn_perm(p0[1], p0[0], 0x05040100u);
  l[1] = __builtin_amdgcn_perm(p0[3], p0[2], 0x05040100u);
  l[2] = __builtin_amdgcn_perm(p1[1], p1[0], 0x05040100u);
  l[3] = __builtin_amdgcn_perm(p1[3], p1[2], 0x05040100u);
  hi = __builtin_bit_cast(short8, h);
  lo = __builtin_bit_cast(short8, l);
}

// ============================ utility kernels ============================

__global__ void fill_i32_kernel(int* p, int v, int n) {
  int i = blockIdx.x * blockDim.x + threadIdx.x;
  if (i < n) p[i] = v;
}

// ============================ bucketed CSR build ============================
// Pass 1: bin edges by dst>>7 into 512 fixed-stride regions. Per-block LDS
// histogram + one global atomicAdd per (block,bucket) reservation -> each
// block writes contiguous ~32B runs (kills the 16x line-amplification the
// old per-edge atomic scatter had: 74MB -> ~9MB HBM writes).
__global__ __launch_bounds__(256) void bucket_bin(
    const int* __restrict__ ei, int* __restrict__ bucket_cnt,
    unsigned* __restrict__ ebuf, int E, int Et) {
  __shared__ unsigned stage[CHUNK];  // 16 KB
  __shared__ int hist[512], rbase[512], lcur[512];
  const int tid = threadIdx.x;
  const long long e0 = (long long)blockIdx.x * CHUNK;
  const int nalive = (int)((Et - e0) < CHUNK ? (Et - e0) : CHUNK);
  for (int i = tid; i < 512; i += 256) hist[i] = 0;
  __syncthreads();
  for (int k = tid; k < nalive; k += 256) {
    long long e = e0 + k;
    int s, d;
    if (e < E) { s = ei[e]; d = ei[E + e]; } else { s = (int)(e - E); d = s; }
    unsigned p = (unsigned)s | ((unsigned)d << 16);  // src:16b | dst:16b
    stage[k] = p;
    atomicAdd(&hist[d >> 7], 1);
  }
  __syncthreads();
  for (int i = tid; i < 512; i += 256) {
    int c = hist[i];
    rbase[i] = c ? atomicAdd(&bucket_cnt[i], c) : 0;
    lcur[i] = 0;
  }
  __syncthreads();
  for (int k = tid; k < nalive; k += 256) {
    unsigned p = stage[k];
    int b = (int)(p >> 23);  // dst>>7
    int lofs = atomicAdd(&lcur[b], 1);
    int pos = rbase[b] + lofs;
    if (pos < CAPB) ebuf[(long long)b * CAPB + pos] = p;
  }
}

// Pass 2: exclusive scan of 512 bucket counts (single block)
__global__ __launch_bounds__(512) void bucket_scan(
    const int* __restrict__ cnt, int* __restrict__ start, int Et) {
  __shared__ int sh[512];
  int tid = threadIdx.x;
  int v = cnt[tid];
  sh[tid] = v;
  __syncthreads();
  int val = v;
  for (int off = 1; off < 512; off <<= 1) {
    int add = (tid >= off) ? sh[tid - off] : 0;
    __syncthreads();
    val += add;
    sh[tid] = val;
    __syncthreads();
  }
  start[tid] = val - v;
  if (tid == 511) start[512] = Et;
}

// Pass 3: per bucket (512 blocks x 128 thr): local 128-dst histogram+scan ->
// row_start + compacted srcs. Each bucket's srcs region written by exactly
// one block -> single-XCD dirty lines, no write amplification.
__global__ __launch_bounds__(128) void bucket_csr(
    const unsigned* __restrict__ ebuf, const int* __restrict__ bucket_cnt,
    const int* __restrict__ bucket_start, int* __restrict__ row_start,
    int* __restrict__ srcs, int N, int Et) {
  __shared__ unsigned stage[CAPB];  // 16 KB
  __shared__ int hist[128], hbase[128], lcur[128];
  const int b = blockIdx.x, tid = threadIdx.x;
  int cnt = bucket_cnt[b];
  cnt = cnt < CAPB ? cnt : CAPB;
  const int gbase = bucket_start[b];
  hist[tid] = 0;
  __syncthreads();
  const unsigned* eb = ebuf + (long long)b * CAPB;
  for (int k = tid; k < cnt; k += 128) {
    unsigned p = eb[k];
    stage[k] = p;
    atomicAdd(&hist[(p >> 16) & 127], 1);
  }
  __syncthreads();
  // exclusive scan over 128
  int v = hist[tid];
  hbase[tid] = v;
  __syncthreads();
  int val = v;
  for (int off = 1; off < 128; off <<= 1) {
    int add = (tid >= off) ? hbase[tid - off] : 0;
    __syncthreads();
    val += add;
    hbase[tid] = val;
    __syncthreads();
  }
  int ex = val - v;
  row_start[b * 128 + tid] = gbase + ex;
  __syncthreads();
  hbase[tid] = ex;
  lcur[tid] = 0;
  __syncthreads();
  for (int k = tid; k < cnt; k += 128) {
    unsigned p = stage[k];
    int o = (p >> 16) & 127;
    int lofs = atomicAdd(&lcur[o], 1);
    srcs[gbase + hbase[o] + lofs] = (int)(p & 0xffffu);
  }
  if (b == 0 && tid == 0) row_start[N] = Et;
}

// ============================ fused W pre-split ============================
struct WJobs {
  const float* W[16];
  short* hi[16];
  short* lo[16];
  int K[16];
  int M16[16];
  int ldw[16];
  int skip[16];
  int tile0[16];
};

__global__ __launch_bounds__(64) void wsplit_all(WJobs jb, int njobs) {
  int b = blockIdx.x;
  int ji = 0;
#pragma unroll
  for (int i = 1; i < 16; ++i)
    if (i < njobs && b >= jb.tile0[i]) ji = i;
  int t = b - jb.tile0[ji];
  int M16 = jb.M16[ji];
  int kc = t / M16, ntG = t % M16;
  int K = jb.K[ji], ldw = jb.ldw[ji];
  const float* __restrict__ W = jb.W[ji];

  int lane = threadIdx.x;
  int kb = kc * 32 + (lane >> 4) * 8;
  int c = ntG * 16 + (lane & 15);
  if (jb.skip[ji] && c >= 64) c += 64;  // skip dead f-gate columns
  float f[8];
#pragma unroll
  for (int j = 0; j < 8; ++j) {
    int k = kb + j;
    f[j] = (k < K) ? W[(long long)k * ldw + c] : 0.0f;
  }
  short8 h, l;
  split_bf16(f, h, l);
  long long off = ((long long)t * 64 + lane) * 8;
  *(short8*)(jb.hi[ji] + off) = h;
  *(short8*)(jb.lo[ji] + off) = l;
}

// ============================ MFMA GEMM ============================
template <int MT, int APK, int OPK>
__global__ __launch_bounds__(64) void gemm_mfma(
    const void* __restrict__ Av, int lda,
    const short* __restrict__ wh, const short* __restrict__ wl,
    const float* __restrict__ bias,
    void* __restrict__ Cv, int ldc,
    int K, int KC, int M16, int gx, int act) {
  const int lane = threadIdx.x;
  const int m = lane & 15, q = lane >> 4;
  const int b = blockIdx.x;
  const int x = (b >> 3) % gx;
  const int y = ((b >> 3) / gx) * 8 + (b & 7);
  const long long r0 = (long long)y * (MT * 16);
  const int ntG0 = x * 4;

  f32x4 acc[MT][4];
#pragma unroll
  for (int i = 0; i < MT; ++i)
#pragma unroll
    for (int j = 0; j < 4; ++j) acc[i][j] = (f32x4)(0.0f);

  for (int kc = 0; kc < KC; ++kc) {
    short8 bh[4], bl[4];
#pragma unroll
    for (int nt = 0; nt < 4; ++nt) {
      long long off = (((long long)kc * M16 + (ntG0 + nt)) * 64 + lane) * 8;
      bh[nt] = *(const short8*)(wh + off);
      bl[nt] = *(const short8*)(wl + off);
    }
    short8 ah[MT], al[MT];
#pragma unroll
    for (int mt = 0; mt < MT; ++mt) {
      if (APK == 1) {
        const unsigned* ap = (const unsigned*)Av + (r0 + mt * 16 + m) * lda + kc * 32 + q * 8;
        u32x4 p0 = *(const u32x4*)ap;
        u32x4 p1 = *(const u32x4*)(ap + 4);
        unpack_pk(p0, p1, ah[mt], al[mt]);
      } else {
        const float* ap = (const float*)Av + (r0 + mt * 16 + m) * lda + kc * 32 + q * 8;
        float f[8];
        const bool full = (kc * 32 + 32 <= K);
        if (full) {
          f32x4u p0 = *(const f32x4u*)ap;
          f32x4u p1 = *(const f32x4u*)(ap + 4);
#pragma unroll
          for (int j = 0; j < 4; ++j) { f[j] = p0[j]; f[4 + j] = p1[j]; }
        } else {
#pragma unroll
          for (int j = 0; j < 8; ++j) {
            int k = kc * 32 + q * 8 + j;
            f[j] = (k < K) ? ap[j] : 0.0f;
          }
        }
        split_bf16(f, ah[mt], al[mt]);
      }
    }
#pragma unroll
    for (int mt = 0; mt < MT; ++mt)
#pragma unroll
      for (int nt = 0; nt < 4; ++nt) {
        acc[mt][nt] = __builtin_amdgcn_mfma_f32_16x16x32_bf16(ah[mt], bh[nt], acc[mt][nt], 0, 0, 0);
        acc[mt][nt] = __builtin_amdgcn_mfma_f32_16x16x32_bf16(ah[mt], bl[nt], acc[mt][nt], 0, 0, 0);
        acc[mt][nt] = __builtin_amdgcn_mfma_f32_16x16x32_bf16(al[mt], bh[nt], acc[mt][nt], 0, 0, 0);
      }
  }

#pragma unroll
  for (int nt = 0; nt < 4; ++nt) {
    int col = (ntG0 + nt) * 16 + m;
    float bsv = bias ? bias[col] : 0.0f;
#pragma unroll
    for (int mt = 0; mt < MT; ++mt) {
      long long rb = r0 + mt * 16 + q * 4;
#pragma unroll
      for (int reg = 0; reg < 4; ++reg) {
        float v = acc[mt][nt][reg] + bsv;
        if (act == 1) v = fmaxf(v, 0.0f);
        if (OPK == 1)
          ((unsigned*)Cv)[(rb + reg) * ldc + col] = packsplit(v);
        else
          ((float*)Cv)[(rb + reg) * ldc + col] = v;
      }
    }
  }
}

// ============================ GAT helpers ============================

template <int FO>
__global__ __launch_bounds__(256) void st_kernel(
    const float* __restrict__ G, const float* __restrict__ asrc,
    const float* __restrict__ adst, float* __restrict__ s, float* __restrict__ t,
    int N) {
  constexpr int LPN = FO / 4;
  int wv = (blockIdx.x * blockDim.x + threadIdx.x) >> 6;
  int lane = threadIdx.x & 63;
  int sub = lane / LPN, cl = lane % LPN;
  long long node = (long long)wv * (64 / LPN) + sub;
  f32x4u g = *(const f32x4u*)(G + node * FO + cl * 4);
  f32x4u a = *(const f32x4u*)(asrc + cl * 4);
  f32x4u ad = *(const f32x4u*)(adst + cl * 4);
  float ps = g[0] * a[0] + g[1] * a[1] + g[2] * a[2] + g[3] * a[3];
  float pt = g[0] * ad[0] + g[1] * ad[1] + g[2] * ad[2] + g[3] * ad[3];
#pragma unroll
  for (int off = LPN / 2; off; off >>= 1) {
    ps += __shfl_xor(ps, off, 64);
    pt += __shfl_xor(pt, off, 64);
  }
  if (cl == 0) { s[node] = ps; t[node] = pt; }
}

// Fused per-dst softmax + gather. One wave per dst (4 dst per block).
template <int FO, int OPK>
__global__ __launch_bounds__(256) void gat_agg(
    const float* __restrict__ G, const float* __restrict__ s,
    const float* __restrict__ t, const int* __restrict__ row_start,
    const int* __restrict__ srcs, const float* __restrict__ bias,
    void* __restrict__ outv, int ldc) {
  constexpr int CAP = 128;
  constexpr int LPE = FO / 4;
  constexpr int EPW = 64 / LPE;
  __shared__ float ecache[4][CAP];
  const int wv = threadIdx.x >> 6;
  const int lane = threadIdx.x & 63;
  const int d = blockIdx.x * 4 + wv;
  const int start = row_start[d], end = row_start[d + 1];
  const float td = t[d];

  float m = NEG_BIG, dsum = 0.0f;
  for (int j = start + lane; j < end; j += 64) {
    float e = leaky(s[srcs[j]] + td);
    int idx = j - start;
    if (idx < CAP) ecache[wv][idx] = e;
    float mn = fmaxf(m, e);
    dsum = dsum * __expf(m - mn) + __expf(e - mn);
    m = mn;
  }
#pragma unroll
  for (int off = 32; off; off >>= 1) {
    float mo = __shfl_xor(m, off, 64);
    float dso = __shfl_xor(dsum, off, 64);
    float mn = fmaxf(m, mo);
    dsum = dsum * __expf(m - mn) + dso * __expf(mo - mn);
    m = mn;
  }
  const float inv = 1.0f / dsum;

  const int deg = end - start;
  const int capdeg = deg < CAP ? deg : CAP;
  for (int idx = lane; idx < capdeg; idx += 64)
    ecache[wv][idx] = __expf(ecache[wv][idx] - m) * inv;
  __syncthreads();

  const int grp = lane / LPE, cl = lane % LPE;
  const float* __restrict__ Gc = G + cl * 4;
  float a0 = 0.0f, a1 = 0.0f, a2 = 0.0f, a3 = 0.0f;
  int j = start + grp;
  for (; j + EPW < end; j += 2 * EPW) {
    int s0 = srcs[j], s1 = srcs[j + EPW];
    int i0 = j - start, i1 = i0 + EPW;
    float al0 = (i0 < CAP) ? ecache[wv][i0]
                           : __expf(leaky(s[s0] + td) - m) * inv;
    float al1 = (i1 < CAP) ? ecache[wv][i1]
                           : __expf(leaky(s[s1] + td) - m) * inv;
    f32x4u g0 = *(const f32x4u*)(Gc + (long long)s0 * FO);
    f32x4u g1 = *(const f32x4u*)(Gc + (long long)s1 * FO);
    a0 = fmaf(al0, g0[0], a0); a1 = fmaf(al0, g0[1], a1);
    a2 = fmaf(al0, g0[2], a2); a3 = fmaf(al0, g0[3], a3);
    a0 = fmaf(al1, g1[0], a0); a1 = fmaf(al1, g1[1], a1);
    a2 = fmaf(al1, g1[2], a2); a3 = fmaf(al1, g1[3], a3);
  }
  if (j < end) {
    int s0 = srcs[j];
    int i0 = j - start;
    float al0 = (i0 < CAP) ? ecache[wv][i0]
                           : __expf(leaky(s[s0] + td) - m) * inv;
    f32x4u g0 = *(const f32x4u*)(Gc + (long long)s0 * FO);
    a0 = fmaf(al0, g0[0], a0); a1 = fmaf(al0, g0[1], a1);
    a2 = fmaf(al0, g0[2], a2); a3 = fmaf(al0, g0[3], a3);
  }
#pragma unroll
  for (int off = 32; off >= LPE; off >>= 1) {
    a0 += __shfl_xor(a0, off, 64);
    a1 += __shfl_xor(a1, off, 64);
    a2 += __shfl_xor(a2, off, 64);
    a3 += __shfl_xor(a3, off, 64);
  }
  if (grp == 0) {
    f32x4u bs = *(const f32x4u*)(bias + cl * 4);
    float v0 = fmaxf(a0 + bs[0], 0.0f);
    float v1 = fmaxf(a1 + bs[1], 0.0f);
    float v2 = fmaxf(a2 + bs[2], 0.0f);
    float v3 = fmaxf(a3 + bs[3], 0.0f);
    if (OPK == 1) {
      u32x4 pv;
      pv[0] = packsplit(v0); pv[1] = packsplit(v1);
      pv[2] = packsplit(v2); pv[3] = packsplit(v3);
      *(u32x4*)((unsigned*)outv + (long long)d * ldc + cl * 4) = pv;
    } else {
      f32x4u v; v[0] = v0; v[1] = v1; v[2] = v2; v[3] = v3;
      *(f32x4u*)((float*)outv + (long long)d * ldc + cl * 4) = v;
    }
  }
}

// ============================ LSTM / head ============================

__global__ void lstm_act_kernel(const float* __restrict__ gates,
                                const float* __restrict__ bias,
                                unsigned* __restrict__ h, int N) {
  int idx = blockIdx.x * blockDim.x + threadIdx.x;
  if (idx >= N * 16) return;
  int i = idx >> 4, c4 = (idx & 15) * 4;
  const float* g = gates + (long long)i * 192;
  f32x4u gi = *(const f32x4u*)(g + c4);
  f32x4u gg = *(const f32x4u*)(g + 64 + c4);
  f32x4u go = *(const f32x4u*)(g + 128 + c4);
  f32x4u bi = *(const f32x4u*)(bias + c4);
  f32x4u bg = *(const f32x4u*)(bias + 128 + c4);
  f32x4u bo = *(const f32x4u*)(bias + 192 + c4);
  u32x4 hv;
#pragma unroll
  for (int k = 0; k < 4; ++k) {
    float cc = sigm(gi[k] + bi[k]) * tanhf(gg[k] + bg[k]);
    hv[k] = packsplit(sigm(go[k] + bo[k]) * tanhf(cc));
  }
  *(u32x4*)(h + (long long)i * 64 + c4) = hv;
}

__global__ void lin3_kernel(const float* __restrict__ Z, const float* __restrict__ w,
                            const float* __restrict__ b, float* __restrict__ out, int N) {
  int i = blockIdx.x * blockDim.x + threadIdx.x;
  if (i >= N) return;
  const float4* z4 = (const float4*)(Z + (long long)i * 64);
  const float4* w4 = (const float4*)w;
  float acc = 0.0f;
#pragma unroll
  for (int k = 0; k < 16; ++k) {
    float4 a = z4[k], ww = w4[k];
    acc += a.x * ww.x + a.y * ww.y + a.z * ww.z + a.w * ww.w;
  }
  out[i] = acc + b[0];
}

// ============================ launcher ============================

struct WSplit { const short* hi; const short* lo; };

extern "C" void kernel_launch(void* const* d_in, const int* in_sizes, int n_in,
                              void* d_out, int out_size, void* d_ws, size_t ws_size,
                              hipStream_t stream) {
  const int N = 65536, E = 1048576;
  const int Et = E + N;

  const float* x        = (const float*)d_in[0];
  const int*   ei       = (const int*)d_in[1];
  const float* poi1_W   = (const float*)d_in[2];
  const float* poi1_b   = (const float*)d_in[3];
  const float* poi2_W   = (const float*)d_in[4];
  const float* poi2_b   = (const float*)d_in[5];
  const float* svi1_W   = (const float*)d_in[6];
  const float* svi1_b   = (const float*)d_in[7];
  const float* svi2_W   = (const float*)d_in[8];
  const float* svi2_b   = (const float*)d_in[9];
  const float* all1_W   = (const float*)d_in[10];
  const float* all1_b   = (const float*)d_in[11];
  const float* all2_W   = (const float*)d_in[12];
  const float* all2_b   = (const float*)d_in[13];
  const float* gat1_W   = (const float*)d_in[14];
  const float* gat1_b   = (const float*)d_in[15];
  const float* gat1_as  = (const float*)d_in[16];
  const float* gat1_ad  = (const float*)d_in[17];
  const float* gat2_W   = (const float*)d_in[18];
  const float* gat2_b   = (const float*)d_in[19];
  const float* gat2_as  = (const float*)d_in[20];
  const float* gat2_ad  = (const float*)d_in[21];
  const float* gat3_W   = (const float*)d_in[22];
  const float* gat3_b   = (const float*)d_in[23];
  const float* gat3_as  = (const float*)d_in[24];
  const float* gat3_ad  = (const float*)d_in[25];
  const float* lstm_Wih0= (const float*)d_in[26];
  const float* lstm_Wih = (const float*)d_in[27];
  const float* lstm_b   = (const float*)d_in[29];
  const float* time1_W  = (const float*)d_in[30];
  const float* time1_b  = (const float*)d_in[31];
  const float* time2_W  = (const float*)d_in[32];
  const float* time2_b  = (const float*)d_in[33];
  const float* lin1_W   = (const float*)d_in[34];
  const float* lin1_b   = (const float*)d_in[35];
  const float* lin2_W   = (const float*)d_in[36];
  const float* lin2_b   = (const float*)d_in[37];
  const float* lin3_W   = (const float*)d_in[38];
  const float* lin3_b   = (const float*)d_in[39];
  float* out = (float*)d_out;

  // ---- workspace layout ----
  float* wsf   = (float*)d_ws;
  float* R192  = wsf;
  float* RA    = R192 + (size_t)N * 192;
  float* RA2   = RA + (size_t)N * 64;
  float* RB    = RA + (size_t)N * 128;
  float* Rz    = RB + (size_t)N * 256;
  float* sArr  = Rz + (size_t)N * 128;
  float* tArr  = sArr + N;
  int* ints         = (int*)(tArr + N);
  int* row_start    = ints;                        // N+1
  int* srcs         = row_start + (N + 1);         // Et
  int* bucket_cnt   = srcs + Et;                   // 512
  int* bucket_start = bucket_cnt + 512;            // 513
  unsigned* ebuf    = (unsigned*)(bucket_start + 513);  // 512*CAPB (8MB)
  short* pool = (short*)(((uintptr_t)(ebuf + 512 * CAPB) + 15) & ~(uintptr_t)15);

  WJobs jb{};
  int nj = 0, tiles = 0;
  auto split = [&](const float* W, int K, int M, int ldw, int skip) -> WSplit {
    int KC = (K + 31) / 32;
    size_t sz = (size_t)KC * M * 32;
    short* hi = pool; pool += sz;
    short* lo = pool; pool += sz;
    jb.W[nj] = W; jb.hi[nj] = hi; jb.lo[nj] = lo;
    jb.K[nj] = K; jb.M16[nj] = M / 16; jb.ldw[nj] = ldw; jb.skip[nj] = skip;
    jb.tile0[nj] = tiles;
    tiles += KC * (M / 16);
    ++nj;
    return {hi, lo};
  };
  auto gemm = [&](const void* A, int lda, WSplit w, const float* bias,
                  void* C, int ldc, int K, int M, int act, int apk, int opk) {
    int gx = M / 64;
    dim3 grid(gx * (N / 32)), blk(64);
    int KC = (K + 31) / 32, M16 = M / 16;
    if (apk == 0 && opk == 0)
      hipLaunchKernelGGL((gemm_mfma<2, 0, 0>), grid, blk, 0, stream,
                         A, lda, w.hi, w.lo, bias, C, ldc, K, KC, M16, gx, act);
    else if (apk == 0 && opk == 1)
      hipLaunchKernelGGL((gemm_mfma<2, 0, 1>), grid, blk, 0, stream,
                         A, lda, w.hi, w.lo, bias, C, ldc, K, KC, M16, gx, act);
    else if (apk == 1 && opk == 0)
      hipLaunchKernelGGL((gemm_mfma<2, 1, 0>), grid, blk, 0, stream,
                         A, lda, w.hi, w.lo, bias, C, ldc, K, KC, M16, gx, act);
    else
      hipLaunchKernelGGL((gemm_mfma<2, 1, 1>), grid, blk, 0, stream,
                         A, lda, w.hi, w.lo, bias, C, ldc, K, KC, M16, gx, act);
  };

  // ---- register all weight splits, then ONE fused split launch ----
  WSplit wpoi1 = split(poi1_W, 13, 64, 64, 0);
  WSplit wpoi2 = split(poi2_W, 64, 64, 64, 0);
  WSplit wsvi1 = split(svi1_W, 365, 128, 128, 0);
  WSplit wsvi2 = split(svi2_W, 128, 128, 128, 0);
  WSplit wall1 = split(all1_W, 192, 128, 128, 0);
  WSplit wall2 = split(all2_W, 128, 128, 128, 0);
  WSplit wg1   = split(gat1_W, 128, 128, 128, 0);
  WSplit wg2   = split(gat2_W, 128, 128, 128, 0);
  WSplit wg3   = split(gat3_W, 128, 64, 64, 0);
  WSplit wls0  = split(lstm_Wih0, 24, 192, 256, 1);
  WSplit wls1  = split(lstm_Wih, 64, 192, 256, 1);
  WSplit wls2  = split(lstm_Wih + 64 * 256, 64, 192, 256, 1);
  WSplit wt1   = split(time1_W, 64, 64, 64, 0);
  WSplit wt2   = split(time2_W, 64, 64, 64, 0);
  WSplit wl1   = split(lin1_W, 128, 64, 64, 0);
  WSplit wl2   = split(lin2_W, 64, 64, 64, 0);
  hipLaunchKernelGGL(wsplit_all, dim3(tiles), dim3(64), 0, stream, jb, nj);

  const int TB = 256;

  // ---- build CSR via bucketed counting sort ----
  hipLaunchKernelGGL(fill_i32_kernel, dim3(2), dim3(TB), 0, stream,
                     bucket_cnt, 0, 512);
  hipLaunchKernelGGL(bucket_bin, dim3((Et + CHUNK - 1) / CHUNK), dim3(256),
                     0, stream, ei, bucket_cnt, ebuf, E, Et);
  hipLaunchKernelGGL(bucket_scan, dim3(1), dim3(512), 0, stream,
                     bucket_cnt, bucket_start, Et);
  hipLaunchKernelGGL(bucket_csr, dim3(512), dim3(128), 0, stream,
                     ebuf, bucket_cnt, bucket_start, row_start, srcs, N, Et);

  // ---- MLP towers (internal tensors packed) ----
  gemm(x + 3, 445, wpoi1, poi1_b, RA, 64, 13, 64, 1, 0, 1);
  gemm(RA, 64, wpoi2, poi2_b, R192, 192, 64, 64, 1, 1, 1);
  gemm(x + 56, 445, wsvi1, svi1_b, RB, 128, 365, 128, 1, 0, 1);
  gemm(RB, 128, wsvi2, svi2_b, R192 + 64, 192, 128, 128, 1, 1, 1);
  gemm(R192, 192, wall1, all1_b, RA, 128, 192, 128, 1, 1, 1);
  gemm(RA, 128, wall2, all2_b, RB, 128, 128, 128, 1, 1, 1);

  const int aggBlocks = N / 4;

  // ---- GAT1 ----
  gemm(RB, 128, wg1, nullptr, RA, 128, 128, 128, 0, 1, 0);
  hipLaunchKernelGGL((st_kernel<128>), dim3(N / 8), dim3(256), 0, stream,
                     RA, gat1_as, gat1_ad, sArr, tArr, N);
  hipLaunchKernelGGL((gat_agg<128, 1>), dim3(aggBlocks), dim3(256), 0, stream,
                     RA, sArr, tArr, row_start, srcs, gat1_b, RB, 128);
  // ---- GAT2 ----
  gemm(RB, 128, wg2, nullptr, RA, 128, 128, 128, 0, 1, 0);
  hipLaunchKernelGGL((st_kernel<128>), dim3(N / 8), dim3(256), 0, stream,
                     RA, gat2_as, gat2_ad, sArr, tArr, N);
  hipLaunchKernelGGL((gat_agg<128, 1>), dim3(aggBlocks), dim3(256), 0, stream,
                     RA, sArr, tArr, row_start, srcs, gat2_b, RB, 128);
  // ---- GAT3 (fo=64 -> Rz cols 0..63 packed) ----
  gemm(RB, 128, wg3, nullptr, RA, 64, 128, 64, 0, 1, 0);
  hipLaunchKernelGGL((st_kernel<64>), dim3(N / 16), dim3(256), 0, stream,
                     RA, gat3_as, gat3_ad, sArr, tArr, N);
  hipLaunchKernelGGL((gat_agg<64, 1>), dim3(aggBlocks), dim3(256), 0, stream,
                     RA, sArr, tArr, row_start, srcs, gat3_b, Rz, 128);

  // ---- "LSTM": layers 0..2, f-gate skipped; h tensors packed ----
  const int actBlocks = (N * 16 + TB - 1) / TB;
  gemm(x + 421, 445, wls0, nullptr, RB, 192, 24, 192, 0, 0, 0);
  hipLaunchKernelGGL(lstm_act_kernel, dim3(actBlocks), dim3(TB), 0, stream,
                     RB, lstm_b, (unsigned*)RA, N);
  gemm(RA, 64, wls1, nullptr, RB, 192, 64, 192, 0, 1, 0);
  hipLaunchKernelGGL(lstm_act_kernel, dim3(actBlocks), dim3(TB), 0, stream,
                     RB, lstm_b + 256, (unsigned*)RA2, N);
  gemm(RA2, 64, wls2, nullptr, RB, 192, 64, 192, 0, 1, 0);
  hipLaunchKernelGGL(lstm_act_kernel, dim3(actBlocks), dim3(TB), 0, stream,
                     RB, lstm_b + 512, (unsigned*)RA, N);

  // ---- time MLP -> Rz cols 64..127 packed ----
  gemm(RA, 64, wt1, time1_b, RA2, 64, 64, 64, 1, 1, 1);
  gemm(RA2, 64, wt2, time2_b, Rz + 64, 128, 64, 64, 1, 1, 1);

  // ---- head ----
  gemm(Rz, 128, wl1, lin1_b, RA, 64, 128, 64, 1, 1, 1);
  gemm(RA, 64, wl2, lin2_b, RA2, 64, 64, 64, 1, 1, 0);
  hipLaunchKernelGGL(lin3_kernel, dim3((N + TB - 1) / TB), dim3(TB), 0, stream,
                     RA2, lin3_W, lin3_b, out, N);
}

// Round 13
// 778.512 us; speedup vs baseline: 2.7452x; 1.0338x over previous
//
#include <hip/hip_runtime.h>
#include <math.h>

#define DEV __device__ __forceinline__

typedef __attribute__((ext_vector_type(8))) short short8;   // 8 bf16 (4 VGPRs)
typedef __attribute__((ext_vector_type(4))) float f32x4;    // MFMA acc
typedef float f32x4u __attribute__((ext_vector_type(4), aligned(4)));
typedef __attribute__((ext_vector_type(4))) unsigned int u32x4;

#define NEG_BIG (-3.0e38f)
#define CAPB 4096   // bucket capacity (mean 2176, +40 sigma)
#define CHUNK 4096  // edges staged per bucket_bin block

DEV float sigm(float x) { return 1.0f / (1.0f + __expf(-x)); }
DEV float leaky(float e) { return (e >= 0.0f) ? e : 0.2f * e; }

// split 8 fp32 -> bf16 hi (truncate) + bf16 lo (truncate of exact residual)
DEV void split_bf16(const float f[8], short8& hi, short8& lo) {
#pragma unroll
  for (int i = 0; i < 8; ++i) {
    unsigned u = __builtin_bit_cast(unsigned, f[i]);
    hi[i] = (short)(u >> 16);
    float h = __builtin_bit_cast(float, u & 0xffff0000u);
    float r = f[i] - h;  // exact (Dekker)
    lo[i] = (short)(__builtin_bit_cast(unsigned, r) >> 16);
  }
}

// fp32 -> packed u32 (bf16hi<<16 | bf16lo); numerics identical to split_bf16
DEV unsigned packsplit(float v) {
  unsigned u = __builtin_bit_cast(unsigned, v);
  unsigned hf = u & 0xffff0000u;
  float r = v - __builtin_bit_cast(float, hf);
  return hf | (__builtin_bit_cast(unsigned, r) >> 16);
}

// unpack 8 packed u32 -> hi/lo short8 via v_perm
DEV void unpack_pk(const u32x4 p0, const u32x4 p1, short8& hi, short8& lo) {
  u32x4 h, l;
  h[0] = __builtin_amdgcn_perm(p0[1], p0[0], 0x07060302u);
  h[1] = __builtin_amdgcn_perm(p0[3], p0[2], 0x07060302u);
  h[2] = __builtin_amdgcn_perm(p1[1], p1[0], 0x07060302u);
  h[3] = __builtin_amdgcn_perm(p1[3], p1[2], 0x07060302u);
  l[0] = __builtin_amdgcn_perm(p0[1], p0[0], 0x05040100u);
  l[1] = __builtin_amdgcn_perm(p0[3], p0[2], 0x05040100u);
  l[2] = __builtin_amdgcn_perm(p1[1], p1[0], 0x05040100u);
  l[3] = __builtin_amdgcn_perm(p1[3], p1[2], 0x05040100u);
  hi = __builtin_bit_cast(short8, h);
  lo = __builtin_bit_cast(short8, l);
}

// ============================ utility kernels ============================

__global__ void fill_i32_kernel(int* p, int v, int n) {
  int i = blockIdx.x * blockDim.x + threadIdx.x;
  if (i < n) p[i] = v;
}

// ============================ bucketed CSR build ============================

__global__ __launch_bounds__(256) void bucket_bin(
    const int* __restrict__ ei, int* __restrict__ bucket_cnt,
    unsigned* __restrict__ ebuf, int E, int Et) {
  __shared__ unsigned stage[CHUNK];  // 16 KB
  __shared__ int hist[512], rbase[512], lcur[512];
  const int tid = threadIdx.x;
  const long long e0 = (long long)blockIdx.x * CHUNK;
  const int nalive = (int)((Et - e0) < CHUNK ? (Et - e0) : CHUNK);
  for (int i = tid; i < 512; i += 256) hist[i] = 0;
  __syncthreads();
  for (int k = tid; k < nalive; k += 256) {
    long long e = e0 + k;
    int s, d;
    if (e < E) { s = ei[e]; d = ei[E + e]; } else { s = (int)(e - E); d = s; }
    unsigned p = (unsigned)s | ((unsigned)d << 16);  // src:16b | dst:16b
    stage[k] = p;
    atomicAdd(&hist[d >> 7], 1);
  }
  __syncthreads();
  for (int i = tid; i < 512; i += 256) {
    int c = hist[i];
    rbase[i] = c ? atomicAdd(&bucket_cnt[i], c) : 0;
    lcur[i] = 0;
  }
  __syncthreads();
  for (int k = tid; k < nalive; k += 256) {
    unsigned p = stage[k];
    int b = (int)(p >> 23);  // dst>>7
    int lofs = atomicAdd(&lcur[b], 1);
    int pos = rbase[b] + lofs;
    if (pos < CAPB) ebuf[(long long)b * CAPB + pos] = p;
  }
}

__global__ __launch_bounds__(512) void bucket_scan(
    const int* __restrict__ cnt, int* __restrict__ start, int Et) {
  __shared__ int sh[512];
  int tid = threadIdx.x;
  int v = cnt[tid];
  sh[tid] = v;
  __syncthreads();
  int val = v;
  for (int off = 1; off < 512; off <<= 1) {
    int add = (tid >= off) ? sh[tid - off] : 0;
    __syncthreads();
    val += add;
    sh[tid] = val;
    __syncthreads();
  }
  start[tid] = val - v;
  if (tid == 511) start[512] = Et;
}

__global__ __launch_bounds__(128) void bucket_csr(
    const unsigned* __restrict__ ebuf, const int* __restrict__ bucket_cnt,
    const int* __restrict__ bucket_start, int* __restrict__ row_start,
    int* __restrict__ srcs, int N, int Et) {
  __shared__ unsigned stage[CAPB];  // 16 KB
  __shared__ int hist[128], hbase[128], lcur[128];
  const int b = blockIdx.x, tid = threadIdx.x;
  int cnt = bucket_cnt[b];
  cnt = cnt < CAPB ? cnt : CAPB;
  const int gbase = bucket_start[b];
  hist[tid] = 0;
  __syncthreads();
  const unsigned* eb = ebuf + (long long)b * CAPB;
  for (int k = tid; k < cnt; k += 128) {
    unsigned p = eb[k];
    stage[k] = p;
    atomicAdd(&hist[(p >> 16) & 127], 1);
  }
  __syncthreads();
  int v = hist[tid];
  hbase[tid] = v;
  __syncthreads();
  int val = v;
  for (int off = 1; off < 128; off <<= 1) {
    int add = (tid >= off) ? hbase[tid - off] : 0;
    __syncthreads();
    val += add;
    hbase[tid] = val;
    __syncthreads();
  }
  int ex = val - v;
  row_start[b * 128 + tid] = gbase + ex;
  __syncthreads();
  hbase[tid] = ex;
  lcur[tid] = 0;
  __syncthreads();
  for (int k = tid; k < cnt; k += 128) {
    unsigned p = stage[k];
    int o = (p >> 16) & 127;
    int lofs = atomicAdd(&lcur[o], 1);
    srcs[gbase + hbase[o] + lofs] = (int)(p & 0xffffu);
  }
  if (b == 0 && tid == 0) row_start[N] = Et;
}

// ============================ fused W pre-split ============================
struct WJobs {
  const float* W[16];
  short* hi[16];
  short* lo[16];
  int K[16];
  int M16[16];
  int ldw[16];
  int skip[16];
  int tile0[16];
};

__global__ __launch_bounds__(64) void wsplit_all(WJobs jb, int njobs) {
  int b = blockIdx.x;
  int ji = 0;
#pragma unroll
  for (int i = 1; i < 16; ++i)
    if (i < njobs && b >= jb.tile0[i]) ji = i;
  int t = b - jb.tile0[ji];
  int M16 = jb.M16[ji];
  int kc = t / M16, ntG = t % M16;
  int K = jb.K[ji], ldw = jb.ldw[ji];
  const float* __restrict__ W = jb.W[ji];

  int lane = threadIdx.x;
  int kb = kc * 32 + (lane >> 4) * 8;
  int c = ntG * 16 + (lane & 15);
  if (jb.skip[ji] && c >= 64) c += 64;  // skip dead f-gate columns
  float f[8];
#pragma unroll
  for (int j = 0; j < 8; ++j) {
    int k = kb + j;
    f[j] = (k < K) ? W[(long long)k * ldw + c] : 0.0f;
  }
  short8 h, l;
  split_bf16(f, h, l);
  long long off = ((long long)t * 64 + lane) * 8;
  *(short8*)(jb.hi[ji] + off) = h;
  *(short8*)(jb.lo[ji] + off) = l;
}

// ============================ MFMA GEMM ============================
// STE=1: fused s/t epilogue (s=G@asrc, t=G@adst) via shfl-reduce + atomicAdd
// (sOut/tOut must be zeroed before launch). Replaces st_kernel.
template <int MT, int APK, int OPK, int STE>
__global__ __launch_bounds__(64) void gemm_mfma(
    const void* __restrict__ Av, int lda,
    const short* __restrict__ wh, const short* __restrict__ wl,
    const float* __restrict__ bias,
    void* __restrict__ Cv, int ldc,
    int K, int KC, int M16, int gx, int act,
    const float* __restrict__ asrc, const float* __restrict__ adst,
    float* __restrict__ sOut, float* __restrict__ tOut) {
  const int lane = threadIdx.x;
  const int m = lane & 15, q = lane >> 4;
  const int b = blockIdx.x;
  const int x = (b >> 3) % gx;
  const int y = ((b >> 3) / gx) * 8 + (b & 7);
  const long long r0 = (long long)y * (MT * 16);
  const int ntG0 = x * 4;

  f32x4 acc[MT][4];
#pragma unroll
  for (int i = 0; i < MT; ++i)
#pragma unroll
    for (int j = 0; j < 4; ++j) acc[i][j] = (f32x4)(0.0f);

  for (int kc = 0; kc < KC; ++kc) {
    short8 bh[4], bl[4];
#pragma unroll
    for (int nt = 0; nt < 4; ++nt) {
      long long off = (((long long)kc * M16 + (ntG0 + nt)) * 64 + lane) * 8;
      bh[nt] = *(const short8*)(wh + off);
      bl[nt] = *(const short8*)(wl + off);
    }
    short8 ah[MT], al[MT];
#pragma unroll
    for (int mt = 0; mt < MT; ++mt) {
      if (APK == 1) {
        const unsigned* ap = (const unsigned*)Av + (r0 + mt * 16 + m) * lda + kc * 32 + q * 8;
        u32x4 p0 = *(const u32x4*)ap;
        u32x4 p1 = *(const u32x4*)(ap + 4);
        unpack_pk(p0, p1, ah[mt], al[mt]);
      } else {
        const float* ap = (const float*)Av + (r0 + mt * 16 + m) * lda + kc * 32 + q * 8;
        float f[8];
        const bool full = (kc * 32 + 32 <= K);
        if (full) {
          f32x4u p0 = *(const f32x4u*)ap;
          f32x4u p1 = *(const f32x4u*)(ap + 4);
#pragma unroll
          for (int j = 0; j < 4; ++j) { f[j] = p0[j]; f[4 + j] = p1[j]; }
        } else {
#pragma unroll
          for (int j = 0; j < 8; ++j) {
            int k = kc * 32 + q * 8 + j;
            f[j] = (k < K) ? ap[j] : 0.0f;
          }
        }
        split_bf16(f, ah[mt], al[mt]);
      }
    }
#pragma unroll
    for (int mt = 0; mt < MT; ++mt)
#pragma unroll
      for (int nt = 0; nt < 4; ++nt) {
        acc[mt][nt] = __builtin_amdgcn_mfma_f32_16x16x32_bf16(ah[mt], bh[nt], acc[mt][nt], 0, 0, 0);
        acc[mt][nt] = __builtin_amdgcn_mfma_f32_16x16x32_bf16(ah[mt], bl[nt], acc[mt][nt], 0, 0, 0);
        acc[mt][nt] = __builtin_amdgcn_mfma_f32_16x16x32_bf16(al[mt], bh[nt], acc[mt][nt], 0, 0, 0);
      }
  }

#pragma unroll
  for (int nt = 0; nt < 4; ++nt) {
    int col = (ntG0 + nt) * 16 + m;
    float bsv = bias ? bias[col] : 0.0f;
#pragma unroll
    for (int mt = 0; mt < MT; ++mt) {
      long long rb = r0 + mt * 16 + q * 4;
#pragma unroll
      for (int reg = 0; reg < 4; ++reg) {
        float v = acc[mt][nt][reg] + bsv;
        if (act == 1) v = fmaxf(v, 0.0f);
        if (OPK == 1)
          ((unsigned*)Cv)[(rb + reg) * ldc + col] = packsplit(v);
        else
          ((float*)Cv)[(rb + reg) * ldc + col] = v;
      }
    }
  }

  if (STE == 1) {
    float as[4], ad[4];
#pragma unroll
    for (int nt = 0; nt < 4; ++nt) {
      int col = (ntG0 + nt) * 16 + m;
      as[nt] = asrc[col];
      ad[nt] = adst[col];
    }
#pragma unroll
    for (int mt = 0; mt < MT; ++mt)
#pragma unroll
      for (int reg = 0; reg < 4; ++reg) {
        float ps = 0.0f, pt = 0.0f;
#pragma unroll
        for (int nt = 0; nt < 4; ++nt) {
          ps = fmaf(acc[mt][nt][reg], as[nt], ps);
          pt = fmaf(acc[mt][nt][reg], ad[nt], pt);
        }
#pragma unroll
        for (int off = 1; off < 16; off <<= 1) {
          ps += __shfl_xor(ps, off, 64);
          pt += __shfl_xor(pt, off, 64);
        }
        if (m == 0) {
          long long r = r0 + mt * 16 + q * 4 + reg;
          atomicAdd(&sOut[r], ps);
          atomicAdd(&tOut[r], pt);
        }
      }
  }
}

// ============================ fused LSTM GEMM ============================
// One wave = 16 rows x all 192 packed gate cols (i,g,o). Key layout fact:
// for output col c = nt*16+m (nt in 0..3), gi/gg/go live in acc[nt],
// acc[nt+4], acc[nt+8] -- same lane, same reg. Fused activation epilogue
// kills the 100 MB/layer gates round-trip + lstm_act launch.
template <int APK>
__global__ __launch_bounds__(64) void gemm_lstm(
    const void* __restrict__ Av, int lda,
    const short* __restrict__ wh, const short* __restrict__ wl,
    const float* __restrict__ bias,   // original 256-wide lstm_b row
    unsigned* __restrict__ H,         // N x 64 packed h out
    int K, int KC) {
  const int lane = threadIdx.x;
  const int m = lane & 15, q = lane >> 4;
  const long long r0 = (long long)blockIdx.x * 16;

  f32x4 acc[12];
#pragma unroll
  for (int j = 0; j < 12; ++j) acc[j] = (f32x4)(0.0f);

  for (int kc = 0; kc < KC; ++kc) {
    short8 ah, al;
    if (APK == 1) {
      const unsigned* ap = (const unsigned*)Av + (r0 + m) * lda + kc * 32 + q * 8;
      u32x4 p0 = *(const u32x4*)ap;
      u32x4 p1 = *(const u32x4*)(ap + 4);
      unpack_pk(p0, p1, ah, al);
    } else {
      const float* ap = (const float*)Av + (r0 + m) * lda + kc * 32 + q * 8;
      float f[8];
      const bool full = (kc * 32 + 32 <= K);
      if (full) {
        f32x4u p0 = *(const f32x4u*)ap;
        f32x4u p1 = *(const f32x4u*)(ap + 4);
#pragma unroll
        for (int j = 0; j < 4; ++j) { f[j] = p0[j]; f[4 + j] = p1[j]; }
      } else {
#pragma unroll
        for (int j = 0; j < 8; ++j) {
          int k = kc * 32 + q * 8 + j;
          f[j] = (k < K) ? ap[j] : 0.0f;
        }
      }
      split_bf16(f, ah, al);
    }
#pragma unroll
    for (int nt = 0; nt < 12; ++nt) {
      long long off = (((long long)kc * 12 + nt) * 64 + lane) * 8;
      short8 bh = *(const short8*)(wh + off);
      short8 bl = *(const short8*)(wl + off);
      acc[nt] = __builtin_amdgcn_mfma_f32_16x16x32_bf16(ah, bh, acc[nt], 0, 0, 0);
      acc[nt] = __builtin_amdgcn_mfma_f32_16x16x32_bf16(ah, bl, acc[nt], 0, 0, 0);
      acc[nt] = __builtin_amdgcn_mfma_f32_16x16x32_bf16(al, bh, acc[nt], 0, 0, 0);
    }
  }

#pragma unroll
  for (int nt = 0; nt < 4; ++nt) {
    int col = nt * 16 + m;
    float bi = bias[col], bg = bias[128 + col], bo = bias[192 + col];
#pragma unroll
    for (int reg = 0; reg < 4; ++reg) {
      float gi = acc[nt][reg] + bi;
      float gg = acc[nt + 4][reg] + bg;
      float go = acc[nt + 8][reg] + bo;
      float cc = sigm(gi) * tanhf(gg);
      H[(r0 + q * 4 + reg) * 64 + col] = packsplit(sigm(go) * tanhf(cc));
    }
  }
}

// ============================ GAT aggregate ============================

template <int FO, int OPK>
__global__ __launch_bounds__(256) void gat_agg(
    const float* __restrict__ G, const float* __restrict__ s,
    const float* __restrict__ t, const int* __restrict__ row_start,
    const int* __restrict__ srcs, const float* __restrict__ bias,
    void* __restrict__ outv, int ldc) {
  constexpr int CAP = 128;
  constexpr int LPE = FO / 4;
  constexpr int EPW = 64 / LPE;
  __shared__ float ecache[4][CAP];
  const int wv = threadIdx.x >> 6;
  const int lane = threadIdx.x & 63;
  const int d = blockIdx.x * 4 + wv;
  const int start = row_start[d], end = row_start[d + 1];
  const float td = t[d];

  float m = NEG_BIG, dsum = 0.0f;
  for (int j = start + lane; j < end; j += 64) {
    float e = leaky(s[srcs[j]] + td);
    int idx = j - start;
    if (idx < CAP) ecache[wv][idx] = e;
    float mn = fmaxf(m, e);
    dsum = dsum * __expf(m - mn) + __expf(e - mn);
    m = mn;
  }
#pragma unroll
  for (int off = 32; off; off >>= 1) {
    float mo = __shfl_xor(m, off, 64);
    float dso = __shfl_xor(dsum, off, 64);
    float mn = fmaxf(m, mo);
    dsum = dsum * __expf(m - mn) + dso * __expf(mo - mn);
    m = mn;
  }
  const float inv = 1.0f / dsum;

  const int deg = end - start;
  const int capdeg = deg < CAP ? deg : CAP;
  for (int idx = lane; idx < capdeg; idx += 64)
    ecache[wv][idx] = __expf(ecache[wv][idx] - m) * inv;
  __syncthreads();

  const int grp = lane / LPE, cl = lane % LPE;
  const float* __restrict__ Gc = G + cl * 4;
  float a0 = 0.0f, a1 = 0.0f, a2 = 0.0f, a3 = 0.0f;
  int j = start + grp;
  for (; j + EPW < end; j += 2 * EPW) {
    int s0 = srcs[j], s1 = srcs[j + EPW];
    int i0 = j - start, i1 = i0 + EPW;
    float al0 = (i0 < CAP) ? ecache[wv][i0]
                           : __expf(leaky(s[s0] + td) - m) * inv;
    float al1 = (i1 < CAP) ? ecache[wv][i1]
                           : __expf(leaky(s[s1] + td) - m) * inv;
    f32x4u g0 = *(const f32x4u*)(Gc + (long long)s0 * FO);
    f32x4u g1 = *(const f32x4u*)(Gc + (long long)s1 * FO);
    a0 = fmaf(al0, g0[0], a0); a1 = fmaf(al0, g0[1], a1);
    a2 = fmaf(al0, g0[2], a2); a3 = fmaf(al0, g0[3], a3);
    a0 = fmaf(al1, g1[0], a0); a1 = fmaf(al1, g1[1], a1);
    a2 = fmaf(al1, g1[2], a2); a3 = fmaf(al1, g1[3], a3);
  }
  if (j < end) {
    int s0 = srcs[j];
    int i0 = j - start;
    float al0 = (i0 < CAP) ? ecache[wv][i0]
                           : __expf(leaky(s[s0] + td) - m) * inv;
    f32x4u g0 = *(const f32x4u*)(Gc + (long long)s0 * FO);
    a0 = fmaf(al0, g0[0], a0); a1 = fmaf(al0, g0[1], a1);
    a2 = fmaf(al0, g0[2], a2); a3 = fmaf(al0, g0[3], a3);
  }
#pragma unroll
  for (int off = 32; off >= LPE; off >>= 1) {
    a0 += __shfl_xor(a0, off, 64);
    a1 += __shfl_xor(a1, off, 64);
    a2 += __shfl_xor(a2, off, 64);
    a3 += __shfl_xor(a3, off, 64);
  }
  if (grp == 0) {
    f32x4u bs = *(const f32x4u*)(bias + cl * 4);
    float v0 = fmaxf(a0 + bs[0], 0.0f);
    float v1 = fmaxf(a1 + bs[1], 0.0f);
    float v2 = fmaxf(a2 + bs[2], 0.0f);
    float v3 = fmaxf(a3 + bs[3], 0.0f);
    if (OPK == 1) {
      u32x4 pv;
      pv[0] = packsplit(v0); pv[1] = packsplit(v1);
      pv[2] = packsplit(v2); pv[3] = packsplit(v3);
      *(u32x4*)((unsigned*)outv + (long long)d * ldc + cl * 4) = pv;
    } else {
      f32x4u v; v[0] = v0; v[1] = v1; v[2] = v2; v[3] = v3;
      *(f32x4u*)((float*)outv + (long long)d * ldc + cl * 4) = v;
    }
  }
}

// ============================ head ============================

__global__ void lin3_kernel(const float* __restrict__ Z, const float* __restrict__ w,
                            const float* __restrict__ b, float* __restrict__ out, int N) {
  int i = blockIdx.x * blockDim.x + threadIdx.x;
  if (i >= N) return;
  const float4* z4 = (const float4*)(Z + (long long)i * 64);
  const float4* w4 = (const float4*)w;
  float acc = 0.0f;
#pragma unroll
  for (int k = 0; k < 16; ++k) {
    float4 a = z4[k], ww = w4[k];
    acc += a.x * ww.x + a.y * ww.y + a.z * ww.z + a.w * ww.w;
  }
  out[i] = acc + b[0];
}

// ============================ launcher ============================

struct WSplit { const short* hi; const short* lo; };

extern "C" void kernel_launch(void* const* d_in, const int* in_sizes, int n_in,
                              void* d_out, int out_size, void* d_ws, size_t ws_size,
                              hipStream_t stream) {
  const int N = 65536, E = 1048576;
  const int Et = E + N;

  const float* x        = (const float*)d_in[0];
  const int*   ei       = (const int*)d_in[1];
  const float* poi1_W   = (const float*)d_in[2];
  const float* poi1_b   = (const float*)d_in[3];
  const float* poi2_W   = (const float*)d_in[4];
  const float* poi2_b   = (const float*)d_in[5];
  const float* svi1_W   = (const float*)d_in[6];
  const float* svi1_b   = (const float*)d_in[7];
  const float* svi2_W   = (const float*)d_in[8];
  const float* svi2_b   = (const float*)d_in[9];
  const float* all1_W   = (const float*)d_in[10];
  const float* all1_b   = (const float*)d_in[11];
  const float* all2_W   = (const float*)d_in[12];
  const float* all2_b   = (const float*)d_in[13];
  const float* gat1_W   = (const float*)d_in[14];
  const float* gat1_b   = (const float*)d_in[15];
  const float* gat1_as  = (const float*)d_in[16];
  const float* gat1_ad  = (const float*)d_in[17];
  const float* gat2_W   = (const float*)d_in[18];
  const float* gat2_b   = (const float*)d_in[19];
  const float* gat2_as  = (const float*)d_in[20];
  const float* gat2_ad  = (const float*)d_in[21];
  const float* gat3_W   = (const float*)d_in[22];
  const float* gat3_b   = (const float*)d_in[23];
  const float* gat3_as  = (const float*)d_in[24];
  const float* gat3_ad  = (const float*)d_in[25];
  const float* lstm_Wih0= (const float*)d_in[26];
  const float* lstm_Wih = (const float*)d_in[27];
  const float* lstm_b   = (const float*)d_in[29];
  const float* time1_W  = (const float*)d_in[30];
  const float* time1_b  = (const float*)d_in[31];
  const float* time2_W  = (const float*)d_in[32];
  const float* time2_b  = (const float*)d_in[33];
  const float* lin1_W   = (const float*)d_in[34];
  const float* lin1_b   = (const float*)d_in[35];
  const float* lin2_W   = (const float*)d_in[36];
  const float* lin2_b   = (const float*)d_in[37];
  const float* lin3_W   = (const float*)d_in[38];
  const float* lin3_b   = (const float*)d_in[39];
  float* out = (float*)d_out;

  // ---- workspace layout ----
  float* wsf   = (float*)d_ws;
  float* R192  = wsf;
  float* RA    = R192 + (size_t)N * 192;
  float* RA2   = RA + (size_t)N * 64;
  float* RB    = RA + (size_t)N * 128;
  float* Rz    = RB + (size_t)N * 256;
  float* sArr  = Rz + (size_t)N * 128;
  float* tArr  = sArr + N;     // contiguous with sArr (joint zero-fill)
  int* ints         = (int*)(tArr + N);
  int* row_start    = ints;                        // N+1
  int* srcs         = row_start + (N + 1);         // Et
  int* bucket_cnt   = srcs + Et;                   // 512
  int* bucket_start = bucket_cnt + 512;            // 513
  unsigned* ebuf    = (unsigned*)(bucket_start + 513);  // 512*CAPB (8MB)
  short* pool = (short*)(((uintptr_t)(ebuf + 512 * CAPB) + 15) & ~(uintptr_t)15);

  WJobs jb{};
  int nj = 0, tiles = 0;
  auto split = [&](const float* W, int K, int M, int ldw, int skip) -> WSplit {
    int KC = (K + 31) / 32;
    size_t sz = (size_t)KC * M * 32;
    short* hi = pool; pool += sz;
    short* lo = pool; pool += sz;
    jb.W[nj] = W; jb.hi[nj] = hi; jb.lo[nj] = lo;
    jb.K[nj] = K; jb.M16[nj] = M / 16; jb.ldw[nj] = ldw; jb.skip[nj] = skip;
    jb.tile0[nj] = tiles;
    tiles += KC * (M / 16);
    ++nj;
    return {hi, lo};
  };
  auto gemm = [&](const void* A, int lda, WSplit w, const float* bias,
                  void* C, int ldc, int K, int M, int act, int apk, int opk) {
    int gx = M / 64;
    dim3 grid(gx * (N / 32)), blk(64);
    int KC = (K + 31) / 32, M16 = M / 16;
    if (apk == 0 && opk == 0)
      hipLaunchKernelGGL((gemm_mfma<2, 0, 0, 0>), grid, blk, 0, stream,
                         A, lda, w.hi, w.lo, bias, C, ldc, K, KC, M16, gx, act,
                         nullptr, nullptr, nullptr, nullptr);
    else if (apk == 0 && opk == 1)
      hipLaunchKernelGGL((gemm_mfma<2, 0, 1, 0>), grid, blk, 0, stream,
                         A, lda, w.hi, w.lo, bias, C, ldc, K, KC, M16, gx, act,
                         nullptr, nullptr, nullptr, nullptr);
    else if (apk == 1 && opk == 0)
      hipLaunchKernelGGL((gemm_mfma<2, 1, 0, 0>), grid, blk, 0, stream,
                         A, lda, w.hi, w.lo, bias, C, ldc, K, KC, M16, gx, act,
                         nullptr, nullptr, nullptr, nullptr);
    else
      hipLaunchKernelGGL((gemm_mfma<2, 1, 1, 0>), grid, blk, 0, stream,
                         A, lda, w.hi, w.lo, bias, C, ldc, K, KC, M16, gx, act,
                         nullptr, nullptr, nullptr, nullptr);
  };
  // GAT GEMM with fused s/t epilogue (APK=1, OPK=0, STE=1)
  auto gemm_st = [&](const void* A, WSplit w, void* G, int M,
                     const float* as_, const float* ad_) {
    int gx = M / 64;
    hipLaunchKernelGGL((gemm_mfma<2, 1, 0, 1>), dim3(gx * (N / 32)), dim3(64),
                       0, stream, A, 128, w.hi, w.lo, (const float*)nullptr,
                       G, M, 128, 4, M / 16, gx, 0, as_, ad_, sArr, tArr);
  };

  // ---- register all weight splits, then ONE fused split launch ----
  WSplit wpoi1 = split(poi1_W, 13, 64, 64, 0);
  WSplit wpoi2 = split(poi2_W, 64, 64, 64, 0);
  WSplit wsvi1 = split(svi1_W, 365, 128, 128, 0);
  WSplit wsvi2 = split(svi2_W, 128, 128, 128, 0);
  WSplit wall1 = split(all1_W, 192, 128, 128, 0);
  WSplit wall2 = split(all2_W, 128, 128, 128, 0);
  WSplit wg1   = split(gat1_W, 128, 128, 128, 0);
  WSplit wg2   = split(gat2_W, 128, 128, 128, 0);
  WSplit wg3   = split(gat3_W, 128, 64, 64, 0);
  WSplit wls0  = split(lstm_Wih0, 24, 192, 256, 1);
  WSplit wls1  = split(lstm_Wih, 64, 192, 256, 1);
  WSplit wls2  = split(lstm_Wih + 64 * 256, 64, 192, 256, 1);
  WSplit wt1   = split(time1_W, 64, 64, 64, 0);
  WSplit wt2   = split(time2_W, 64, 64, 64, 0);
  WSplit wl1   = split(lin1_W, 128, 64, 64, 0);
  WSplit wl2   = split(lin2_W, 64, 64, 64, 0);
  hipLaunchKernelGGL(wsplit_all, dim3(tiles), dim3(64), 0, stream, jb, nj);

  const int TB = 256;

  // ---- build CSR via bucketed counting sort ----
  hipLaunchKernelGGL(fill_i32_kernel, dim3(2), dim3(TB), 0, stream,
                     bucket_cnt, 0, 512);
  hipLaunchKernelGGL(bucket_bin, dim3((Et + CHUNK - 1) / CHUNK), dim3(256),
                     0, stream, ei, bucket_cnt, ebuf, E, Et);
  hipLaunchKernelGGL(bucket_scan, dim3(1), dim3(512), 0, stream,
                     bucket_cnt, bucket_start, Et);
  hipLaunchKernelGGL(bucket_csr, dim3(512), dim3(128), 0, stream,
                     ebuf, bucket_cnt, bucket_start, row_start, srcs, N, Et);

  // ---- MLP towers (internal tensors packed) ----
  gemm(x + 3, 445, wpoi1, poi1_b, RA, 64, 13, 64, 1, 0, 1);
  gemm(RA, 64, wpoi2, poi2_b, R192, 192, 64, 64, 1, 1, 1);
  gemm(x + 56, 445, wsvi1, svi1_b, RB, 128, 365, 128, 1, 0, 1);
  gemm(RB, 128, wsvi2, svi2_b, R192 + 64, 192, 128, 128, 1, 1, 1);
  gemm(R192, 192, wall1, all1_b, RA, 128, 192, 128, 1, 1, 1);
  gemm(RA, 128, wall2, all2_b, RB, 128, 128, 128, 1, 1, 1);

  const int aggBlocks = N / 4;
  const int fillST = (2 * N + TB - 1) / TB;

  // ---- GAT1: zero s/t -> GEMM(+s/t epilogue) -> aggregate ----
  hipLaunchKernelGGL(fill_i32_kernel, dim3(fillST), dim3(TB), 0, stream,
                     (int*)sArr, 0, 2 * N);
  gemm_st(RB, wg1, RA, 128, gat1_as, gat1_ad);
  hipLaunchKernelGGL((gat_agg<128, 1>), dim3(aggBlocks), dim3(256), 0, stream,
                     RA, sArr, tArr, row_start, srcs, gat1_b, RB, 128);
  // ---- GAT2 ----
  hipLaunchKernelGGL(fill_i32_kernel, dim3(fillST), dim3(TB), 0, stream,
                     (int*)sArr, 0, 2 * N);
  gemm_st(RB, wg2, RA, 128, gat2_as, gat2_ad);
  hipLaunchKernelGGL((gat_agg<128, 1>), dim3(aggBlocks), dim3(256), 0, stream,
                     RA, sArr, tArr, row_start, srcs, gat2_b, RB, 128);
  // ---- GAT3 (fo=64 -> Rz cols 0..63 packed) ----
  hipLaunchKernelGGL(fill_i32_kernel, dim3(fillST), dim3(TB), 0, stream,
                     (int*)sArr, 0, 2 * N);
  gemm_st(RB, wg3, RA, 64, gat3_as, gat3_ad);
  hipLaunchKernelGGL((gat_agg<64, 1>), dim3(aggBlocks), dim3(256), 0, stream,
                     RA, sArr, tArr, row_start, srcs, gat3_b, Rz, 128);

  // ---- "LSTM": fused GEMM+activation, f-gate skipped, packed h ----
  hipLaunchKernelGGL((gemm_lstm<0>), dim3(N / 16), dim3(64), 0, stream,
                     x + 421, 445, wls0.hi, wls0.lo, lstm_b,
                     (unsigned*)RA, 24, 1);
  hipLaunchKernelGGL((gemm_lstm<1>), dim3(N / 16), dim3(64), 0, stream,
                     RA, 64, wls1.hi, wls1.lo, lstm_b + 256,
                     (unsigned*)RA2, 64, 2);
  hipLaunchKernelGGL((gemm_lstm<1>), dim3(N / 16), dim3(64), 0, stream,
                     RA2, 64, wls2.hi, wls2.lo, lstm_b + 512,
                     (unsigned*)RA, 64, 2);

  // ---- time MLP -> Rz cols 64..127 packed ----
  gemm(RA, 64, wt1, time1_b, RA2, 64, 64, 64, 1, 1, 1);
  gemm(RA2, 64, wt2, time2_b, Rz + 64, 128, 64, 64, 1, 1, 1);

  // ---- head ----
  gemm(Rz, 128, wl1, lin1_b, RA, 64, 128, 64, 1, 1, 1);
  gemm(RA, 64, wl2, lin2_b, RA2, 64, 64, 64, 1, 1, 0);
  hipLaunchKernelGGL(lin3_kernel, dim3((N + TB - 1) / TB), dim3(TB), 0, stream,
                     RA2, lin3_W, lin3_b, out, N);
}

// Round 14
// 757.466 us; speedup vs baseline: 2.8214x; 1.0278x over previous
//
#include <hip/hip_runtime.h>
#include <math.h>

#define DEV __device__ __forceinline__

typedef __attribute__((ext_vector_type(8))) short short8;   // 8 bf16 (4 VGPRs)
typedef __attribute__((ext_vector_type(4))) float f32x4;    // MFMA acc
typedef float f32x4u __attribute__((ext_vector_type(4), aligned(4)));
typedef __attribute__((ext_vector_type(4))) unsigned int u32x4;

#define NEG_BIG (-3.0e38f)
#define CAPB 4096   // bucket capacity (mean 2176, +40 sigma)
#define CHUNK 4096  // edges staged per bucket_bin block

DEV float sigm(float x) { return 1.0f / (1.0f + __expf(-x)); }
DEV float leaky(float e) { return (e >= 0.0f) ? e : 0.2f * e; }

// split 8 fp32 -> bf16 hi (truncate) + bf16 lo (truncate of exact residual)
DEV void split_bf16(const float f[8], short8& hi, short8& lo) {
#pragma unroll
  for (int i = 0; i < 8; ++i) {
    unsigned u = __builtin_bit_cast(unsigned, f[i]);
    hi[i] = (short)(u >> 16);
    float h = __builtin_bit_cast(float, u & 0xffff0000u);
    float r = f[i] - h;  // exact (Dekker)
    lo[i] = (short)(__builtin_bit_cast(unsigned, r) >> 16);
  }
}

// fp32 -> packed u32 (bf16hi<<16 | bf16lo); numerics identical to split_bf16
DEV unsigned packsplit(float v) {
  unsigned u = __builtin_bit_cast(unsigned, v);
  unsigned hf = u & 0xffff0000u;
  float r = v - __builtin_bit_cast(float, hf);
  return hf | (__builtin_bit_cast(unsigned, r) >> 16);
}

// unpack 8 packed u32 -> hi/lo short8 via v_perm
DEV void unpack_pk(const u32x4 p0, const u32x4 p1, short8& hi, short8& lo) {
  u32x4 h, l;
  h[0] = __builtin_amdgcn_perm(p0[1], p0[0], 0x07060302u);
  h[1] = __builtin_amdgcn_perm(p0[3], p0[2], 0x07060302u);
  h[2] = __builtin_amdgcn_perm(p1[1], p1[0], 0x07060302u);
  h[3] = __builtin_amdgcn_perm(p1[3], p1[2], 0x07060302u);
  l[0] = __builtin_amdgcn_perm(p0[1], p0[0], 0x05040100u);
  l[1] = __builtin_amdgcn_perm(p0[3], p0[2], 0x05040100u);
  l[2] = __builtin_amdgcn_perm(p1[1], p1[0], 0x05040100u);
  l[3] = __builtin_amdgcn_perm(p1[3], p1[2], 0x05040100u);
  hi = __builtin_bit_cast(short8, h);
  lo = __builtin_bit_cast(short8, l);
}

// ============================ utility kernels ============================

__global__ void fill_i32_kernel(int* p, int v, int n) {
  int i = blockIdx.x * blockDim.x + threadIdx.x;
  if (i < n) p[i] = v;
}

// ============================ bucketed CSR build ============================

__global__ __launch_bounds__(256) void bucket_bin(
    const int* __restrict__ ei, int* __restrict__ bucket_cnt,
    unsigned* __restrict__ ebuf, int E, int Et) {
  __shared__ unsigned stage[CHUNK];  // 16 KB
  __shared__ int hist[512], rbase[512], lcur[512];
  const int tid = threadIdx.x;
  const long long e0 = (long long)blockIdx.x * CHUNK;
  const int nalive = (int)((Et - e0) < CHUNK ? (Et - e0) : CHUNK);
  for (int i = tid; i < 512; i += 256) hist[i] = 0;
  __syncthreads();
  for (int k = tid; k < nalive; k += 256) {
    long long e = e0 + k;
    int s, d;
    if (e < E) { s = ei[e]; d = ei[E + e]; } else { s = (int)(e - E); d = s; }
    unsigned p = (unsigned)s | ((unsigned)d << 16);  // src:16b | dst:16b
    stage[k] = p;
    atomicAdd(&hist[d >> 7], 1);
  }
  __syncthreads();
  for (int i = tid; i < 512; i += 256) {
    int c = hist[i];
    rbase[i] = c ? atomicAdd(&bucket_cnt[i], c) : 0;
    lcur[i] = 0;
  }
  __syncthreads();
  for (int k = tid; k < nalive; k += 256) {
    unsigned p = stage[k];
    int b = (int)(p >> 23);  // dst>>7
    int lofs = atomicAdd(&lcur[b], 1);
    int pos = rbase[b] + lofs;
    if (pos < CAPB) ebuf[(long long)b * CAPB + pos] = p;
  }
}

__global__ __launch_bounds__(512) void bucket_scan(
    const int* __restrict__ cnt, int* __restrict__ start, int Et) {
  __shared__ int sh[512];
  int tid = threadIdx.x;
  int v = cnt[tid];
  sh[tid] = v;
  __syncthreads();
  int val = v;
  for (int off = 1; off < 512; off <<= 1) {
    int add = (tid >= off) ? sh[tid - off] : 0;
    __syncthreads();
    val += add;
    sh[tid] = val;
    __syncthreads();
  }
  start[tid] = val - v;
  if (tid == 511) start[512] = Et;
}

__global__ __launch_bounds__(128) void bucket_csr(
    const unsigned* __restrict__ ebuf, const int* __restrict__ bucket_cnt,
    const int* __restrict__ bucket_start, int* __restrict__ row_start,
    int* __restrict__ srcs, int N, int Et) {
  __shared__ unsigned stage[CAPB];  // 16 KB
  __shared__ int hist[128], hbase[128], lcur[128];
  const int b = blockIdx.x, tid = threadIdx.x;
  int cnt = bucket_cnt[b];
  cnt = cnt < CAPB ? cnt : CAPB;
  const int gbase = bucket_start[b];
  hist[tid] = 0;
  __syncthreads();
  const unsigned* eb = ebuf + (long long)b * CAPB;
  for (int k = tid; k < cnt; k += 128) {
    unsigned p = eb[k];
    stage[k] = p;
    atomicAdd(&hist[(p >> 16) & 127], 1);
  }
  __syncthreads();
  int v = hist[tid];
  hbase[tid] = v;
  __syncthreads();
  int val = v;
  for (int off = 1; off < 128; off <<= 1) {
    int add = (tid >= off) ? hbase[tid - off] : 0;
    __syncthreads();
    val += add;
    hbase[tid] = val;
    __syncthreads();
  }
  int ex = val - v;
  row_start[b * 128 + tid] = gbase + ex;
  __syncthreads();
  hbase[tid] = ex;
  lcur[tid] = 0;
  __syncthreads();
  for (int k = tid; k < cnt; k += 128) {
    unsigned p = stage[k];
    int o = (p >> 16) & 127;
    int lofs = atomicAdd(&lcur[o], 1);
    srcs[gbase + hbase[o] + lofs] = (int)(p & 0xffffu);
  }
  if (b == 0 && tid == 0) row_start[N] = Et;
}

// ============================ fused W pre-split ============================
struct WJobs {
  const float* W[16];
  short* hi[16];
  short* lo[16];
  int K[16];
  int M16[16];
  int ldw[16];
  int skip[16];
  int tile0[16];
};

__global__ __launch_bounds__(64) void wsplit_all(WJobs jb, int njobs) {
  int b = blockIdx.x;
  int ji = 0;
#pragma unroll
  for (int i = 1; i < 16; ++i)
    if (i < njobs && b >= jb.tile0[i]) ji = i;
  int t = b - jb.tile0[ji];
  int M16 = jb.M16[ji];
  int kc = t / M16, ntG = t % M16;
  int K = jb.K[ji], ldw = jb.ldw[ji];
  const float* __restrict__ W = jb.W[ji];

  int lane = threadIdx.x;
  int kb = kc * 32 + (lane >> 4) * 8;
  int c = ntG * 16 + (lane & 15);
  if (jb.skip[ji] && c >= 64) c += 64;  // skip dead f-gate columns
  float f[8];
#pragma unroll
  for (int j = 0; j < 8; ++j) {
    int k = kb + j;
    f[j] = (k < K) ? W[(long long)k * ldw + c] : 0.0f;
  }
  short8 h, l;
  split_bf16(f, h, l);
  long long off = ((long long)t * 64 + lane) * 8;
  *(short8*)(jb.hi[ji] + off) = h;
  *(short8*)(jb.lo[ji] + off) = l;
}

// ============================ MFMA GEMM ============================
// One wave per block covering MT*16 rows x NT*16 = ALL M columns (gx==1):
// A is streamed exactly once per GEMM (r13: gx=2 made every M=128 GEMM read
// A twice). NT processed in register-halves of 4 n-tiles (VGPR ~130).
// STE=1: fused s/t epilogue -- with full M per wave this is a plain register
// reduction + direct store: NO atomics, NO pre-zeroing.
template <int MT, int NT, int APK, int OPK, int STE>
__global__ __launch_bounds__(64) void gemm_mfma(
    const void* __restrict__ Av, int lda,
    const short* __restrict__ wh, const short* __restrict__ wl,
    const float* __restrict__ bias,
    void* __restrict__ Cv, int ldc,
    int K, int KC, int act,
    const float* __restrict__ asrc, const float* __restrict__ adst,
    float* __restrict__ sOut, float* __restrict__ tOut) {
  const int lane = threadIdx.x;
  const int m = lane & 15, q = lane >> 4;
  const long long r0 = (long long)blockIdx.x * (MT * 16);

  f32x4 acc[MT][NT];
#pragma unroll
  for (int i = 0; i < MT; ++i)
#pragma unroll
    for (int j = 0; j < NT; ++j) acc[i][j] = (f32x4)(0.0f);

  for (int kc = 0; kc < KC; ++kc) {
    short8 ah[MT], al[MT];
#pragma unroll
    for (int mt = 0; mt < MT; ++mt) {
      if (APK == 1) {
        const unsigned* ap = (const unsigned*)Av + (r0 + mt * 16 + m) * lda + kc * 32 + q * 8;
        u32x4 p0 = *(const u32x4*)ap;
        u32x4 p1 = *(const u32x4*)(ap + 4);
        unpack_pk(p0, p1, ah[mt], al[mt]);
      } else {
        const float* ap = (const float*)Av + (r0 + mt * 16 + m) * lda + kc * 32 + q * 8;
        float f[8];
        const bool full = (kc * 32 + 32 <= K);
        if (full) {
          f32x4u p0 = *(const f32x4u*)ap;
          f32x4u p1 = *(const f32x4u*)(ap + 4);
#pragma unroll
          for (int j = 0; j < 4; ++j) { f[j] = p0[j]; f[4 + j] = p1[j]; }
        } else {
#pragma unroll
          for (int j = 0; j < 8; ++j) {
            int k = kc * 32 + q * 8 + j;
            f[j] = (k < K) ? ap[j] : 0.0f;
          }
        }
        split_bf16(f, ah[mt], al[mt]);
      }
    }
    // NT n-tiles in halves of 4 to bound live B-frag registers
#pragma unroll
    for (int g = 0; g < NT / 4; ++g) {
      short8 bh[4], bl[4];
#pragma unroll
      for (int j = 0; j < 4; ++j) {
        long long off = (((long long)kc * NT + (g * 4 + j)) * 64 + lane) * 8;
        bh[j] = *(const short8*)(wh + off);
        bl[j] = *(const short8*)(wl + off);
      }
#pragma unroll
      for (int mt = 0; mt < MT; ++mt)
#pragma unroll
        for (int j = 0; j < 4; ++j) {
          int nt = g * 4 + j;
          acc[mt][nt] = __builtin_amdgcn_mfma_f32_16x16x32_bf16(ah[mt], bh[j], acc[mt][nt], 0, 0, 0);
          acc[mt][nt] = __builtin_amdgcn_mfma_f32_16x16x32_bf16(ah[mt], bl[j], acc[mt][nt], 0, 0, 0);
          acc[mt][nt] = __builtin_amdgcn_mfma_f32_16x16x32_bf16(al[mt], bh[j], acc[mt][nt], 0, 0, 0);
        }
    }
  }

#pragma unroll
  for (int nt = 0; nt < NT; ++nt) {
    int col = nt * 16 + m;
    float bsv = bias ? bias[col] : 0.0f;
#pragma unroll
    for (int mt = 0; mt < MT; ++mt) {
      long long rb = r0 + mt * 16 + q * 4;
#pragma unroll
      for (int reg = 0; reg < 4; ++reg) {
        float v = acc[mt][nt][reg] + bsv;
        if (act == 1) v = fmaxf(v, 0.0f);
        if (OPK == 1)
          ((unsigned*)Cv)[(rb + reg) * ldc + col] = packsplit(v);
        else
          ((float*)Cv)[(rb + reg) * ldc + col] = v;
      }
    }
  }

  if (STE == 1) {
    float as[NT], ad[NT];
#pragma unroll
    for (int nt = 0; nt < NT; ++nt) {
      int col = nt * 16 + m;
      as[nt] = asrc[col];
      ad[nt] = adst[col];
    }
#pragma unroll
    for (int mt = 0; mt < MT; ++mt)
#pragma unroll
      for (int reg = 0; reg < 4; ++reg) {
        float ps = 0.0f, pt = 0.0f;
#pragma unroll
        for (int nt = 0; nt < NT; ++nt) {
          ps = fmaf(acc[mt][nt][reg], as[nt], ps);
          pt = fmaf(acc[mt][nt][reg], ad[nt], pt);
        }
#pragma unroll
        for (int off = 1; off < 16; off <<= 1) {
          ps += __shfl_xor(ps, off, 64);
          pt += __shfl_xor(pt, off, 64);
        }
        if (m == 0) {
          long long r = r0 + mt * 16 + q * 4 + reg;
          sOut[r] = ps;
          tOut[r] = pt;
        }
      }
  }
}

// ============================ fused LSTM GEMM ============================
// One wave = 16 rows x all 192 packed gate cols (i,g,o): gi/gg/go for col
// c = nt*16+m live in acc[nt], acc[nt+4], acc[nt+8] -- same lane, same reg.
template <int APK>
__global__ __launch_bounds__(64) void gemm_lstm(
    const void* __restrict__ Av, int lda,
    const short* __restrict__ wh, const short* __restrict__ wl,
    const float* __restrict__ bias,   // original 256-wide lstm_b row
    unsigned* __restrict__ H,         // N x 64 packed h out
    int K, int KC) {
  const int lane = threadIdx.x;
  const int m = lane & 15, q = lane >> 4;
  const long long r0 = (long long)blockIdx.x * 16;

  f32x4 acc[12];
#pragma unroll
  for (int j = 0; j < 12; ++j) acc[j] = (f32x4)(0.0f);

  for (int kc = 0; kc < KC; ++kc) {
    short8 ah, al;
    if (APK == 1) {
      const unsigned* ap = (const unsigned*)Av + (r0 + m) * lda + kc * 32 + q * 8;
      u32x4 p0 = *(const u32x4*)ap;
      u32x4 p1 = *(const u32x4*)(ap + 4);
      unpack_pk(p0, p1, ah, al);
    } else {
      const float* ap = (const float*)Av + (r0 + m) * lda + kc * 32 + q * 8;
      float f[8];
      const bool full = (kc * 32 + 32 <= K);
      if (full) {
        f32x4u p0 = *(const f32x4u*)ap;
        f32x4u p1 = *(const f32x4u*)(ap + 4);
#pragma unroll
        for (int j = 0; j < 4; ++j) { f[j] = p0[j]; f[4 + j] = p1[j]; }
      } else {
#pragma unroll
        for (int j = 0; j < 8; ++j) {
          int k = kc * 32 + q * 8 + j;
          f[j] = (k < K) ? ap[j] : 0.0f;
        }
      }
      split_bf16(f, ah, al);
    }
#pragma unroll
    for (int nt = 0; nt < 12; ++nt) {
      long long off = (((long long)kc * 12 + nt) * 64 + lane) * 8;
      short8 bh = *(const short8*)(wh + off);
      short8 bl = *(const short8*)(wl + off);
      acc[nt] = __builtin_amdgcn_mfma_f32_16x16x32_bf16(ah, bh, acc[nt], 0, 0, 0);
      acc[nt] = __builtin_amdgcn_mfma_f32_16x16x32_bf16(ah, bl, acc[nt], 0, 0, 0);
      acc[nt] = __builtin_amdgcn_mfma_f32_16x16x32_bf16(al, bh, acc[nt], 0, 0, 0);
    }
  }

#pragma unroll
  for (int nt = 0; nt < 4; ++nt) {
    int col = nt * 16 + m;
    float bi = bias[col], bg = bias[128 + col], bo = bias[192 + col];
#pragma unroll
    for (int reg = 0; reg < 4; ++reg) {
      float gi = acc[nt][reg] + bi;
      float gg = acc[nt + 4][reg] + bg;
      float go = acc[nt + 8][reg] + bo;
      float cc = sigm(gi) * tanhf(gg);
      H[(r0 + q * 4 + reg) * 64 + col] = packsplit(sigm(go) * tanhf(cc));
    }
  }
}

// ============================ GAT aggregate ============================

template <int FO, int OPK>
__global__ __launch_bounds__(256) void gat_agg(
    const float* __restrict__ G, const float* __restrict__ s,
    const float* __restrict__ t, const int* __restrict__ row_start,
    const int* __restrict__ srcs, const float* __restrict__ bias,
    void* __restrict__ outv, int ldc) {
  constexpr int CAP = 128;
  constexpr int LPE = FO / 4;
  constexpr int EPW = 64 / LPE;
  __shared__ float ecache[4][CAP];
  const int wv = threadIdx.x >> 6;
  const int lane = threadIdx.x & 63;
  const int d = blockIdx.x * 4 + wv;
  const int start = row_start[d], end = row_start[d + 1];
  const float td = t[d];

  float m = NEG_BIG, dsum = 0.0f;
  for (int j = start + lane; j < end; j += 64) {
    float e = leaky(s[srcs[j]] + td);
    int idx = j - start;
    if (idx < CAP) ecache[wv][idx] = e;
    float mn = fmaxf(m, e);
    dsum = dsum * __expf(m - mn) + __expf(e - mn);
    m = mn;
  }
#pragma unroll
  for (int off = 32; off; off >>= 1) {
    float mo = __shfl_xor(m, off, 64);
    float dso = __shfl_xor(dsum, off, 64);
    float mn = fmaxf(m, mo);
    dsum = dsum * __expf(m - mn) + dso * __expf(mo - mn);
    m = mn;
  }
  const float inv = 1.0f / dsum;

  const int deg = end - start;
  const int capdeg = deg < CAP ? deg : CAP;
  for (int idx = lane; idx < capdeg; idx += 64)
    ecache[wv][idx] = __expf(ecache[wv][idx] - m) * inv;
  __syncthreads();

  const int grp = lane / LPE, cl = lane % LPE;
  const float* __restrict__ Gc = G + cl * 4;
  float a0 = 0.0f, a1 = 0.0f, a2 = 0.0f, a3 = 0.0f;
  int j = start + grp;
  for (; j + EPW < end; j += 2 * EPW) {
    int s0 = srcs[j], s1 = srcs[j + EPW];
    int i0 = j - start, i1 = i0 + EPW;
    float al0 = (i0 < CAP) ? ecache[wv][i0]
                           : __expf(leaky(s[s0] + td) - m) * inv;
    float al1 = (i1 < CAP) ? ecache[wv][i1]
                           : __expf(leaky(s[s1] + td) - m) * inv;
    f32x4u g0 = *(const f32x4u*)(Gc + (long long)s0 * FO);
    f32x4u g1 = *(const f32x4u*)(Gc + (long long)s1 * FO);
    a0 = fmaf(al0, g0[0], a0); a1 = fmaf(al0, g0[1], a1);
    a2 = fmaf(al0, g0[2], a2); a3 = fmaf(al0, g0[3], a3);
    a0 = fmaf(al1, g1[0], a0); a1 = fmaf(al1, g1[1], a1);
    a2 = fmaf(al1, g1[2], a2); a3 = fmaf(al1, g1[3], a3);
  }
  if (j < end) {
    int s0 = srcs[j];
    int i0 = j - start;
    float al0 = (i0 < CAP) ? ecache[wv][i0]
                           : __expf(leaky(s[s0] + td) - m) * inv;
    f32x4u g0 = *(const f32x4u*)(Gc + (long long)s0 * FO);
    a0 = fmaf(al0, g0[0], a0); a1 = fmaf(al0, g0[1], a1);
    a2 = fmaf(al0, g0[2], a2); a3 = fmaf(al0, g0[3], a3);
  }
#pragma unroll
  for (int off = 32; off >= LPE; off >>= 1) {
    a0 += __shfl_xor(a0, off, 64);
    a1 += __shfl_xor(a1, off, 64);
    a2 += __shfl_xor(a2, off, 64);
    a3 += __shfl_xor(a3, off, 64);
  }
  if (grp == 0) {
    f32x4u bs = *(const f32x4u*)(bias + cl * 4);
    float v0 = fmaxf(a0 + bs[0], 0.0f);
    float v1 = fmaxf(a1 + bs[1], 0.0f);
    float v2 = fmaxf(a2 + bs[2], 0.0f);
    float v3 = fmaxf(a3 + bs[3], 0.0f);
    if (OPK == 1) {
      u32x4 pv;
      pv[0] = packsplit(v0); pv[1] = packsplit(v1);
      pv[2] = packsplit(v2); pv[3] = packsplit(v3);
      *(u32x4*)((unsigned*)outv + (long long)d * ldc + cl * 4) = pv;
    } else {
      f32x4u v; v[0] = v0; v[1] = v1; v[2] = v2; v[3] = v3;
      *(f32x4u*)((float*)outv + (long long)d * ldc + cl * 4) = v;
    }
  }
}

// ============================ head ============================

__global__ void lin3_kernel(const float* __restrict__ Z, const float* __restrict__ w,
                            const float* __restrict__ b, float* __restrict__ out, int N) {
  int i = blockIdx.x * blockDim.x + threadIdx.x;
  if (i >= N) return;
  const float4* z4 = (const float4*)(Z + (long long)i * 64);
  const float4* w4 = (const float4*)w;
  float acc = 0.0f;
#pragma unroll
  for (int k = 0; k < 16; ++k) {
    float4 a = z4[k], ww = w4[k];
    acc += a.x * ww.x + a.y * ww.y + a.z * ww.z + a.w * ww.w;
  }
  out[i] = acc + b[0];
}

// ============================ launcher ============================

struct WSplit { const short* hi; const short* lo; };

extern "C" void kernel_launch(void* const* d_in, const int* in_sizes, int n_in,
                              void* d_out, int out_size, void* d_ws, size_t ws_size,
                              hipStream_t stream) {
  const int N = 65536, E = 1048576;
  const int Et = E + N;

  const float* x        = (const float*)d_in[0];
  const int*   ei       = (const int*)d_in[1];
  const float* poi1_W   = (const float*)d_in[2];
  const float* poi1_b   = (const float*)d_in[3];
  const float* poi2_W   = (const float*)d_in[4];
  const float* poi2_b   = (const float*)d_in[5];
  const float* svi1_W   = (const float*)d_in[6];
  const float* svi1_b   = (const float*)d_in[7];
  const float* svi2_W   = (const float*)d_in[8];
  const float* svi2_b   = (const float*)d_in[9];
  const float* all1_W   = (const float*)d_in[10];
  const float* all1_b   = (const float*)d_in[11];
  const float* all2_W   = (const float*)d_in[12];
  const float* all2_b   = (const float*)d_in[13];
  const float* gat1_W   = (const float*)d_in[14];
  const float* gat1_b   = (const float*)d_in[15];
  const float* gat1_as  = (const float*)d_in[16];
  const float* gat1_ad  = (const float*)d_in[17];
  const float* gat2_W   = (const float*)d_in[18];
  const float* gat2_b   = (const float*)d_in[19];
  const float* gat2_as  = (const float*)d_in[20];
  const float* gat2_ad  = (const float*)d_in[21];
  const float* gat3_W   = (const float*)d_in[22];
  const float* gat3_b   = (const float*)d_in[23];
  const float* gat3_as  = (const float*)d_in[24];
  const float* gat3_ad  = (const float*)d_in[25];
  const float* lstm_Wih0= (const float*)d_in[26];
  const float* lstm_Wih = (const float*)d_in[27];
  const float* lstm_b   = (const float*)d_in[29];
  const float* time1_W  = (const float*)d_in[30];
  const float* time1_b  = (const float*)d_in[31];
  const float* time2_W  = (const float*)d_in[32];
  const float* time2_b  = (const float*)d_in[33];
  const float* lin1_W   = (const float*)d_in[34];
  const float* lin1_b   = (const float*)d_in[35];
  const float* lin2_W   = (const float*)d_in[36];
  const float* lin2_b   = (const float*)d_in[37];
  const float* lin3_W   = (const float*)d_in[38];
  const float* lin3_b   = (const float*)d_in[39];
  float* out = (float*)d_out;

  // ---- workspace layout ----
  float* wsf   = (float*)d_ws;
  float* R192  = wsf;
  float* RA    = R192 + (size_t)N * 192;
  float* RA2   = RA + (size_t)N * 64;
  float* RB    = RA + (size_t)N * 128;
  float* Rz    = RB + (size_t)N * 256;
  float* sArr  = Rz + (size_t)N * 128;
  float* tArr  = sArr + N;
  int* ints         = (int*)(tArr + N);
  int* row_start    = ints;                        // N+1
  int* srcs         = row_start + (N + 1);         // Et
  int* bucket_cnt   = srcs + Et;                   // 512
  int* bucket_start = bucket_cnt + 512;            // 513
  unsigned* ebuf    = (unsigned*)(bucket_start + 513);  // 512*CAPB (8MB)
  short* pool = (short*)(((uintptr_t)(ebuf + 512 * CAPB) + 15) & ~(uintptr_t)15);

  WJobs jb{};
  int nj = 0, tiles = 0;
  auto split = [&](const float* W, int K, int M, int ldw, int skip) -> WSplit {
    int KC = (K + 31) / 32;
    size_t sz = (size_t)KC * M * 32;
    short* hi = pool; pool += sz;
    short* lo = pool; pool += sz;
    jb.W[nj] = W; jb.hi[nj] = hi; jb.lo[nj] = lo;
    jb.K[nj] = K; jb.M16[nj] = M / 16; jb.ldw[nj] = ldw; jb.skip[nj] = skip;
    jb.tile0[nj] = tiles;
    tiles += KC * (M / 16);
    ++nj;
    return {hi, lo};
  };

  // M=64 -> NT=4, M=128 -> NT=8; grid covers all rows (MT=2 -> 32 rows/block)
  auto gemm = [&](const void* A, int lda, WSplit w, const float* bias,
                  void* C, int ldc, int K, int M, int act, int apk, int opk) {
    int KC = (K + 31) / 32;
    dim3 grid(N / 32), blk(64);
    if (M == 64) {
      if (apk == 0 && opk == 1)
        hipLaunchKernelGGL((gemm_mfma<2, 4, 0, 1, 0>), grid, blk, 0, stream,
                           A, lda, w.hi, w.lo, bias, C, ldc, K, KC, act,
                           nullptr, nullptr, nullptr, nullptr);
      else if (apk == 1 && opk == 1)
        hipLaunchKernelGGL((gemm_mfma<2, 4, 1, 1, 0>), grid, blk, 0, stream,
                           A, lda, w.hi, w.lo, bias, C, ldc, K, KC, act,
                           nullptr, nullptr, nullptr, nullptr);
      else if (apk == 1 && opk == 0)
        hipLaunchKernelGGL((gemm_mfma<2, 4, 1, 0, 0>), grid, blk, 0, stream,
                           A, lda, w.hi, w.lo, bias, C, ldc, K, KC, act,
                           nullptr, nullptr, nullptr, nullptr);
      else
        hipLaunchKernelGGL((gemm_mfma<2, 4, 0, 0, 0>), grid, blk, 0, stream,
                           A, lda, w.hi, w.lo, bias, C, ldc, K, KC, act,
                           nullptr, nullptr, nullptr, nullptr);
    } else {  // M == 128
      if (apk == 0 && opk == 1)
        hipLaunchKernelGGL((gemm_mfma<2, 8, 0, 1, 0>), grid, blk, 0, stream,
                           A, lda, w.hi, w.lo, bias, C, ldc, K, KC, act,
                           nullptr, nullptr, nullptr, nullptr);
      else if (apk == 1 && opk == 1)
        hipLaunchKernelGGL((gemm_mfma<2, 8, 1, 1, 0>), grid, blk, 0, stream,
                           A, lda, w.hi, w.lo, bias, C, ldc, K, KC, act,
                           nullptr, nullptr, nullptr, nullptr);
      else if (apk == 1 && opk == 0)
        hipLaunchKernelGGL((gemm_mfma<2, 8, 1, 0, 0>), grid, blk, 0, stream,
                           A, lda, w.hi, w.lo, bias, C, ldc, K, KC, act,
                           nullptr, nullptr, nullptr, nullptr);
      else
        hipLaunchKernelGGL((gemm_mfma<2, 8, 0, 0, 0>), grid, blk, 0, stream,
                           A, lda, w.hi, w.lo, bias, C, ldc, K, KC, act,
                           nullptr, nullptr, nullptr, nullptr);
    }
  };
  // GAT GEMM with fused s/t epilogue (direct store; no fill, no atomics)
  auto gemm_st = [&](const void* A, WSplit w, void* G, int M,
                     const float* as_, const float* ad_) {
    dim3 grid(N / 32), blk(64);
    if (M == 128)
      hipLaunchKernelGGL((gemm_mfma<2, 8, 1, 0, 1>), grid, blk, 0, stream,
                         A, 128, w.hi, w.lo, (const float*)nullptr,
                         G, 128, 128, 4, 0, as_, ad_, sArr, tArr);
    else
      hipLaunchKernelGGL((gemm_mfma<2, 4, 1, 0, 1>), grid, blk, 0, stream,
                         A, 128, w.hi, w.lo, (const float*)nullptr,
                         G, 64, 128, 4, 0, as_, ad_, sArr, tArr);
  };

  // ---- register all weight splits, then ONE fused split launch ----
  WSplit wpoi1 = split(poi1_W, 13, 64, 64, 0);
  WSplit wpoi2 = split(poi2_W, 64, 64, 64, 0);
  WSplit wsvi1 = split(svi1_W, 365, 128, 128, 0);
  WSplit wsvi2 = split(svi2_W, 128, 128, 128, 0);
  WSplit wall1 = split(all1_W, 192, 128, 128, 0);
  WSplit wall2 = split(all2_W, 128, 128, 128, 0);
  WSplit wg1   = split(gat1_W, 128, 128, 128, 0);
  WSplit wg2   = split(gat2_W, 128, 128, 128, 0);
  WSplit wg3   = split(gat3_W, 128, 64, 64, 0);
  WSplit wls0  = split(lstm_Wih0, 24, 192, 256, 1);
  WSplit wls1  = split(lstm_Wih, 64, 192, 256, 1);
  WSplit wls2  = split(lstm_Wih + 64 * 256, 64, 192, 256, 1);
  WSplit wt1   = split(time1_W, 64, 64, 64, 0);
  WSplit wt2   = split(time2_W, 64, 64, 64, 0);
  WSplit wl1   = split(lin1_W, 128, 64, 64, 0);
  WSplit wl2   = split(lin2_W, 64, 64, 64, 0);
  hipLaunchKernelGGL(wsplit_all, dim3(tiles), dim3(64), 0, stream, jb, nj);

  const int TB = 256;

  // ---- build CSR via bucketed counting sort ----
  hipLaunchKernelGGL(fill_i32_kernel, dim3(2), dim3(TB), 0, stream,
                     bucket_cnt, 0, 512);
  hipLaunchKernelGGL(bucket_bin, dim3((Et + CHUNK - 1) / CHUNK), dim3(256),
                     0, stream, ei, bucket_cnt, ebuf, E, Et);
  hipLaunchKernelGGL(bucket_scan, dim3(1), dim3(512), 0, stream,
                     bucket_cnt, bucket_start, Et);
  hipLaunchKernelGGL(bucket_csr, dim3(512), dim3(128), 0, stream,
                     ebuf, bucket_cnt, bucket_start, row_start, srcs, N, Et);

  // ---- MLP towers (internal tensors packed) ----
  gemm(x + 3, 445, wpoi1, poi1_b, RA, 64, 13, 64, 1, 0, 1);
  gemm(RA, 64, wpoi2, poi2_b, R192, 192, 64, 64, 1, 1, 1);
  gemm(x + 56, 445, wsvi1, svi1_b, RB, 128, 365, 128, 1, 0, 1);
  gemm(RB, 128, wsvi2, svi2_b, R192 + 64, 192, 128, 128, 1, 1, 1);
  gemm(R192, 192, wall1, all1_b, RA, 128, 192, 128, 1, 1, 1);
  gemm(RA, 128, wall2, all2_b, RB, 128, 128, 128, 1, 1, 1);

  const int aggBlocks = N / 4;

  // ---- GAT1: GEMM(+direct s/t epilogue) -> aggregate ----
  gemm_st(RB, wg1, RA, 128, gat1_as, gat1_ad);
  hipLaunchKernelGGL((gat_agg<128, 1>), dim3(aggBlocks), dim3(256), 0, stream,
                     RA, sArr, tArr, row_start, srcs, gat1_b, RB, 128);
  // ---- GAT2 ----
  gemm_st(RB, wg2, RA, 128, gat2_as, gat2_ad);
  hipLaunchKernelGGL((gat_agg<128, 1>), dim3(aggBlocks), dim3(256), 0, stream,
                     RA, sArr, tArr, row_start, srcs, gat2_b, RB, 128);
  // ---- GAT3 (fo=64 -> Rz cols 0..63 packed) ----
  gemm_st(RB, wg3, RA, 64, gat3_as, gat3_ad);
  hipLaunchKernelGGL((gat_agg<64, 1>), dim3(aggBlocks), dim3(256), 0, stream,
                     RA, sArr, tArr, row_start, srcs, gat3_b, Rz, 128);

  // ---- "LSTM": fused GEMM+activation, f-gate skipped, packed h ----
  hipLaunchKernelGGL((gemm_lstm<0>), dim3(N / 16), dim3(64), 0, stream,
                     x + 421, 445, wls0.hi, wls0.lo, lstm_b,
                     (unsigned*)RA, 24, 1);
  hipLaunchKernelGGL((gemm_lstm<1>), dim3(N / 16), dim3(64), 0, stream,
                     RA, 64, wls1.hi, wls1.lo, lstm_b + 256,
                     (unsigned*)RA2, 64, 2);
  hipLaunchKernelGGL((gemm_lstm<1>), dim3(N / 16), dim3(64), 0, stream,
                     RA2, 64, wls2.hi, wls2.lo, lstm_b + 512,
                     (unsigned*)RA, 64, 2);

  // ---- time MLP -> Rz cols 64..127 packed ----
  gemm(RA, 64, wt1, time1_b, RA2, 64, 64, 64, 1, 1, 1);
  gemm(RA2, 64, wt2, time2_b, Rz + 64, 128, 64, 64, 1, 1, 1);

  // ---- head ----
  gemm(Rz, 128, wl1, lin1_b, RA, 64, 128, 64, 1, 1, 1);
  gemm(RA, 64, wl2, lin2_b, RA2, 64, 64, 64, 1, 1, 0);
  hipLaunchKernelGGL(lin3_kernel, dim3((N + TB - 1) / TB), dim3(TB), 0, stream,
                     RA2, lin3_W, lin3_b, out, N);
}